// Round 11
// baseline (390.258 us; speedup 1.0000x reference)
//
#include <hip/hip_runtime.h>
#include <hip/hip_bf16.h>
#include <math.h>

#define DEV __device__ __forceinline__

#define BB 2
#define VV 6
#define CC 128
#define NQ 1200
#define HH 8
#define PTSN 4
#define FFND 256
#define LVLSN 4
#define LTOT 29750
#define NROWS (BB*NQ)

__constant__ int c_W[4] = {200,100,50,25};
__constant__ int c_H[4] = {112,56,28,14};
__constant__ int c_S[4] = {0,22400,28000,29400};

DEV float bflo(unsigned u){ union{unsigned i; float f;}x; x.i = u<<16; return x.f; }
DEV float bfhi(unsigned u){ union{unsigned i; float f;}x; x.i = u&0xffff0000u; return x.f; }
DEV unsigned short f2bf(float f){ union{float f; unsigned i;}x; x.f=f; unsigned i=x.i;
  return (unsigned short)((i + 0x7fffu + ((i>>16)&1u))>>16); }
DEV unsigned addbf2(unsigned a, unsigned b){
  float lo = bflo(a)+bflo(b); float hi = bfhi(a)+bfhi(b);
  return (unsigned)f2bf(lo) | ((unsigned)f2bf(hi)<<16);
}
DEV float sigm(float z){ return 1.f/(1.f+__expf(-z)); }

typedef __attribute__((ext_vector_type(8))) short bf16x8;
typedef __attribute__((ext_vector_type(4))) float f32x4;

// ---------------- fused setup: bucket(2) + wt(16) + cw2t(16) + xpose(76) + qpe(600) ----------------
__global__ void k_misc(const int* __restrict__ view, int* __restrict__ order,
                       int* __restrict__ counts,
                       const float* __restrict__ vw, unsigned short* __restrict__ wt,
                       const float* __restrict__ cw2, unsigned short* __restrict__ cw2t,
                       const float* __restrict__ iqf, float* __restrict__ x,
                       const float* __restrict__ pos,
                       const float* __restrict__ w1, const float* __restrict__ b1,
                       const float* __restrict__ w2, const float* __restrict__ b2,
                       float* __restrict__ qpe){
  int bid = blockIdx.x;
  int t = threadIdx.x;
  if(bid < BB){
    if(t < 64){
      int b = bid; int lane = t;
      int base0=0,base1=0,base2=0,base3=0,base4=0,base5=0;
      for(int c0=0;c0<NQ;c0+=64){
        int n = c0 + lane;
        int v = (n<NQ) ? view[b*NQ+n] : -1;
        unsigned long long lower = (lane==63)? 0x7fffffffffffffffull : ((1ull<<lane)-1ull);
        #define BUCKET_STEP(VVV, BASE) { \
          unsigned long long mk = __ballot(v==VVV); \
          if(v==VVV){ int r = BASE + __popcll(mk & lower); order[(b*VV+VVV)*NQ + r] = n; } \
          BASE += __popcll(mk); }
        BUCKET_STEP(0, base0) BUCKET_STEP(1, base1) BUCKET_STEP(2, base2)
        BUCKET_STEP(3, base3) BUCKET_STEP(4, base4) BUCKET_STEP(5, base5)
        #undef BUCKET_STEP
      }
      if(lane==0){
        counts[b*VV+0]=base0; counts[b*VV+1]=base1; counts[b*VV+2]=base2;
        counts[b*VV+3]=base3; counts[b*VV+4]=base4; counts[b*VV+5]=base5;
      }
    }
  } else if(bid < BB+16){
    int d0 = (bid-BB)*8;
    __shared__ float s[128][9];
    #pragma unroll
    for(int p=0;p<4;p++){ int i = t + p*256; int c = i>>3, dd = i&7;
      s[c][dd] = vw[c*128 + d0 + dd]; }
    __syncthreads();
    #pragma unroll
    for(int p=0;p<4;p++){ int i = t + p*256; int dd = i>>7, c = i&127;
      wt[(size_t)(d0+dd)*128 + c] = f2bf(s[c][dd]); }
  } else if(bid < BB+32){
    int d0 = (bid-BB-16)*8;
    __shared__ float s[128][9];
    #pragma unroll
    for(int p=0;p<4;p++){ int i = t + p*256; int c = i>>3, dd = i&7;
      s[c][dd] = cw2[c*128 + d0 + dd]; }
    __syncthreads();
    #pragma unroll
    for(int p=0;p<4;p++){ int i = t + p*256; int dd = i>>7, c = i&127;
      cw2t[(size_t)(d0+dd)*128 + c] = f2bf(s[c][dd]); }
  } else if(bid < BB+32+76){
    __shared__ float tile[128][33];
    int idx = bid - (BB+32);
    int b = idx/38; int n0 = (idx%38)*32;
    for(int i=t;i<128*32;i+=256){ int c=i>>5, nn=i&31; int n=n0+nn;
      tile[c][nn] = (n<NQ)? iqf[((size_t)b*CC + c)*NQ + n] : 0.f; }
    __syncthreads();
    for(int i=t;i<32*128;i+=256){ int nn=i>>7, c=i&127;
      int n=n0+nn; if(n<NQ) x[((size_t)b*NQ+n)*128 + c] = tile[c][nn]; }
  } else {
    __shared__ float hid[4][128];
    int row0 = (bid - (BB+32+76))*4;
    int r = t>>7, d = t&127;
    #pragma unroll
    for(int rr=r; rr<4; rr+=2){
      int row = row0 + rr;
      float p0 = pos[row*2+0], p1 = pos[row*2+1];
      hid[rr][d] = fmaxf(p0*w1[d] + p1*w1[128+d] + b1[d], 0.f);
    }
    __syncthreads();
    #pragma unroll
    for(int rr=r; rr<4; rr+=2){
      float acc = b2[d];
      #pragma unroll 4
      for(int c=0;c<128;c++) acc += hid[rr][c]*w2[c*128 + d];
      qpe[(size_t)(row0+rr)*128+d] = acc;
    }
  }
}

// ---------------- kvpe via MFMA: hid MLP -> GEMM1 (cw2t) -> GEMM2 (wt) ----------------
__global__ void __launch_bounds__(256) k_kvpe2(
    const float* __restrict__ kpos,
    const float* __restrict__ cw1, const float* __restrict__ cb1,
    const unsigned short* __restrict__ cw2t, const float* __restrict__ cb2,
    const unsigned short* __restrict__ wt, const float* __restrict__ vb,
    unsigned short* __restrict__ kvpe){
  __shared__ unsigned short h_t[64][136];
  __shared__ unsigned short k_t[64][136];
  int t = threadIdx.x;
  int r0 = blockIdx.x*64;
  int lane = t&63, wave = t>>6;
  int fr = lane&15, kg = lane>>4;

  int p = t & 63;
  int d0 = p*2;
  float w1a0 = cw1[d0],     w1a1 = cw1[d0+1];
  float w1b0 = cw1[128+d0], w1b1 = cw1[128+d0+1];
  float b10 = cb1[d0], b11 = cb1[d0+1];
  #pragma unroll 4
  for(int k=0;k<16;k++){
    int r = wave + k*4;
    int row = r0 + r;
    float p0=0.f, p1=0.f;
    if(row < LTOT){ p0 = kpos[row*2]; p1 = kpos[row*2+1]; }
    float h0 = fmaxf(p0*w1a0 + p1*w1b0 + b10, 0.f);
    float h1 = fmaxf(p0*w1a1 + p1*w1b1 + b11, 0.f);
    *reinterpret_cast<unsigned*>(&h_t[r][d0]) = (unsigned)f2bf(h0) | ((unsigned)f2bf(h1)<<16);
  }
  __syncthreads();

  f32x4 acc[4][2];
  #pragma unroll
  for(int i=0;i<4;i++)
    #pragma unroll
    for(int j=0;j<2;j++) acc[i][j] = (f32x4)0.f;
  #pragma unroll
  for(int ck=0; ck<4; ck++){
    int c0 = ck*32;
    bf16x8 bfr[2], af[4];
    #pragma unroll
    for(int j=0;j<2;j++){ int d = wave*32 + j*16 + fr;
      bfr[j] = *reinterpret_cast<const bf16x8*>(cw2t + (size_t)d*128 + c0 + kg*8); }
    #pragma unroll
    for(int i=0;i<4;i++) af[i] = *reinterpret_cast<const bf16x8*>(&h_t[i*16 + fr][c0 + kg*8]);
    #pragma unroll
    for(int i=0;i<4;i++)
      #pragma unroll
      for(int j=0;j<2;j++)
        acc[i][j] = __builtin_amdgcn_mfma_f32_16x16x32_bf16(af[i], bfr[j], acc[i][j], 0, 0, 0);
  }
  #pragma unroll
  for(int i=0;i<4;i++){
    int rbase = i*16 + kg*4;
    #pragma unroll
    for(int j=0;j<2;j++){
      int d = wave*32 + j*16 + fr;
      float bv_ = cb2[d];
      #pragma unroll
      for(int r=0;r<4;r++) k_t[rbase + r][d] = f2bf(acc[i][j][r] + bv_);
    }
  }
  __syncthreads();

  #pragma unroll
  for(int i=0;i<4;i++)
    #pragma unroll
    for(int j=0;j<2;j++) acc[i][j] = (f32x4)0.f;
  #pragma unroll
  for(int ck=0; ck<4; ck++){
    int c0 = ck*32;
    bf16x8 bfr[2], af[4];
    #pragma unroll
    for(int j=0;j<2;j++){ int d = wave*32 + j*16 + fr;
      bfr[j] = *reinterpret_cast<const bf16x8*>(wt + (size_t)d*128 + c0 + kg*8); }
    #pragma unroll
    for(int i=0;i<4;i++) af[i] = *reinterpret_cast<const bf16x8*>(&k_t[i*16 + fr][c0 + kg*8]);
    #pragma unroll
    for(int i=0;i<4;i++)
      #pragma unroll
      for(int j=0;j<2;j++)
        acc[i][j] = __builtin_amdgcn_mfma_f32_16x16x32_bf16(af[i], bfr[j], acc[i][j], 0, 0, 0);
  }
  __syncthreads();
  unsigned short (*c_l)[136] = h_t;
  #pragma unroll
  for(int i=0;i<4;i++){
    int rbase = i*16 + kg*4;
    #pragma unroll
    for(int j=0;j<2;j++){
      int d = wave*32 + j*16 + fr;
      float bv_ = vb[d];
      #pragma unroll
      for(int r=0;r<4;r++) c_l[rbase + r][d] = f2bf(acc[i][j][r] + bv_);
    }
  }
  __syncthreads();
  #pragma unroll
  for(int p4=0;p4<4;p4++){
    int i = t + p4*256;
    int row = i>>4, seg = i&15;
    int glr = r0 + row;
    if(glr < LTOT){
      uint4 cu = *reinterpret_cast<const uint4*>(&c_l[row][seg*8]);
      *reinterpret_cast<uint4*>(kvpe + (size_t)glr*CC + seg*8) = cu;
    }
  }
}

// ---------------- merged: self-attention (blocks 0..1823, self-projecting) + value GEMM ----------------
#define NATT (19*48*2)
__global__ void __launch_bounds__(256) k_value_attn(
    const float* __restrict__ f0, const float* __restrict__ f1,
    const float* __restrict__ f2, const float* __restrict__ f3,
    const unsigned short* __restrict__ kvpe, const unsigned short* __restrict__ wt,
    unsigned short* __restrict__ value,
    const float* __restrict__ x, const float* __restrict__ qpe,
    const float* __restrict__ sa_wqkv, const float* __restrict__ sa_bqkv,
    const int* __restrict__ order, const int* __restrict__ counts,
    float* __restrict__ att){
  __shared__ __align__(16) char smem[45568];
  int t = threadIdx.x;
  int bid = blockIdx.x;
  if(bid < NATT){
    // ---- attention block: (qt, v, h, b), K-tile=64, projections computed in-block ----
    int qt = bid % 19;
    int vh = (bid/19) % 48;
    int b  = bid/(19*48);
    int v = vh>>3, h = vh&7;
    int C = counts[b*VV+v];
    int q0 = qt*64;
    if(q0 >= C) return;
    const int* ord = order + (size_t)(b*VV+v)*NQ;
    float (*xq_s)[128] = (float(*)[128])smem;                 // 32768 (aliases red)
    float (*red)[64][18] = (float(*)[64][18])smem;            // 18432 (used at end only)
    float (*k_s)[16] = (float(*)[16])(smem + 32768);          // 4096
    float (*v_s)[16] = (float(*)[16])(smem + 36864);          // 4096
    float (*q_s)[17] = (float(*)[17])(smem + 40960);          // 4352
    int* qn_s = (int*)(smem + 45312);                         // 256
    int hh16 = h*16;
    for(int i=t;i<64;i+=256){ int qi=q0+i; qn_s[i] = (qi<C)? ord[qi] : -1; }
    __syncthreads();
    // stage query rows (x+qpe)
    for(int i=t;i<8192;i+=256){ int r=i>>7, c=i&127; int n=qn_s[r];
      float vv=0.f;
      if(n>=0){ size_t rw=((size_t)b*NQ+n)*128+c; vv = x[rw]+qpe[rw]; }
      xq_s[r][c]=vv; }
    __syncthreads();
    // q projection for this head
    for(int i=t;i<1024;i+=256){ int r=i>>4, c16=i&15;
      float a = sa_bqkv[hh16+c16];
      #pragma unroll 4
      for(int c=0;c<128;c++) a += xq_s[r][c]*sa_wqkv[c*384 + hh16 + c16];
      q_s[r][c16]=a; }
    int qi = t&63, sub = t>>6;
    float m = -1e30f, s = 0.f, acc[16];
    #pragma unroll
    for(int c=0;c<16;c++) acc[c]=0.f;
    for(int k0=0; k0<C; k0+=64){
      int kn = C-k0; if(kn>64) kn=64;
      __syncthreads();  // prev tile mm-loop done; xq_s free; q_s visible
      for(int i=t;i<8192;i+=256){ int r=i>>7, c=i&127;
        float vv=0.f;
        if(r<kn){ int n=ord[k0+r]; size_t rw=((size_t)b*NQ+n)*128+c; vv = x[rw]+qpe[rw]; }
        xq_s[r][c]=vv; }
      __syncthreads();
      // k,v projections for this head
      for(int i=t;i<2048;i+=256){ int r=i>>5, j=i&31; int kv=j>>4, c16=j&15;
        int od = 128 + kv*128 + hh16 + c16;
        float a = sa_bqkv[od];
        #pragma unroll 4
        for(int c=0;c<128;c++) a += xq_s[r][c]*sa_wqkv[c*384 + od];
        if(kv==0) k_s[r][c16]=a; else v_s[r][c16]=a; }
      __syncthreads();
      for(int mm=sub; mm<kn; mm+=4){
        float l=0.f;
        #pragma unroll
        for(int c=0;c<16;c++) l += q_s[qi][c]*k_s[mm][c];
        l *= 0.25f;
        float newm = fmaxf(m,l);
        float e = __expf(l - newm);
        if(newm > m){
          float rr = __expf(m - newm);
          s *= rr;
          #pragma unroll
          for(int c=0;c<16;c++) acc[c]*=rr;
          m = newm;
        }
        s += e;
        #pragma unroll
        for(int c=0;c<16;c++) acc[c] += e*v_s[mm][c];
      }
    }
    __syncthreads();  // all mm-loops done before red (aliases xq_s) is written
    red[sub][qi][0]=m; red[sub][qi][1]=s;
    #pragma unroll
    for(int c=0;c<16;c++) red[sub][qi][2+c]=acc[c];
    __syncthreads();
    if(sub==0){
      int n = qn_s[qi];
      if(n>=0){
        float M=-1e30f;
        #pragma unroll
        for(int j=0;j<4;j++) M=fmaxf(M,red[j][qi][0]);
        float S=0.f; float o[16];
        #pragma unroll
        for(int c=0;c<16;c++) o[c]=0.f;
        #pragma unroll
        for(int j=0;j<4;j++){ float e=__expf(red[j][qi][0]-M); S += e*red[j][qi][1];
          #pragma unroll
          for(int c=0;c<16;c++) o[c] += e*red[j][qi][2+c]; }
        float inv = 1.f/S;
        #pragma unroll
        for(int c=0;c<16;c++) att[((size_t)b*NQ+n)*128 + hh16 + c] = o[c]*inv;
      }
    }
    return;
  }
  // ---- value GEMM (k_value6 core, unchanged) ----
  unsigned short (*a_t)[136] = (unsigned short(*)[136])smem;  // 17408
  int bxy = bid - NATT;
  int bv = bxy % 12;
  int bx = bxy / 12;
  int lvl, tile;
  if(bx < 350){ lvl=0; tile=bx; }
  else if(bx < 438){ lvl=1; tile=bx-350; }
  else if(bx < 460){ lvl=2; tile=bx-438; }
  else { lvl=3; tile=bx-460; }
  const int HW = (lvl==0)?22400:(lvl==1)?5600:(lvl==2)?1400:350;
  const int startL = (lvl==0)?0:(lvl==1)?22400:(lvl==2)?28000:29400;
  const float* feat = (lvl==0)?f0:(lvl==1)?f1:(lvl==2)?f2:f3;
  const float* fbase = feat + (size_t)bv*128*(size_t)HW;
  int l0 = tile*64;

  int lane = t&63, wave = t>>6;
  int fr = lane&15, kg = lane>>4;

  int l_u = t & 63, oct0 = t>>6;
  int gl = l0 + l_u; bool ok = (gl < HW);
  const float* fcol = fbase + (size_t)(oct0*8)*HW + (ok ? gl : 0);

  float v32[4][8];
  #pragma unroll
  for(int q=0;q<4;q++)
    #pragma unroll
    for(int j=0;j<8;j++)
      v32[q][j] = ok ? fcol[(size_t)(q*32+j)*HW] : 0.f;

  #pragma unroll
  for(int q=0;q<4;q++){
    uint4 u;
    u.x = (unsigned)f2bf(v32[q][0]) | ((unsigned)f2bf(v32[q][1])<<16);
    u.y = (unsigned)f2bf(v32[q][2]) | ((unsigned)f2bf(v32[q][3])<<16);
    u.z = (unsigned)f2bf(v32[q][4]) | ((unsigned)f2bf(v32[q][5])<<16);
    u.w = (unsigned)f2bf(v32[q][6]) | ((unsigned)f2bf(v32[q][7])<<16);
    *reinterpret_cast<uint4*>(&a_t[l_u][oct0*8 + q*32]) = u;
  }
  __syncthreads();

  f32x4 acc[4][2];
  #pragma unroll
  for(int i=0;i<4;i++)
    #pragma unroll
    for(int j=0;j<2;j++) acc[i][j] = (f32x4)0.f;

  #pragma unroll
  for(int ck=0; ck<4; ck++){
    int c0 = ck*32;
    bf16x8 bfr[2];
    #pragma unroll
    for(int j=0;j<2;j++){
      int d = wave*32 + j*16 + fr;
      bfr[j] = *reinterpret_cast<const bf16x8*>(wt + (size_t)d*128 + c0 + kg*8);
    }
    bf16x8 af[4];
    #pragma unroll
    for(int i=0;i<4;i++) af[i] = *reinterpret_cast<const bf16x8*>(&a_t[i*16 + fr][c0 + kg*8]);
    #pragma unroll
    for(int i=0;i<4;i++)
      #pragma unroll
      for(int j=0;j<2;j++)
        acc[i][j] = __builtin_amdgcn_mfma_f32_16x16x32_bf16(af[i], bfr[j], acc[i][j], 0, 0, 0);
  }

  __syncthreads();
  unsigned short (*c_l)[136] = a_t;
  #pragma unroll
  for(int i=0;i<4;i++){
    int rbase = i*16 + kg*4;
    #pragma unroll
    for(int j=0;j<2;j++){
      int d = wave*32 + j*16 + fr;
      #pragma unroll
      for(int r=0;r<4;r++) c_l[rbase + r][d] = f2bf(acc[i][j][r]);
    }
  }
  __syncthreads();
  #pragma unroll
  for(int p=0;p<4;p++){
    int i = t + p*256;
    int row = i>>4, seg = i&15;
    int glr = l0 + row;
    if(glr < HW){
      uint4 cu = *reinterpret_cast<const uint4*>(&c_l[row][seg*8]);
      const uint4 ku = *reinterpret_cast<const uint4*>(kvpe + (size_t)(startL+glr)*CC + seg*8);
      uint4 ou;
      ou.x = addbf2(cu.x, ku.x); ou.y = addbf2(cu.y, ku.y);
      ou.z = addbf2(cu.z, ku.z); ou.w = addbf2(cu.w, ku.w);
      *reinterpret_cast<uint4*>(value + ((size_t)bv*LTOT + startL + glr)*CC + seg*8) = ou;
    }
  }
}

// ---------------- fused: proj+LN1 -> qc (LDS) -> offset matvec + attn-weight softmax ----------------
__global__ void __launch_bounds__(384) k_q2(
    const float* __restrict__ att, const float* __restrict__ sa_wo, const float* __restrict__ sa_bo,
    float* __restrict__ x, const float* __restrict__ ln1_g, const float* __restrict__ ln1_b,
    const float* __restrict__ qpe,
    const float* __restrict__ dow, const float* __restrict__ dob,
    const float* __restrict__ daw, const float* __restrict__ dab,
    float* __restrict__ offb, float* __restrict__ awb){
  int r0 = blockIdx.x*8; int t = threadIdx.x; // 384 threads
  __shared__ float s_att[8][128];
  __shared__ float s_qc[8][128];
  __shared__ float s_m[8][2][2];
  __shared__ float s_aw[8][130];
  for(int i=t;i<1024;i+=384){ int r=i>>7, c=i&127; s_att[r][c]=att[(size_t)(r0+r)*128+c]; }
  __syncthreads();
  int lane = t&63, wid = (t>>6)&1;
  float v[8];
  if(t < 128){
    int d = t;
    float acc[8];
    #pragma unroll
    for(int r=0;r<8;r++) acc[r]=sa_bo[d];
    #pragma unroll 4
    for(int c=0;c<128;c++){ float wv = sa_wo[c*128+d];
      #pragma unroll
      for(int r=0;r<8;r++) acc[r] += s_att[r][c]*wv; }
    #pragma unroll
    for(int r=0;r<8;r++){
      v[r] = acc[r] + x[(size_t)(r0+r)*128 + d];
      float s1=v[r], s2=v[r]*v[r];
      for(int o=32;o>0;o>>=1){ s1 += __shfl_down(s1,o); s2 += __shfl_down(s2,o); }
      if(lane==0){ s_m[r][wid][0]=s1; s_m[r][wid][1]=s2; }
    }
  }
  __syncthreads();
  if(t < 128){
    int d = t;
    #pragma unroll
    for(int r=0;r<8;r++){
      float S1=s_m[r][0][0]+s_m[r][1][0], S2=s_m[r][0][1]+s_m[r][1][1];
      float mean=S1*(1.f/128.f), var=S2*(1.f/128.f)-mean*mean;
      float rs=rsqrtf(var+1e-5f);
      float o=(v[r]-mean)*rs*ln1_g[d]+ln1_b[d];
      x[(size_t)(r0+r)*128+d]=o;
      s_qc[r][d]=o+qpe[(size_t)(r0+r)*128+d];
    }
  }
  __syncthreads();
  if(t < 256){
    int d = t;
    float acc[8];
    #pragma unroll
    for(int r=0;r<8;r++) acc[r]=dob[d];
    #pragma unroll 4
    for(int c=0;c<128;c++){ float wv = dow[(size_t)c*256+d];
      #pragma unroll
      for(int r=0;r<8;r++) acc[r] += s_qc[r][c]*wv; }
    #pragma unroll
    for(int r=0;r<8;r++) offb[(size_t)(r0+r)*256+d]=acc[r];
  } else {
    int d = t - 256;
    float acc[8];
    #pragma unroll
    for(int r=0;r<8;r++) acc[r]=dab[d];
    #pragma unroll 4
    for(int c=0;c<128;c++){ float wv = daw[(size_t)c*128+d];
      #pragma unroll
      for(int r=0;r<8;r++) acc[r] += s_qc[r][c]*wv; }
    #pragma unroll
    for(int r=0;r<8;r++) s_aw[r][d]=acc[r];
  }
  __syncthreads();
  if(t < 64){
    int r = t>>3, h = t&7;
    float mx=-1e30f;
    #pragma unroll
    for(int i=0;i<16;i++) mx = fmaxf(mx, s_aw[r][h*16+i]);
    float e[16]; float sm=0.f;
    #pragma unroll
    for(int i=0;i<16;i++){ e[i]=__expf(s_aw[r][h*16+i]-mx); sm+=e[i]; }
    float inv = 1.f/sm;
    #pragma unroll
    for(int i=0;i<16;i++) awb[(size_t)(r0+r)*128 + h*16+i] = e[i]*inv;
  }
}

// ---------------- fused tail: bilinear sample + proj_ln2 + FFN1 + FFN2/LN3 + head ----------------
__global__ void __launch_bounds__(128) k_tail2(
    const float* __restrict__ qpos, const int* __restrict__ view,
    const float* __restrict__ offb, const float* __restrict__ awb,
    const unsigned short* __restrict__ value,
    const float* __restrict__ dOw, const float* __restrict__ dOb,
    const float* __restrict__ xres,
    const float* __restrict__ ln2_g, const float* __restrict__ ln2_b,
    const float* __restrict__ fw1, const float* __restrict__ fb1,
    const float* __restrict__ fw2, const float* __restrict__ fb2,
    const float* __restrict__ ln3_g, const float* __restrict__ ln3_b,
    const float* __restrict__ pw1, const float* __restrict__ pb1,
    const float* __restrict__ pw2, const float* __restrict__ pb2,
    const int* __restrict__ counts, float* __restrict__ dout){
  int r0 = blockIdx.x*4; int d = threadIdx.x;  // 128 threads
  __shared__ float s_a[4][256];
  __shared__ float s_x[4][128];
  __shared__ float s_m[4][2][2];
  __shared__ float s_res[4][6];
  __shared__ float sred[128][17];
  __shared__ float s_ca[4][128];
  int lane = d&63, wid = d>>6;

  // ---- sample phase: gathers for all 4 rows issued, then reduced ----
  int h = d>>4, lp = d&15, lvl = lp>>2;
  int w = c_W[lvl], hh = c_H[lvl];
  float samp[4][16]; float aw4[4];
  int vw4[4];
  #pragma unroll
  for(int r=0;r<4;r++){
    size_t row = (size_t)(r0+r);
    int b = (r0+r)/NQ;
    float rx = sigm(qpos[row*2]), ry = sigm(qpos[row*2+1]);
    int vw = view[row]; vw4[r]=vw;
    float ox = offb[row*256 + d*2], oy = offb[row*256 + d*2+1];
    aw4[r] = awb[row*128 + d];
    float lx = rx*(float)w + ox - 0.5f;
    float ly = ry*(float)hh + oy - 0.5f;
    float x0f = floorf(lx), y0f = floorf(ly);
    float fx = lx - x0f, fy = ly - y0f;
    int x0 = (int)x0f, y0 = (int)y0f;
    #pragma unroll
    for(int c=0;c<16;c++) samp[r][c]=0.f;
    size_t brow = ((size_t)(b*VV + vw))*LTOT + c_S[lvl];
    #pragma unroll
    for(int dy=0;dy<2;dy++){
      #pragma unroll
      for(int dx=0;dx<2;dx++){
        int xi=x0+dx, yi=y0+dy;
        if(xi<0||xi>=w||yi<0||yi>=hh) continue;
        float wt = (dx?fx:(1.f-fx))*(dy?fy:(1.f-fy));
        const uint4* vp = reinterpret_cast<const uint4*>(value + (brow + (size_t)yi*w + xi)*CC + h*16);
        uint4 u0 = vp[0], u1 = vp[1];
        samp[r][0] += wt*bflo(u0.x); samp[r][1] += wt*bfhi(u0.x);
        samp[r][2] += wt*bflo(u0.y); samp[r][3] += wt*bfhi(u0.y);
        samp[r][4] += wt*bflo(u0.z); samp[r][5] += wt*bfhi(u0.z);
        samp[r][6] += wt*bflo(u0.w); samp[r][7] += wt*bfhi(u0.w);
        samp[r][8] += wt*bflo(u1.x); samp[r][9] += wt*bfhi(u1.x);
        samp[r][10]+= wt*bflo(u1.y); samp[r][11]+= wt*bfhi(u1.y);
        samp[r][12]+= wt*bflo(u1.z); samp[r][13]+= wt*bfhi(u1.z);
        samp[r][14]+= wt*bflo(u1.w); samp[r][15]+= wt*bfhi(u1.w);
      }
    }
  }
  #pragma unroll
  for(int r=0;r<4;r++){
    #pragma unroll
    for(int c=0;c<16;c++) sred[d][c] = aw4[r]*samp[r][c];
    __syncthreads();
    int h2=d>>4, c2=d&15;
    float sum=0.f;
    #pragma unroll
    for(int j=0;j<16;j++) sum += sred[h2*16+j][c2];
    s_ca[r][d] = sum;
    __syncthreads();
  }

  // ---- proj2 + resid + LN2 -> s_x ----
  #pragma unroll
  for(int r=0;r<4;r++) s_a[r][d] = s_ca[r][d];
  __syncthreads();
  float acc[4];
  #pragma unroll
  for(int r=0;r<4;r++) acc[r]=dOb[d];
  #pragma unroll 4
  for(int c=0;c<128;c++){ float wv = dOw[c*128+d];
    #pragma unroll
    for(int r=0;r<4;r++) acc[r] += s_a[r][c]*wv; }
  float v[4];
  #pragma unroll
  for(int r=0;r<4;r++){
    v[r] = acc[r] + xres[(size_t)(r0+r)*128 + d];
    float s1=v[r], s2=v[r]*v[r];
    for(int o=32;o>0;o>>=1){ s1 += __shfl_down(s1,o); s2 += __shfl_down(s2,o); }
    if(lane==0){ s_m[r][wid][0]=s1; s_m[r][wid][1]=s2; }
  }
  __syncthreads();
  #pragma unroll
  for(int r=0;r<4;r++){
    float S1=s_m[r][0][0]+s_m[r][1][0], S2=s_m[r][0][1]+s_m[r][1][1];
    float mean=S1*(1.f/128.f), var=S2*(1.f/128.f)-mean*mean;
    float rs=rsqrtf(var+1e-5f);
    s_x[r][d]=(v[r]-mean)*rs*ln2_g[d]+ln2_b[d];
  }
  __syncthreads();

  // ---- FFN1 ----
  float a2a[4], a2b[4];
  #pragma unroll
  for(int r=0;r<4;r++){ a2a[r]=fb1[d]; a2b[r]=fb1[d+128]; }
  #pragma unroll 4
  for(int c=0;c<128;c++){ float w0 = fw1[c*256+d], w1_ = fw1[c*256+d+128];
    #pragma unroll
    for(int r=0;r<4;r++){ float xv = s_x[r][c]; a2a[r] += xv*w0; a2b[r] += xv*w1_; } }
  __syncthreads();
  #pragma unroll
  for(int r=0;r<4;r++){ s_a[r][d]=fmaxf(a2a[r],0.f); s_a[r][d+128]=fmaxf(a2b[r],0.f); }
  __syncthreads();

  // ---- FFN2 + resid + LN3 + valid-zero ----
  float a3[4];
  #pragma unroll
  for(int r=0;r<4;r++) a3[r]=fb2[d];
  #pragma unroll 4
  for(int c=0;c<256;c++){ float wv = fw2[c*128+d];
    #pragma unroll
    for(int r=0;r<4;r++) a3[r] += s_a[r][c]*wv; }
  #pragma unroll
  for(int r=0;r<4;r++){
    v[r] = a3[r] + s_x[r][d];
    float s1=v[r], s2=v[r]*v[r];
    for(int o=32;o>0;o>>=1){ s1 += __shfl_down(s1,o); s2 += __shfl_down(s2,o); }
    if(lane==0){ s_m[r][wid][0]=s1; s_m[r][wid][1]=s2; }
  }
  __syncthreads();
  #pragma unroll
  for(int r=0;r<4;r++){
    float S1=s_m[r][0][0]+s_m[r][1][0], S2=s_m[r][0][1]+s_m[r][1][1];
    float mean=S1*(1.f/128.f), var=S2*(1.f/128.f)-mean*mean;
    float rs=rsqrtf(var+1e-5f);
    float o=(v[r]-mean)*rs*ln3_g[d]+ln3_b[d];
    int row=r0+r; int b=row/NQ, n=row%NQ;
    bool val = counts[b*VV + vw4[r]] > 1;
    float oz = val ? o : 0.f;
    s_x[r][d]=oz;
    dout[((size_t)b*CC + d)*NQ + n]=oz;
  }
  __syncthreads();

  // ---- head ----
  float a4[4];
  #pragma unroll
  for(int r=0;r<4;r++) a4[r]=pb1[d];
  #pragma unroll 4
  for(int c=0;c<128;c++){ float wv = pw1[c*128+d];
    #pragma unroll
    for(int r=0;r<4;r++) a4[r] += s_x[r][c]*wv; }
  #pragma unroll
  for(int r=0;r<4;r++) s_a[r][d]=fmaxf(a4[r],0.f);
  __syncthreads();

  if(d < 24){
    int r = d/6, o = d%6;
    float a5 = pb2[o];
    #pragma unroll 4
    for(int c=0;c<128;c++) a5 += s_a[r][c]*pw2[c*6+o];
    s_res[r][o] = a5;
  }
  __syncthreads();
  if(d < 4){
    int r = d; int row = r0+r; int b=row/NQ, n=row%NQ;
    const int O1 = BB*CC*NQ;
    const int O2 = O1 + BB*NQ*2;
    const int O3 = O2 + BB*2*NQ;
    const int O4 = O3 + BB*4*NQ;
    float p0=qpos[row*2], p1=qpos[row*2+1];
    float cr0 = s_res[r][0]+p0, cr1 = s_res[r][1]+p1;
    dout[O1 + row*2]   = cr0;
    dout[O1 + row*2+1] = cr1;
    float cen0 = sigm(cr0), cen1 = sigm(cr1);
    dout[O2 + (b*2+0)*NQ + n] = cen0;
    dout[O2 + (b*2+1)*NQ + n] = cen1;
    float f0=sigm(s_res[r][2]), f1=sigm(s_res[r][3]), f2=sigm(s_res[r][4]), f3=sigm(s_res[r][5]);
    dout[O3 + (b*4+0)*NQ + n] = f0;
    dout[O3 + (b*4+1)*NQ + n] = f1;
    dout[O3 + (b*4+2)*NQ + n] = f2;
    dout[O3 + (b*4+3)*NQ + n] = f3;
    float bw=f0+f2, bh=f1+f3;
    float cx=(2.f*cen0 - f0 + f2)*0.5f;
    float cy=(2.f*cen1 - f1 + f3)*0.5f;
    dout[O4 + (b*4+0)*NQ + n] = cx;
    dout[O4 + (b*4+1)*NQ + n] = cy;
    dout[O4 + (b*4+2)*NQ + n] = bw;
    dout[O4 + (b*4+3)*NQ + n] = bh;
  }
}

extern "C" void kernel_launch(void* const* d_in, const int* in_sizes, int n_in,
                              void* d_out, int out_size, void* d_ws, size_t ws_size,
                              hipStream_t stream){
  (void)in_sizes; (void)n_in; (void)out_size; (void)ws_size;
  const float* in_iqf  = (const float*)d_in[0];
  const float* in_qpos = (const float*)d_in[1];
  const float* in_feat[4] = {(const float*)d_in[2],(const float*)d_in[3],(const float*)d_in[4],(const float*)d_in[5]};
  const float* in_kpos = (const float*)d_in[6];
  const float* sp_w1=(const float*)d_in[7], *sp_b1=(const float*)d_in[8], *sp_w2=(const float*)d_in[9], *sp_b2=(const float*)d_in[10];
  const float* cp_w1=(const float*)d_in[11], *cp_b1=(const float*)d_in[12], *cp_w2=(const float*)d_in[13], *cp_b2=(const float*)d_in[14];
  const float* sa_wqkv=(const float*)d_in[15], *sa_bqkv=(const float*)d_in[16], *sa_wo=(const float*)d_in[17], *sa_bo=(const float*)d_in[18];
  const float* ln1_g=(const float*)d_in[19], *ln1_b=(const float*)d_in[20];
  const float* dvw=(const float*)d_in[21], *dvb=(const float*)d_in[22];
  const float* dow=(const float*)d_in[23], *dob=(const float*)d_in[24];
  const float* daw=(const float*)d_in[25], *dab=(const float*)d_in[26];
  const float* dOw=(const float*)d_in[27], *dOb=(const float*)d_in[28];
  const float* ln2_g=(const float*)d_in[29], *ln2_b=(const float*)d_in[30];
  const float* fw1=(const float*)d_in[31], *fb1=(const float*)d_in[32], *fw2=(const float*)d_in[33], *fb2=(const float*)d_in[34];
  const float* ln3_g=(const float*)d_in[35], *ln3_b=(const float*)d_in[36];
  const float* pw1=(const float*)d_in[37], *pb1=(const float*)d_in[38], *pw2=(const float*)d_in[39], *pb2=(const float*)d_in[40];
  const int* in_view = (const int*)d_in[41];
  float* out = (float*)d_out;

  char* ws = (char*)d_ws;
  unsigned short* value = (unsigned short*)ws;                       // 91,392,000 B
  unsigned short* kvpe  = (unsigned short*)(ws + 91392000);          //  7,616,000 B
  float* f = (float*)(ws + 91392000 + 7616000);
  float* qpe  = f;               // 307200
  float* x    = f + 307200;      // 307200
  float* att  = f + 1536000;     // 307200
  float* offb = f + 2150400;     // 614400
  float* awb  = f + 2764800;     // 307200
  int* counts = (int*)(f + 4300800);   // 12 ints
  int* order  = (int*)(f + 4300816);   // B*VV*NQ = 14400 ints
  unsigned short* wtb   = (unsigned short*)(f + 4315216);  // 32768 B
  unsigned short* cw2tb = (unsigned short*)(f + 4323408);  // 32768 B

  k_misc<<<dim3(BB+32+76+600),dim3(256),0,stream>>>(in_view,order,counts,dvw,wtb,
      cp_w2,cw2tb,in_iqf,x,in_qpos,sp_w1,sp_b1,sp_w2,sp_b2,qpe);
  k_kvpe2<<<dim3((LTOT+63)/64),dim3(256),0,stream>>>(in_kpos,cp_w1,cp_b1,cw2tb,cp_b2,wtb,dvb,kvpe);
  k_value_attn<<<dim3(NATT + 466*12),dim3(256),0,stream>>>(in_feat[0],in_feat[1],in_feat[2],in_feat[3],
      kvpe,wtb,value,x,qpe,sa_wqkv,sa_bqkv,order,counts,att);
  k_q2<<<dim3(NROWS/8),dim3(384),0,stream>>>(att,sa_wo,sa_bo,x,ln1_g,ln1_b,qpe,
      dow,dob,daw,dab,offb,awb);
  k_tail2<<<dim3(NROWS/4),dim3(128),0,stream>>>(in_qpos,in_view,offb,awb,value,
      dOw,dOb,x,ln2_g,ln2_b,fw1,fb1,fw2,fb2,ln3_g,ln3_b,pw1,pb1,pw2,pb2,counts,out);
}

// Round 12
// 229.045 us; speedup vs baseline: 1.7039x; 1.7039x over previous
//
#include <hip/hip_runtime.h>
#include <hip/hip_bf16.h>
#include <math.h>

#define DEV __device__ __forceinline__

#define BB 2
#define VV 6
#define CC 128
#define NQ 1200
#define HH 8
#define PTSN 4
#define FFND 256
#define LVLSN 4
#define LTOT 29750
#define NROWS (BB*NQ)

__constant__ int c_W[4] = {200,100,50,25};
__constant__ int c_H[4] = {112,56,28,14};
__constant__ int c_S[4] = {0,22400,28000,29400};

DEV float bflo(unsigned u){ union{unsigned i; float f;}x; x.i = u<<16; return x.f; }
DEV float bfhi(unsigned u){ union{unsigned i; float f;}x; x.i = u&0xffff0000u; return x.f; }
DEV unsigned short f2bf(float f){ union{float f; unsigned i;}x; x.f=f; unsigned i=x.i;
  return (unsigned short)((i + 0x7fffu + ((i>>16)&1u))>>16); }
DEV unsigned addbf2(unsigned a, unsigned b){
  float lo = bflo(a)+bflo(b); float hi = bfhi(a)+bfhi(b);
  return (unsigned)f2bf(lo) | ((unsigned)f2bf(hi)<<16);
}
DEV float sigm(float z){ return 1.f/(1.f+__expf(-z)); }

typedef __attribute__((ext_vector_type(8))) short bf16x8;
typedef __attribute__((ext_vector_type(4))) float f32x4;

// ---------------- fused setup: bucket(2) + wt(16) + cw2t(16) + xpose(76) + qpe(600) ----------------
__global__ void k_misc(const int* __restrict__ view, int* __restrict__ order,
                       int* __restrict__ counts,
                       const float* __restrict__ vw, unsigned short* __restrict__ wt,
                       const float* __restrict__ cw2, unsigned short* __restrict__ cw2t,
                       const float* __restrict__ iqf, float* __restrict__ x,
                       const float* __restrict__ pos,
                       const float* __restrict__ w1, const float* __restrict__ b1,
                       const float* __restrict__ w2, const float* __restrict__ b2,
                       float* __restrict__ qpe){
  int bid = blockIdx.x;
  int t = threadIdx.x;
  if(bid < BB){
    if(t < 64){
      int b = bid; int lane = t;
      int base0=0,base1=0,base2=0,base3=0,base4=0,base5=0;
      for(int c0=0;c0<NQ;c0+=64){
        int n = c0 + lane;
        int v = (n<NQ) ? view[b*NQ+n] : -1;
        unsigned long long lower = (lane==63)? 0x7fffffffffffffffull : ((1ull<<lane)-1ull);
        #define BUCKET_STEP(VVV, BASE) { \
          unsigned long long mk = __ballot(v==VVV); \
          if(v==VVV){ int r = BASE + __popcll(mk & lower); order[(b*VV+VVV)*NQ + r] = n; } \
          BASE += __popcll(mk); }
        BUCKET_STEP(0, base0) BUCKET_STEP(1, base1) BUCKET_STEP(2, base2)
        BUCKET_STEP(3, base3) BUCKET_STEP(4, base4) BUCKET_STEP(5, base5)
        #undef BUCKET_STEP
      }
      if(lane==0){
        counts[b*VV+0]=base0; counts[b*VV+1]=base1; counts[b*VV+2]=base2;
        counts[b*VV+3]=base3; counts[b*VV+4]=base4; counts[b*VV+5]=base5;
      }
    }
  } else if(bid < BB+16){
    int d0 = (bid-BB)*8;
    __shared__ float s[128][9];
    #pragma unroll
    for(int p=0;p<4;p++){ int i = t + p*256; int c = i>>3, dd = i&7;
      s[c][dd] = vw[c*128 + d0 + dd]; }
    __syncthreads();
    #pragma unroll
    for(int p=0;p<4;p++){ int i = t + p*256; int dd = i>>7, c = i&127;
      wt[(size_t)(d0+dd)*128 + c] = f2bf(s[c][dd]); }
  } else if(bid < BB+32){
    int d0 = (bid-BB-16)*8;
    __shared__ float s[128][9];
    #pragma unroll
    for(int p=0;p<4;p++){ int i = t + p*256; int c = i>>3, dd = i&7;
      s[c][dd] = cw2[c*128 + d0 + dd]; }
    __syncthreads();
    #pragma unroll
    for(int p=0;p<4;p++){ int i = t + p*256; int dd = i>>7, c = i&127;
      cw2t[(size_t)(d0+dd)*128 + c] = f2bf(s[c][dd]); }
  } else if(bid < BB+32+76){
    __shared__ float tile[128][33];
    int idx = bid - (BB+32);
    int b = idx/38; int n0 = (idx%38)*32;
    for(int i=t;i<128*32;i+=256){ int c=i>>5, nn=i&31; int n=n0+nn;
      tile[c][nn] = (n<NQ)? iqf[((size_t)b*CC + c)*NQ + n] : 0.f; }
    __syncthreads();
    for(int i=t;i<32*128;i+=256){ int nn=i>>7, c=i&127;
      int n=n0+nn; if(n<NQ) x[((size_t)b*NQ+n)*128 + c] = tile[c][nn]; }
  } else {
    __shared__ float hid[4][128];
    int row0 = (bid - (BB+32+76))*4;
    int r = t>>7, d = t&127;
    #pragma unroll
    for(int rr=r; rr<4; rr+=2){
      int row = row0 + rr;
      float p0 = pos[row*2+0], p1 = pos[row*2+1];
      hid[rr][d] = fmaxf(p0*w1[d] + p1*w1[128+d] + b1[d], 0.f);
    }
    __syncthreads();
    #pragma unroll
    for(int rr=r; rr<4; rr+=2){
      float acc = b2[d];
      #pragma unroll 4
      for(int c=0;c<128;c++) acc += hid[rr][c]*w2[c*128 + d];
      qpe[(size_t)(row0+rr)*128+d] = acc;
    }
  }
}

// ---------------- kvpe via MFMA: hid MLP -> GEMM1 (cw2t) -> GEMM2 (wt) ----------------
__global__ void __launch_bounds__(256) k_kvpe2(
    const float* __restrict__ kpos,
    const float* __restrict__ cw1, const float* __restrict__ cb1,
    const unsigned short* __restrict__ cw2t, const float* __restrict__ cb2,
    const unsigned short* __restrict__ wt, const float* __restrict__ vb,
    unsigned short* __restrict__ kvpe){
  __shared__ unsigned short h_t[64][136];
  __shared__ unsigned short k_t[64][136];
  int t = threadIdx.x;
  int r0 = blockIdx.x*64;
  int lane = t&63, wave = t>>6;
  int fr = lane&15, kg = lane>>4;

  int p = t & 63;
  int d0 = p*2;
  float w1a0 = cw1[d0],     w1a1 = cw1[d0+1];
  float w1b0 = cw1[128+d0], w1b1 = cw1[128+d0+1];
  float b10 = cb1[d0], b11 = cb1[d0+1];
  #pragma unroll 4
  for(int k=0;k<16;k++){
    int r = wave + k*4;
    int row = r0 + r;
    float p0=0.f, p1=0.f;
    if(row < LTOT){ p0 = kpos[row*2]; p1 = kpos[row*2+1]; }
    float h0 = fmaxf(p0*w1a0 + p1*w1b0 + b10, 0.f);
    float h1 = fmaxf(p0*w1a1 + p1*w1b1 + b11, 0.f);
    *reinterpret_cast<unsigned*>(&h_t[r][d0]) = (unsigned)f2bf(h0) | ((unsigned)f2bf(h1)<<16);
  }
  __syncthreads();

  f32x4 acc[4][2];
  #pragma unroll
  for(int i=0;i<4;i++)
    #pragma unroll
    for(int j=0;j<2;j++) acc[i][j] = (f32x4)0.f;
  #pragma unroll
  for(int ck=0; ck<4; ck++){
    int c0 = ck*32;
    bf16x8 bfr[2], af[4];
    #pragma unroll
    for(int j=0;j<2;j++){ int d = wave*32 + j*16 + fr;
      bfr[j] = *reinterpret_cast<const bf16x8*>(cw2t + (size_t)d*128 + c0 + kg*8); }
    #pragma unroll
    for(int i=0;i<4;i++) af[i] = *reinterpret_cast<const bf16x8*>(&h_t[i*16 + fr][c0 + kg*8]);
    #pragma unroll
    for(int i=0;i<4;i++)
      #pragma unroll
      for(int j=0;j<2;j++)
        acc[i][j] = __builtin_amdgcn_mfma_f32_16x16x32_bf16(af[i], bfr[j], acc[i][j], 0, 0, 0);
  }
  #pragma unroll
  for(int i=0;i<4;i++){
    int rbase = i*16 + kg*4;
    #pragma unroll
    for(int j=0;j<2;j++){
      int d = wave*32 + j*16 + fr;
      float bv_ = cb2[d];
      #pragma unroll
      for(int r=0;r<4;r++) k_t[rbase + r][d] = f2bf(acc[i][j][r] + bv_);
    }
  }
  __syncthreads();

  #pragma unroll
  for(int i=0;i<4;i++)
    #pragma unroll
    for(int j=0;j<2;j++) acc[i][j] = (f32x4)0.f;
  #pragma unroll
  for(int ck=0; ck<4; ck++){
    int c0 = ck*32;
    bf16x8 bfr[2], af[4];
    #pragma unroll
    for(int j=0;j<2;j++){ int d = wave*32 + j*16 + fr;
      bfr[j] = *reinterpret_cast<const bf16x8*>(wt + (size_t)d*128 + c0 + kg*8); }
    #pragma unroll
    for(int i=0;i<4;i++) af[i] = *reinterpret_cast<const bf16x8*>(&k_t[i*16 + fr][c0 + kg*8]);
    #pragma unroll
    for(int i=0;i<4;i++)
      #pragma unroll
      for(int j=0;j<2;j++)
        acc[i][j] = __builtin_amdgcn_mfma_f32_16x16x32_bf16(af[i], bfr[j], acc[i][j], 0, 0, 0);
  }
  __syncthreads();
  unsigned short (*c_l)[136] = h_t;
  #pragma unroll
  for(int i=0;i<4;i++){
    int rbase = i*16 + kg*4;
    #pragma unroll
    for(int j=0;j<2;j++){
      int d = wave*32 + j*16 + fr;
      float bv_ = vb[d];
      #pragma unroll
      for(int r=0;r<4;r++) c_l[rbase + r][d] = f2bf(acc[i][j][r] + bv_);
    }
  }
  __syncthreads();
  #pragma unroll
  for(int p4=0;p4<4;p4++){
    int i = t + p4*256;
    int row = i>>4, seg = i&15;
    int glr = r0 + row;
    if(glr < LTOT){
      uint4 cu = *reinterpret_cast<const uint4*>(&c_l[row][seg*8]);
      *reinterpret_cast<uint4*>(kvpe + (size_t)glr*CC + seg*8) = cu;
    }
  }
}

// ---------------- merged: qkv matvec (blocks 0..299) + value GEMM (blocks 300..5891) ----------------
#define QKVB 300
__global__ void __launch_bounds__(256) k_value_qkv(
    const float* __restrict__ f0, const float* __restrict__ f1,
    const float* __restrict__ f2, const float* __restrict__ f3,
    const unsigned short* __restrict__ kvpe, const unsigned short* __restrict__ wt,
    unsigned short* __restrict__ value,
    const float* __restrict__ x, const float* __restrict__ qpe,
    const float* __restrict__ sa_wqkv, const float* __restrict__ sa_bqkv,
    float* __restrict__ qkv){
  __shared__ unsigned short a_t[64][136];
  __shared__ float s_q[8][128];
  int t = threadIdx.x;
  int bid = blockIdx.x;
  if(bid < QKVB){
    int r0 = bid*8;
    for(int i=t;i<1024;i+=256){ int r=i>>7, c=i&127;
      size_t row = (size_t)(r0+r);
      s_q[r][c] = x[row*128+c] + qpe[row*128+c]; }
    __syncthreads();
    for(int d=t; d<384; d+=256){
      float acc[8];
      #pragma unroll
      for(int r=0;r<8;r++) acc[r]=sa_bqkv[d];
      #pragma unroll 4
      for(int c=0;c<128;c++){ float wv = sa_wqkv[c*384+d];
        #pragma unroll
        for(int r=0;r<8;r++) acc[r] += s_q[r][c]*wv; }
      #pragma unroll
      for(int r=0;r<8;r++) qkv[(size_t)(r0+r)*384+d]=acc[r];
    }
    return;
  }
  int bxy = bid - QKVB;
  int bv = bxy % 12;
  int bx = bxy / 12;
  int lvl, tile;
  if(bx < 350){ lvl=0; tile=bx; }
  else if(bx < 438){ lvl=1; tile=bx-350; }
  else if(bx < 460){ lvl=2; tile=bx-438; }
  else { lvl=3; tile=bx-460; }
  const int HW = (lvl==0)?22400:(lvl==1)?5600:(lvl==2)?1400:350;
  const int startL = (lvl==0)?0:(lvl==1)?22400:(lvl==2)?28000:29400;
  const float* feat = (lvl==0)?f0:(lvl==1)?f1:(lvl==2)?f2:f3;
  const float* fbase = feat + (size_t)bv*128*(size_t)HW;
  int l0 = tile*64;

  int lane = t&63, wave = t>>6;
  int fr = lane&15, kg = lane>>4;

  int l_u = t & 63, oct0 = t>>6;
  int gl = l0 + l_u; bool ok = (gl < HW);
  const float* fcol = fbase + (size_t)(oct0*8)*HW + (ok ? gl : 0);

  float v32[4][8];
  #pragma unroll
  for(int q=0;q<4;q++)
    #pragma unroll
    for(int j=0;j<8;j++)
      v32[q][j] = ok ? fcol[(size_t)(q*32+j)*HW] : 0.f;

  #pragma unroll
  for(int q=0;q<4;q++){
    uint4 u;
    u.x = (unsigned)f2bf(v32[q][0]) | ((unsigned)f2bf(v32[q][1])<<16);
    u.y = (unsigned)f2bf(v32[q][2]) | ((unsigned)f2bf(v32[q][3])<<16);
    u.z = (unsigned)f2bf(v32[q][4]) | ((unsigned)f2bf(v32[q][5])<<16);
    u.w = (unsigned)f2bf(v32[q][6]) | ((unsigned)f2bf(v32[q][7])<<16);
    *reinterpret_cast<uint4*>(&a_t[l_u][oct0*8 + q*32]) = u;
  }
  __syncthreads();

  f32x4 acc[4][2];
  #pragma unroll
  for(int i=0;i<4;i++)
    #pragma unroll
    for(int j=0;j<2;j++) acc[i][j] = (f32x4)0.f;

  #pragma unroll
  for(int ck=0; ck<4; ck++){
    int c0 = ck*32;
    bf16x8 bfr[2];
    #pragma unroll
    for(int j=0;j<2;j++){
      int d = wave*32 + j*16 + fr;
      bfr[j] = *reinterpret_cast<const bf16x8*>(wt + (size_t)d*128 + c0 + kg*8);
    }
    bf16x8 af[4];
    #pragma unroll
    for(int i=0;i<4;i++) af[i] = *reinterpret_cast<const bf16x8*>(&a_t[i*16 + fr][c0 + kg*8]);
    #pragma unroll
    for(int i=0;i<4;i++)
      #pragma unroll
      for(int j=0;j<2;j++)
        acc[i][j] = __builtin_amdgcn_mfma_f32_16x16x32_bf16(af[i], bfr[j], acc[i][j], 0, 0, 0);
  }

  __syncthreads();
  unsigned short (*c_l)[136] = a_t;
  #pragma unroll
  for(int i=0;i<4;i++){
    int rbase = i*16 + kg*4;
    #pragma unroll
    for(int j=0;j<2;j++){
      int d = wave*32 + j*16 + fr;
      #pragma unroll
      for(int r=0;r<4;r++) c_l[rbase + r][d] = f2bf(acc[i][j][r]);
    }
  }
  __syncthreads();
  #pragma unroll
  for(int p=0;p<4;p++){
    int i = t + p*256;
    int row = i>>4, seg = i&15;
    int glr = l0 + row;
    if(glr < HW){
      uint4 cu = *reinterpret_cast<const uint4*>(&c_l[row][seg*8]);
      const uint4 ku = *reinterpret_cast<const uint4*>(kvpe + (size_t)(startL+glr)*CC + seg*8);
      uint4 ou;
      ou.x = addbf2(cu.x, ku.x); ou.y = addbf2(cu.y, ku.y);
      ou.z = addbf2(cu.z, ku.z); ou.w = addbf2(cu.w, ku.w);
      *reinterpret_cast<uint4*>(value + ((size_t)bv*LTOT + startL + glr)*CC + seg*8) = ou;
    }
  }
}

// ---------------- bucketed self-attention ----------------
#define QT2 64
#define KT2 128
__global__ void __launch_bounds__(256) k_attn_v(const float* __restrict__ qkv,
        const int* __restrict__ order, const int* __restrict__ counts,
        float* __restrict__ att){
  int qt = blockIdx.x;
  int vh = blockIdx.y; int v = vh>>3, h = vh&7;
  int b = blockIdx.z;
  int C = counts[b*VV+v];
  int q0 = qt*QT2;
  if(q0 >= C) return;
  const int* ord = order + (size_t)(b*VV+v)*NQ;
  int t = threadIdx.x;
  __shared__ float q_s[QT2][17];
  __shared__ int qn_s[QT2];
  __shared__ float k_s[KT2][16];
  __shared__ float v_s[KT2][16];
  __shared__ float red[4][QT2][18];
  for(int i=t;i<QT2;i+=256){ int qi=q0+i; qn_s[i] = (qi<C)? ord[qi] : -1; }
  __syncthreads();
  for(int i=t;i<QT2*16;i+=256){ int r=i>>4,c=i&15; int n=qn_s[r];
    q_s[r][c] = (n>=0)? qkv[((size_t)b*NQ+n)*384 + h*16 + c] : 0.f; }
  int qi = t&63, sub = t>>6;
  float m = -1e30f, s = 0.f, acc[16];
  #pragma unroll
  for(int c=0;c<16;c++) acc[c]=0.f;
  for(int k0=0; k0<C; k0+=KT2){
    int kn = C-k0; if(kn>KT2) kn=KT2;
    __syncthreads();
    for(int i=t;i<KT2*16;i+=256){ int r=i>>4,c=i&15;
      float kv=0.f, vv=0.f;
      if(r<kn){ int n=ord[k0+r]; size_t base=((size_t)b*NQ+n)*384 + h*16 + c;
        kv = qkv[base+128]; vv = qkv[base+256]; }
      k_s[r][c]=kv; v_s[r][c]=vv; }
    __syncthreads();
    for(int mm=sub; mm<kn; mm+=4){
      float l=0.f;
      #pragma unroll
      for(int c=0;c<16;c++) l += q_s[qi][c]*k_s[mm][c];
      l *= 0.25f;
      float newm = fmaxf(m,l);
      float e = __expf(l - newm);
      if(newm > m){
        float rr = __expf(m - newm);
        s *= rr;
        #pragma unroll
        for(int c=0;c<16;c++) acc[c]*=rr;
        m = newm;
      }
      s += e;
      #pragma unroll
      for(int c=0;c<16;c++) acc[c] += e*v_s[mm][c];
    }
  }
  red[sub][qi][0]=m; red[sub][qi][1]=s;
  #pragma unroll
  for(int c=0;c<16;c++) red[sub][qi][2+c]=acc[c];
  __syncthreads();
  if(sub==0){
    int n = qn_s[qi];
    if(n>=0){
      float M=-1e30f;
      #pragma unroll
      for(int j=0;j<4;j++) M=fmaxf(M,red[j][qi][0]);
      float S=0.f; float o[16];
      #pragma unroll
      for(int c=0;c<16;c++) o[c]=0.f;
      #pragma unroll
      for(int j=0;j<4;j++){ float e=__expf(red[j][qi][0]-M); S += e*red[j][qi][1];
        #pragma unroll
        for(int c=0;c<16;c++) o[c] += e*red[j][qi][2+c]; }
      float inv = 1.f/S;
      #pragma unroll
      for(int c=0;c<16;c++) att[((size_t)b*NQ+n)*128 + h*16 + c] = o[c]*inv;
    }
  }
}

// ---------------- fused: proj+LN1 -> qc (LDS) -> offset matvec + attn-weight softmax ----------------
__global__ void __launch_bounds__(384) k_q2(
    const float* __restrict__ att, const float* __restrict__ sa_wo, const float* __restrict__ sa_bo,
    float* __restrict__ x, const float* __restrict__ ln1_g, const float* __restrict__ ln1_b,
    const float* __restrict__ qpe,
    const float* __restrict__ dow, const float* __restrict__ dob,
    const float* __restrict__ daw, const float* __restrict__ dab,
    float* __restrict__ offb, float* __restrict__ awb){
  int r0 = blockIdx.x*8; int t = threadIdx.x; // 384 threads
  __shared__ float s_att[8][128];
  __shared__ float s_qc[8][128];
  __shared__ float s_m[8][2][2];
  __shared__ float s_aw[8][130];
  for(int i=t;i<1024;i+=384){ int r=i>>7, c=i&127; s_att[r][c]=att[(size_t)(r0+r)*128+c]; }
  __syncthreads();
  int lane = t&63, wid = (t>>6)&1;
  float v[8];
  if(t < 128){
    int d = t;
    float acc[8];
    #pragma unroll
    for(int r=0;r<8;r++) acc[r]=sa_bo[d];
    #pragma unroll 4
    for(int c=0;c<128;c++){ float wv = sa_wo[c*128+d];
      #pragma unroll
      for(int r=0;r<8;r++) acc[r] += s_att[r][c]*wv; }
    #pragma unroll
    for(int r=0;r<8;r++){
      v[r] = acc[r] + x[(size_t)(r0+r)*128 + d];
      float s1=v[r], s2=v[r]*v[r];
      for(int o=32;o>0;o>>=1){ s1 += __shfl_down(s1,o); s2 += __shfl_down(s2,o); }
      if(lane==0){ s_m[r][wid][0]=s1; s_m[r][wid][1]=s2; }
    }
  }
  __syncthreads();
  if(t < 128){
    int d = t;
    #pragma unroll
    for(int r=0;r<8;r++){
      float S1=s_m[r][0][0]+s_m[r][1][0], S2=s_m[r][0][1]+s_m[r][1][1];
      float mean=S1*(1.f/128.f), var=S2*(1.f/128.f)-mean*mean;
      float rs=rsqrtf(var+1e-5f);
      float o=(v[r]-mean)*rs*ln1_g[d]+ln1_b[d];
      x[(size_t)(r0+r)*128+d]=o;
      s_qc[r][d]=o+qpe[(size_t)(r0+r)*128+d];
    }
  }
  __syncthreads();
  if(t < 256){
    int d = t;
    float acc[8];
    #pragma unroll
    for(int r=0;r<8;r++) acc[r]=dob[d];
    #pragma unroll 4
    for(int c=0;c<128;c++){ float wv = dow[(size_t)c*256+d];
      #pragma unroll
      for(int r=0;r<8;r++) acc[r] += s_qc[r][c]*wv; }
    #pragma unroll
    for(int r=0;r<8;r++) offb[(size_t)(r0+r)*256+d]=acc[r];
  } else {
    int d = t - 256;
    float acc[8];
    #pragma unroll
    for(int r=0;r<8;r++) acc[r]=dab[d];
    #pragma unroll 4
    for(int c=0;c<128;c++){ float wv = daw[(size_t)c*128+d];
      #pragma unroll
      for(int r=0;r<8;r++) acc[r] += s_qc[r][c]*wv; }
    #pragma unroll
    for(int r=0;r<8;r++) s_aw[r][d]=acc[r];
  }
  __syncthreads();
  if(t < 64){
    int r = t>>3, h = t&7;
    float mx=-1e30f;
    #pragma unroll
    for(int i=0;i<16;i++) mx = fmaxf(mx, s_aw[r][h*16+i]);
    float e[16]; float sm=0.f;
    #pragma unroll
    for(int i=0;i<16;i++){ e[i]=__expf(s_aw[r][h*16+i]-mx); sm+=e[i]; }
    float inv = 1.f/sm;
    #pragma unroll
    for(int i=0;i<16;i++) awb[(size_t)(r0+r)*128 + h*16+i] = e[i]*inv;
  }
}

// ---------------- fused tail: bilinear sample + proj_ln2 + FFN1 + FFN2/LN3 + head ----------------
__global__ void __launch_bounds__(128) k_tail2(
    const float* __restrict__ qpos, const int* __restrict__ view,
    const float* __restrict__ offb, const float* __restrict__ awb,
    const unsigned short* __restrict__ value,
    const float* __restrict__ dOw, const float* __restrict__ dOb,
    const float* __restrict__ xres,
    const float* __restrict__ ln2_g, const float* __restrict__ ln2_b,
    const float* __restrict__ fw1, const float* __restrict__ fb1,
    const float* __restrict__ fw2, const float* __restrict__ fb2,
    const float* __restrict__ ln3_g, const float* __restrict__ ln3_b,
    const float* __restrict__ pw1, const float* __restrict__ pb1,
    const float* __restrict__ pw2, const float* __restrict__ pb2,
    const int* __restrict__ counts, float* __restrict__ dout){
  int r0 = blockIdx.x*4; int d = threadIdx.x;  // 128 threads
  __shared__ float s_a[4][256];
  __shared__ float s_x[4][128];
  __shared__ float s_m[4][2][2];
  __shared__ float s_res[4][6];
  __shared__ float sred[128][17];
  __shared__ float s_ca[4][128];
  int lane = d&63, wid = d>>6;

  int h = d>>4, lp = d&15, lvl = lp>>2;
  int w = c_W[lvl], hh = c_H[lvl];
  float samp[4][16]; float aw4[4];
  int vw4[4];
  #pragma unroll
  for(int r=0;r<4;r++){
    size_t row = (size_t)(r0+r);
    int b = (r0+r)/NQ;
    float rx = sigm(qpos[row*2]), ry = sigm(qpos[row*2+1]);
    int vw = view[row]; vw4[r]=vw;
    float ox = offb[row*256 + d*2], oy = offb[row*256 + d*2+1];
    aw4[r] = awb[row*128 + d];
    float lx = rx*(float)w + ox - 0.5f;
    float ly = ry*(float)hh + oy - 0.5f;
    float x0f = floorf(lx), y0f = floorf(ly);
    float fx = lx - x0f, fy = ly - y0f;
    int x0 = (int)x0f, y0 = (int)y0f;
    #pragma unroll
    for(int c=0;c<16;c++) samp[r][c]=0.f;
    size_t brow = ((size_t)(b*VV + vw))*LTOT + c_S[lvl];
    #pragma unroll
    for(int dy=0;dy<2;dy++){
      #pragma unroll
      for(int dx=0;dx<2;dx++){
        int xi=x0+dx, yi=y0+dy;
        if(xi<0||xi>=w||yi<0||yi>=hh) continue;
        float wt = (dx?fx:(1.f-fx))*(dy?fy:(1.f-fy));
        const uint4* vp = reinterpret_cast<const uint4*>(value + (brow + (size_t)yi*w + xi)*CC + h*16);
        uint4 u0 = vp[0], u1 = vp[1];
        samp[r][0] += wt*bflo(u0.x); samp[r][1] += wt*bfhi(u0.x);
        samp[r][2] += wt*bflo(u0.y); samp[r][3] += wt*bfhi(u0.y);
        samp[r][4] += wt*bflo(u0.z); samp[r][5] += wt*bfhi(u0.z);
        samp[r][6] += wt*bflo(u0.w); samp[r][7] += wt*bfhi(u0.w);
        samp[r][8] += wt*bflo(u1.x); samp[r][9] += wt*bfhi(u1.x);
        samp[r][10]+= wt*bflo(u1.y); samp[r][11]+= wt*bfhi(u1.y);
        samp[r][12]+= wt*bflo(u1.z); samp[r][13]+= wt*bfhi(u1.z);
        samp[r][14]+= wt*bflo(u1.w); samp[r][15]+= wt*bfhi(u1.w);
      }
    }
  }
  #pragma unroll
  for(int r=0;r<4;r++){
    #pragma unroll
    for(int c=0;c<16;c++) sred[d][c] = aw4[r]*samp[r][c];
    __syncthreads();
    int h2=d>>4, c2=d&15;
    float sum=0.f;
    #pragma unroll
    for(int j=0;j<16;j++) sum += sred[h2*16+j][c2];
    s_ca[r][d] = sum;
    __syncthreads();
  }

  #pragma unroll
  for(int r=0;r<4;r++) s_a[r][d] = s_ca[r][d];
  __syncthreads();
  float acc[4];
  #pragma unroll
  for(int r=0;r<4;r++) acc[r]=dOb[d];
  #pragma unroll 4
  for(int c=0;c<128;c++){ float wv = dOw[c*128+d];
    #pragma unroll
    for(int r=0;r<4;r++) acc[r] += s_a[r][c]*wv; }
  float v[4];
  #pragma unroll
  for(int r=0;r<4;r++){
    v[r] = acc[r] + xres[(size_t)(r0+r)*128 + d];
    float s1=v[r], s2=v[r]*v[r];
    for(int o=32;o>0;o>>=1){ s1 += __shfl_down(s1,o); s2 += __shfl_down(s2,o); }
    if(lane==0){ s_m[r][wid][0]=s1; s_m[r][wid][1]=s2; }
  }
  __syncthreads();
  #pragma unroll
  for(int r=0;r<4;r++){
    float S1=s_m[r][0][0]+s_m[r][1][0], S2=s_m[r][0][1]+s_m[r][1][1];
    float mean=S1*(1.f/128.f), var=S2*(1.f/128.f)-mean*mean;
    float rs=rsqrtf(var+1e-5f);
    s_x[r][d]=(v[r]-mean)*rs*ln2_g[d]+ln2_b[d];
  }
  __syncthreads();

  float a2a[4], a2b[4];
  #pragma unroll
  for(int r=0;r<4;r++){ a2a[r]=fb1[d]; a2b[r]=fb1[d+128]; }
  #pragma unroll 4
  for(int c=0;c<128;c++){ float w0 = fw1[c*256+d], w1_ = fw1[c*256+d+128];
    #pragma unroll
    for(int r=0;r<4;r++){ float xv = s_x[r][c]; a2a[r] += xv*w0; a2b[r] += xv*w1_; } }
  __syncthreads();
  #pragma unroll
  for(int r=0;r<4;r++){ s_a[r][d]=fmaxf(a2a[r],0.f); s_a[r][d+128]=fmaxf(a2b[r],0.f); }
  __syncthreads();

  float a3[4];
  #pragma unroll
  for(int r=0;r<4;r++) a3[r]=fb2[d];
  #pragma unroll 4
  for(int c=0;c<256;c++){ float wv = fw2[c*128+d];
    #pragma unroll
    for(int r=0;r<4;r++) a3[r] += s_a[r][c]*wv; }
  #pragma unroll
  for(int r=0;r<4;r++){
    v[r] = a3[r] + s_x[r][d];
    float s1=v[r], s2=v[r]*v[r];
    for(int o=32;o>0;o>>=1){ s1 += __shfl_down(s1,o); s2 += __shfl_down(s2,o); }
    if(lane==0){ s_m[r][wid][0]=s1; s_m[r][wid][1]=s2; }
  }
  __syncthreads();
  #pragma unroll
  for(int r=0;r<4;r++){
    float S1=s_m[r][0][0]+s_m[r][1][0], S2=s_m[r][0][1]+s_m[r][1][1];
    float mean=S1*(1.f/128.f), var=S2*(1.f/128.f)-mean*mean;
    float rs=rsqrtf(var+1e-5f);
    float o=(v[r]-mean)*rs*ln3_g[d]+ln3_b[d];
    int row=r0+r; int b=row/NQ, n=row%NQ;
    bool val = counts[b*VV + vw4[r]] > 1;
    float oz = val ? o : 0.f;
    s_x[r][d]=oz;
    dout[((size_t)b*CC + d)*NQ + n]=oz;
  }
  __syncthreads();

  float a4[4];
  #pragma unroll
  for(int r=0;r<4;r++) a4[r]=pb1[d];
  #pragma unroll 4
  for(int c=0;c<128;c++){ float wv = pw1[c*128+d];
    #pragma unroll
    for(int r=0;r<4;r++) a4[r] += s_x[r][c]*wv; }
  #pragma unroll
  for(int r=0;r<4;r++) s_a[r][d]=fmaxf(a4[r],0.f);
  __syncthreads();

  if(d < 24){
    int r = d/6, o = d%6;
    float a5 = pb2[o];
    #pragma unroll 4
    for(int c=0;c<128;c++) a5 += s_a[r][c]*pw2[c*6+o];
    s_res[r][o] = a5;
  }
  __syncthreads();
  if(d < 4){
    int r = d; int row = r0+r; int b=row/NQ, n=row%NQ;
    const int O1 = BB*CC*NQ;
    const int O2 = O1 + BB*NQ*2;
    const int O3 = O2 + BB*2*NQ;
    const int O4 = O3 + BB*4*NQ;
    float p0=qpos[row*2], p1=qpos[row*2+1];
    float cr0 = s_res[r][0]+p0, cr1 = s_res[r][1]+p1;
    dout[O1 + row*2]   = cr0;
    dout[O1 + row*2+1] = cr1;
    float cen0 = sigm(cr0), cen1 = sigm(cr1);
    dout[O2 + (b*2+0)*NQ + n] = cen0;
    dout[O2 + (b*2+1)*NQ + n] = cen1;
    float f0=sigm(s_res[r][2]), f1=sigm(s_res[r][3]), f2=sigm(s_res[r][4]), f3=sigm(s_res[r][5]);
    dout[O3 + (b*4+0)*NQ + n] = f0;
    dout[O3 + (b*4+1)*NQ + n] = f1;
    dout[O3 + (b*4+2)*NQ + n] = f2;
    dout[O3 + (b*4+3)*NQ + n] = f3;
    float bw=f0+f2, bh=f1+f3;
    float cx=(2.f*cen0 - f0 + f2)*0.5f;
    float cy=(2.f*cen1 - f1 + f3)*0.5f;
    dout[O4 + (b*4+0)*NQ + n] = cx;
    dout[O4 + (b*4+1)*NQ + n] = cy;
    dout[O4 + (b*4+2)*NQ + n] = bw;
    dout[O4 + (b*4+3)*NQ + n] = bh;
  }
}

extern "C" void kernel_launch(void* const* d_in, const int* in_sizes, int n_in,
                              void* d_out, int out_size, void* d_ws, size_t ws_size,
                              hipStream_t stream){
  (void)in_sizes; (void)n_in; (void)out_size; (void)ws_size;
  const float* in_iqf  = (const float*)d_in[0];
  const float* in_qpos = (const float*)d_in[1];
  const float* in_feat[4] = {(const float*)d_in[2],(const float*)d_in[3],(const float*)d_in[4],(const float*)d_in[5]};
  const float* in_kpos = (const float*)d_in[6];
  const float* sp_w1=(const float*)d_in[7], *sp_b1=(const float*)d_in[8], *sp_w2=(const float*)d_in[9], *sp_b2=(const float*)d_in[10];
  const float* cp_w1=(const float*)d_in[11], *cp_b1=(const float*)d_in[12], *cp_w2=(const float*)d_in[13], *cp_b2=(const float*)d_in[14];
  const float* sa_wqkv=(const float*)d_in[15], *sa_bqkv=(const float*)d_in[16], *sa_wo=(const float*)d_in[17], *sa_bo=(const float*)d_in[18];
  const float* ln1_g=(const float*)d_in[19], *ln1_b=(const float*)d_in[20];
  const float* dvw=(const float*)d_in[21], *dvb=(const float*)d_in[22];
  const float* dow=(const float*)d_in[23], *dob=(const float*)d_in[24];
  const float* daw=(const float*)d_in[25], *dab=(const float*)d_in[26];
  const float* dOw=(const float*)d_in[27], *dOb=(const float*)d_in[28];
  const float* ln2_g=(const float*)d_in[29], *ln2_b=(const float*)d_in[30];
  const float* fw1=(const float*)d_in[31], *fb1=(const float*)d_in[32], *fw2=(const float*)d_in[33], *fb2=(const float*)d_in[34];
  const float* ln3_g=(const float*)d_in[35], *ln3_b=(const float*)d_in[36];
  const float* pw1=(const float*)d_in[37], *pb1=(const float*)d_in[38], *pw2=(const float*)d_in[39], *pb2=(const float*)d_in[40];
  const int* in_view = (const int*)d_in[41];
  float* out = (float*)d_out;

  char* ws = (char*)d_ws;
  unsigned short* value = (unsigned short*)ws;                       // 91,392,000 B
  unsigned short* kvpe  = (unsigned short*)(ws + 91392000);          //  7,616,000 B
  float* f = (float*)(ws + 91392000 + 7616000);
  float* qpe  = f;               // 307200
  float* x    = f + 307200;      // 307200
  float* qkv  = f + 614400;      // 921600
  float* att  = f + 1536000;     // 307200
  float* offb = f + 2150400;     // 614400
  float* awb  = f + 2764800;     // 307200
  int* counts = (int*)(f + 4300800);   // 12 ints
  int* order  = (int*)(f + 4300816);   // B*VV*NQ = 14400 ints
  unsigned short* wtb   = (unsigned short*)(f + 4315216);  // 32768 B
  unsigned short* cw2tb = (unsigned short*)(f + 4323408);  // 32768 B

  k_misc<<<dim3(BB+32+76+600),dim3(256),0,stream>>>(in_view,order,counts,dvw,wtb,
      cp_w2,cw2tb,in_iqf,x,in_qpos,sp_w1,sp_b1,sp_w2,sp_b2,qpe);
  k_kvpe2<<<dim3((LTOT+63)/64),dim3(256),0,stream>>>(in_kpos,cp_w1,cp_b1,cw2tb,cp_b2,wtb,dvb,kvpe);
  k_value_qkv<<<dim3(QKVB + 466*12),dim3(256),0,stream>>>(in_feat[0],in_feat[1],in_feat[2],in_feat[3],
      kvpe,wtb,value,x,qpe,sa_wqkv,sa_bqkv,qkv);
  k_attn_v<<<dim3((NQ+QT2-1)/QT2, VV*HH, BB),dim3(256),0,stream>>>(qkv,order,counts,att);
  k_q2<<<dim3(NROWS/8),dim3(384),0,stream>>>(att,sa_wo,sa_bo,x,ln1_g,ln1_b,qpe,
      dow,dob,daw,dab,offb,awb);
  k_tail2<<<dim3(NROWS/4),dim3(128),0,stream>>>(in_qpos,in_view,offb,awb,value,
      dOw,dOb,x,ln2_g,ln2_b,fw1,fb1,fw2,fb2,ln3_g,ln3_b,pw1,pb1,pw2,pb2,counts,out);
}

// Round 13
// 212.069 us; speedup vs baseline: 1.8402x; 1.0800x over previous
//
#include <hip/hip_runtime.h>
#include <hip/hip_bf16.h>
#include <math.h>

#define DEV __device__ __forceinline__

#define BB 2
#define VV 6
#define CC 128
#define NQ 1200
#define HH 8
#define PTSN 4
#define FFND 256
#define LVLSN 4
#define LTOT 29750
#define NROWS (BB*NQ)

__constant__ int c_W[4] = {200,100,50,25};
__constant__ int c_H[4] = {112,56,28,14};
__constant__ int c_S[4] = {0,22400,28000,29400};

DEV float bflo(unsigned u){ union{unsigned i; float f;}x; x.i = u<<16; return x.f; }
DEV float bfhi(unsigned u){ union{unsigned i; float f;}x; x.i = u&0xffff0000u; return x.f; }
DEV unsigned short f2bf(float f){ union{float f; unsigned i;}x; x.f=f; unsigned i=x.i;
  return (unsigned short)((i + 0x7fffu + ((i>>16)&1u))>>16); }
DEV unsigned addbf2(unsigned a, unsigned b){
  float lo = bflo(a)+bflo(b); float hi = bfhi(a)+bfhi(b);
  return (unsigned)f2bf(lo) | ((unsigned)f2bf(hi)<<16);
}
DEV float sigm(float z){ return 1.f/(1.f+__expf(-z)); }

typedef __attribute__((ext_vector_type(8))) short bf16x8;
typedef __attribute__((ext_vector_type(4))) float f32x4;

// ---------------- fused setup: bucket(2) + wt(16) + cw2t(16) + xpose(76) + qpe(600) ----------------
__global__ void k_misc(const int* __restrict__ view, int* __restrict__ order,
                       int* __restrict__ counts,
                       const float* __restrict__ vw, unsigned short* __restrict__ wt,
                       const float* __restrict__ cw2, unsigned short* __restrict__ cw2t,
                       const float* __restrict__ iqf, float* __restrict__ x,
                       const float* __restrict__ pos,
                       const float* __restrict__ w1, const float* __restrict__ b1,
                       const float* __restrict__ w2, const float* __restrict__ b2,
                       float* __restrict__ qpe){
  int bid = blockIdx.x;
  int t = threadIdx.x;
  if(bid < BB){
    if(t < 64){
      int b = bid; int lane = t;
      int base0=0,base1=0,base2=0,base3=0,base4=0,base5=0;
      for(int c0=0;c0<NQ;c0+=64){
        int n = c0 + lane;
        int v = (n<NQ) ? view[b*NQ+n] : -1;
        unsigned long long lower = (lane==63)? 0x7fffffffffffffffull : ((1ull<<lane)-1ull);
        #define BUCKET_STEP(VVV, BASE) { \
          unsigned long long mk = __ballot(v==VVV); \
          if(v==VVV){ int r = BASE + __popcll(mk & lower); order[(b*VV+VVV)*NQ + r] = n; } \
          BASE += __popcll(mk); }
        BUCKET_STEP(0, base0) BUCKET_STEP(1, base1) BUCKET_STEP(2, base2)
        BUCKET_STEP(3, base3) BUCKET_STEP(4, base4) BUCKET_STEP(5, base5)
        #undef BUCKET_STEP
      }
      if(lane==0){
        counts[b*VV+0]=base0; counts[b*VV+1]=base1; counts[b*VV+2]=base2;
        counts[b*VV+3]=base3; counts[b*VV+4]=base4; counts[b*VV+5]=base5;
      }
    }
  } else if(bid < BB+16){
    int d0 = (bid-BB)*8;
    __shared__ float s[128][9];
    #pragma unroll
    for(int p=0;p<4;p++){ int i = t + p*256; int c = i>>3, dd = i&7;
      s[c][dd] = vw[c*128 + d0 + dd]; }
    __syncthreads();
    #pragma unroll
    for(int p=0;p<4;p++){ int i = t + p*256; int dd = i>>7, c = i&127;
      wt[(size_t)(d0+dd)*128 + c] = f2bf(s[c][dd]); }
  } else if(bid < BB+32){
    int d0 = (bid-BB-16)*8;
    __shared__ float s[128][9];
    #pragma unroll
    for(int p=0;p<4;p++){ int i = t + p*256; int c = i>>3, dd = i&7;
      s[c][dd] = cw2[c*128 + d0 + dd]; }
    __syncthreads();
    #pragma unroll
    for(int p=0;p<4;p++){ int i = t + p*256; int dd = i>>7, c = i&127;
      cw2t[(size_t)(d0+dd)*128 + c] = f2bf(s[c][dd]); }
  } else if(bid < BB+32+76){
    __shared__ float tile[128][33];
    int idx = bid - (BB+32);
    int b = idx/38; int n0 = (idx%38)*32;
    for(int i=t;i<128*32;i+=256){ int c=i>>5, nn=i&31; int n=n0+nn;
      tile[c][nn] = (n<NQ)? iqf[((size_t)b*CC + c)*NQ + n] : 0.f; }
    __syncthreads();
    for(int i=t;i<32*128;i+=256){ int nn=i>>7, c=i&127;
      int n=n0+nn; if(n<NQ) x[((size_t)b*NQ+n)*128 + c] = tile[c][nn]; }
  } else {
    __shared__ float hid[4][128];
    int row0 = (bid - (BB+32+76))*4;
    int r = t>>7, d = t&127;
    #pragma unroll
    for(int rr=r; rr<4; rr+=2){
      int row = row0 + rr;
      float p0 = pos[row*2+0], p1 = pos[row*2+1];
      hid[rr][d] = fmaxf(p0*w1[d] + p1*w1[128+d] + b1[d], 0.f);
    }
    __syncthreads();
    #pragma unroll
    for(int rr=r; rr<4; rr+=2){
      float acc = b2[d];
      #pragma unroll 4
      for(int c=0;c<128;c++) acc += hid[rr][c]*w2[c*128 + d];
      qpe[(size_t)(row0+rr)*128+d] = acc;
    }
  }
}

// ---------------- merged: kvpe MFMA (blocks 0..464) + qkv matvec (blocks 465..764) ----------------
#define NKVPE 465
__global__ void __launch_bounds__(256) k_kvpe_qkv(
    const float* __restrict__ kpos,
    const float* __restrict__ cw1, const float* __restrict__ cb1,
    const unsigned short* __restrict__ cw2t, const float* __restrict__ cb2,
    const unsigned short* __restrict__ wt, const float* __restrict__ vb,
    unsigned short* __restrict__ kvpe,
    const float* __restrict__ x, const float* __restrict__ qpe,
    const float* __restrict__ sa_wqkv, const float* __restrict__ sa_bqkv,
    float* __restrict__ qkv){
  __shared__ unsigned short h_t[64][136];
  __shared__ unsigned short k_t[64][136];
  int t = threadIdx.x;
  int bid = blockIdx.x;
  if(bid >= NKVPE){
    // ---- qkv matvec: 8 rows, out width 384 ----
    float (*s_q)[128] = (float(*)[128])h_t;  // alias (4KB < 17.4KB)
    int r0 = (bid - NKVPE)*8;
    for(int i=t;i<1024;i+=256){ int r=i>>7, c=i&127;
      size_t row = (size_t)(r0+r);
      s_q[r][c] = x[row*128+c] + qpe[row*128+c]; }
    __syncthreads();
    for(int d=t; d<384; d+=256){
      float acc[8];
      #pragma unroll
      for(int r=0;r<8;r++) acc[r]=sa_bqkv[d];
      #pragma unroll 4
      for(int c=0;c<128;c++){ float wv = sa_wqkv[c*384+d];
        #pragma unroll
        for(int r=0;r<8;r++) acc[r] += s_q[r][c]*wv; }
      #pragma unroll
      for(int r=0;r<8;r++) qkv[(size_t)(r0+r)*384+d]=acc[r];
    }
    return;
  }
  int r0 = bid*64;
  int lane = t&63, wave = t>>6;
  int fr = lane&15, kg = lane>>4;

  int p = t & 63;
  int d0 = p*2;
  float w1a0 = cw1[d0],     w1a1 = cw1[d0+1];
  float w1b0 = cw1[128+d0], w1b1 = cw1[128+d0+1];
  float b10 = cb1[d0], b11 = cb1[d0+1];
  #pragma unroll 4
  for(int k=0;k<16;k++){
    int r = wave + k*4;
    int row = r0 + r;
    float p0=0.f, p1=0.f;
    if(row < LTOT){ p0 = kpos[row*2]; p1 = kpos[row*2+1]; }
    float h0 = fmaxf(p0*w1a0 + p1*w1b0 + b10, 0.f);
    float h1 = fmaxf(p0*w1a1 + p1*w1b1 + b11, 0.f);
    *reinterpret_cast<unsigned*>(&h_t[r][d0]) = (unsigned)f2bf(h0) | ((unsigned)f2bf(h1)<<16);
  }
  __syncthreads();

  f32x4 acc[4][2];
  #pragma unroll
  for(int i=0;i<4;i++)
    #pragma unroll
    for(int j=0;j<2;j++) acc[i][j] = (f32x4)0.f;
  #pragma unroll
  for(int ck=0; ck<4; ck++){
    int c0 = ck*32;
    bf16x8 bfr[2], af[4];
    #pragma unroll
    for(int j=0;j<2;j++){ int d = wave*32 + j*16 + fr;
      bfr[j] = *reinterpret_cast<const bf16x8*>(cw2t + (size_t)d*128 + c0 + kg*8); }
    #pragma unroll
    for(int i=0;i<4;i++) af[i] = *reinterpret_cast<const bf16x8*>(&h_t[i*16 + fr][c0 + kg*8]);
    #pragma unroll
    for(int i=0;i<4;i++)
      #pragma unroll
      for(int j=0;j<2;j++)
        acc[i][j] = __builtin_amdgcn_mfma_f32_16x16x32_bf16(af[i], bfr[j], acc[i][j], 0, 0, 0);
  }
  #pragma unroll
  for(int i=0;i<4;i++){
    int rbase = i*16 + kg*4;
    #pragma unroll
    for(int j=0;j<2;j++){
      int d = wave*32 + j*16 + fr;
      float bv_ = cb2[d];
      #pragma unroll
      for(int r=0;r<4;r++) k_t[rbase + r][d] = f2bf(acc[i][j][r] + bv_);
    }
  }
  __syncthreads();

  #pragma unroll
  for(int i=0;i<4;i++)
    #pragma unroll
    for(int j=0;j<2;j++) acc[i][j] = (f32x4)0.f;
  #pragma unroll
  for(int ck=0; ck<4; ck++){
    int c0 = ck*32;
    bf16x8 bfr[2], af[4];
    #pragma unroll
    for(int j=0;j<2;j++){ int d = wave*32 + j*16 + fr;
      bfr[j] = *reinterpret_cast<const bf16x8*>(wt + (size_t)d*128 + c0 + kg*8); }
    #pragma unroll
    for(int i=0;i<4;i++) af[i] = *reinterpret_cast<const bf16x8*>(&k_t[i*16 + fr][c0 + kg*8]);
    #pragma unroll
    for(int i=0;i<4;i++)
      #pragma unroll
      for(int j=0;j<2;j++)
        acc[i][j] = __builtin_amdgcn_mfma_f32_16x16x32_bf16(af[i], bfr[j], acc[i][j], 0, 0, 0);
  }
  __syncthreads();
  unsigned short (*c_l)[136] = h_t;
  #pragma unroll
  for(int i=0;i<4;i++){
    int rbase = i*16 + kg*4;
    #pragma unroll
    for(int j=0;j<2;j++){
      int d = wave*32 + j*16 + fr;
      float bv_ = vb[d];
      #pragma unroll
      for(int r=0;r<4;r++) c_l[rbase + r][d] = f2bf(acc[i][j][r] + bv_);
    }
  }
  __syncthreads();
  #pragma unroll
  for(int p4=0;p4<4;p4++){
    int i = t + p4*256;
    int row = i>>4, seg = i&15;
    int glr = r0 + row;
    if(glr < LTOT){
      uint4 cu = *reinterpret_cast<const uint4*>(&c_l[row][seg*8]);
      *reinterpret_cast<uint4*>(kvpe + (size_t)glr*CC + seg*8) = cu;
    }
  }
}

// ---------------- merged: self-attention (blocks 0..1823, reads qkv) + value GEMM ----------------
#define NATT (19*48*2)
#define QT2 64
#define KTA 64
__global__ void __launch_bounds__(256) k_value_attn2(
    const float* __restrict__ f0, const float* __restrict__ f1,
    const float* __restrict__ f2, const float* __restrict__ f3,
    const unsigned short* __restrict__ kvpe, const unsigned short* __restrict__ wt,
    unsigned short* __restrict__ value,
    const float* __restrict__ qkv,
    const int* __restrict__ order, const int* __restrict__ counts,
    float* __restrict__ att){
  __shared__ __align__(16) char smem[18688];
  int t = threadIdx.x;
  int bid = blockIdx.x;
  if(bid < NATT){
    int qt = bid % 19;
    int vh = (bid/19) % 48;
    int b  = bid/(19*48);
    int v = vh>>3, h = vh&7;
    int C = counts[b*VV+v];
    int q0 = qt*QT2;
    if(q0 >= C) return;
    const int* ord = order + (size_t)(b*VV+v)*NQ;
    float (*q_s)[17] = (float(*)[17])smem;               // 4352
    float (*k_s)[16] = (float(*)[16])(smem + 4352);      // 4096
    float (*v_s)[16] = (float(*)[16])(smem + 8448);      // 4096
    float (*red)[QT2][18] = (float(*)[QT2][18])smem;     // 18432, aliases q/k/v
    int* qn_s = (int*)(smem + 18432);                    // 256
    for(int i=t;i<QT2;i+=256){ int qi=q0+i; qn_s[i] = (qi<C)? ord[qi] : -1; }
    __syncthreads();
    for(int i=t;i<QT2*16;i+=256){ int r=i>>4,c=i&15; int n=qn_s[r];
      q_s[r][c] = (n>=0)? qkv[((size_t)b*NQ+n)*384 + h*16 + c] : 0.f; }
    int qi = t&63, sub = t>>6;
    float m = -1e30f, s = 0.f, acc[16];
    #pragma unroll
    for(int c=0;c<16;c++) acc[c]=0.f;
    for(int k0=0; k0<C; k0+=KTA){
      int kn = C-k0; if(kn>KTA) kn=KTA;
      __syncthreads();
      for(int i=t;i<KTA*16;i+=256){ int r=i>>4,c=i&15;
        float kv=0.f, vv=0.f;
        if(r<kn){ int n=ord[k0+r]; size_t base=((size_t)b*NQ+n)*384 + h*16 + c;
          kv = qkv[base+128]; vv = qkv[base+256]; }
        k_s[r][c]=kv; v_s[r][c]=vv; }
      __syncthreads();
      for(int mm=sub; mm<kn; mm+=4){
        float l=0.f;
        #pragma unroll
        for(int c=0;c<16;c++) l += q_s[qi][c]*k_s[mm][c];
        l *= 0.25f;
        float newm = fmaxf(m,l);
        float e = __expf(l - newm);
        if(newm > m){
          float rr = __expf(m - newm);
          s *= rr;
          #pragma unroll
          for(int c=0;c<16;c++) acc[c]*=rr;
          m = newm;
        }
        s += e;
        #pragma unroll
        for(int c=0;c<16;c++) acc[c] += e*v_s[mm][c];
      }
    }
    __syncthreads();   // all mm loops done before red (aliases q/k/v staging) is written
    red[sub][qi][0]=m; red[sub][qi][1]=s;
    #pragma unroll
    for(int c=0;c<16;c++) red[sub][qi][2+c]=acc[c];
    __syncthreads();
    if(sub==0){
      int n = qn_s[qi];
      if(n>=0){
        float M=-1e30f;
        #pragma unroll
        for(int j=0;j<4;j++) M=fmaxf(M,red[j][qi][0]);
        float S=0.f; float o[16];
        #pragma unroll
        for(int c=0;c<16;c++) o[c]=0.f;
        #pragma unroll
        for(int j=0;j<4;j++){ float e=__expf(red[j][qi][0]-M); S += e*red[j][qi][1];
          #pragma unroll
          for(int c=0;c<16;c++) o[c] += e*red[j][qi][2+c]; }
        float inv = 1.f/S;
        #pragma unroll
        for(int c=0;c<16;c++) att[((size_t)b*NQ+n)*128 + h*16 + c] = o[c]*inv;
      }
    }
    return;
  }
  // ---- value GEMM (k_value6 core, unchanged) ----
  unsigned short (*a_t)[136] = (unsigned short(*)[136])smem;  // 17408
  int bxy = bid - NATT;
  int bv = bxy % 12;
  int bx = bxy / 12;
  int lvl, tile;
  if(bx < 350){ lvl=0; tile=bx; }
  else if(bx < 438){ lvl=1; tile=bx-350; }
  else if(bx < 460){ lvl=2; tile=bx-438; }
  else { lvl=3; tile=bx-460; }
  const int HW = (lvl==0)?22400:(lvl==1)?5600:(lvl==2)?1400:350;
  const int startL = (lvl==0)?0:(lvl==1)?22400:(lvl==2)?28000:29400;
  const float* feat = (lvl==0)?f0:(lvl==1)?f1:(lvl==2)?f2:f3;
  const float* fbase = feat + (size_t)bv*128*(size_t)HW;
  int l0 = tile*64;

  int lane = t&63, wave = t>>6;
  int fr = lane&15, kg = lane>>4;

  int l_u = t & 63, oct0 = t>>6;
  int gl = l0 + l_u; bool ok = (gl < HW);
  const float* fcol = fbase + (size_t)(oct0*8)*HW + (ok ? gl : 0);

  float v32[4][8];
  #pragma unroll
  for(int q=0;q<4;q++)
    #pragma unroll
    for(int j=0;j<8;j++)
      v32[q][j] = ok ? fcol[(size_t)(q*32+j)*HW] : 0.f;

  #pragma unroll
  for(int q=0;q<4;q++){
    uint4 u;
    u.x = (unsigned)f2bf(v32[q][0]) | ((unsigned)f2bf(v32[q][1])<<16);
    u.y = (unsigned)f2bf(v32[q][2]) | ((unsigned)f2bf(v32[q][3])<<16);
    u.z = (unsigned)f2bf(v32[q][4]) | ((unsigned)f2bf(v32[q][5])<<16);
    u.w = (unsigned)f2bf(v32[q][6]) | ((unsigned)f2bf(v32[q][7])<<16);
    *reinterpret_cast<uint4*>(&a_t[l_u][oct0*8 + q*32]) = u;
  }
  __syncthreads();

  f32x4 acc[4][2];
  #pragma unroll
  for(int i=0;i<4;i++)
    #pragma unroll
    for(int j=0;j<2;j++) acc[i][j] = (f32x4)0.f;

  #pragma unroll
  for(int ck=0; ck<4; ck++){
    int c0 = ck*32;
    bf16x8 bfr[2];
    #pragma unroll
    for(int j=0;j<2;j++){
      int d = wave*32 + j*16 + fr;
      bfr[j] = *reinterpret_cast<const bf16x8*>(wt + (size_t)d*128 + c0 + kg*8);
    }
    bf16x8 af[4];
    #pragma unroll
    for(int i=0;i<4;i++) af[i] = *reinterpret_cast<const bf16x8*>(&a_t[i*16 + fr][c0 + kg*8]);
    #pragma unroll
    for(int i=0;i<4;i++)
      #pragma unroll
      for(int j=0;j<2;j++)
        acc[i][j] = __builtin_amdgcn_mfma_f32_16x16x32_bf16(af[i], bfr[j], acc[i][j], 0, 0, 0);
  }

  __syncthreads();
  unsigned short (*c_l)[136] = a_t;
  #pragma unroll
  for(int i=0;i<4;i++){
    int rbase = i*16 + kg*4;
    #pragma unroll
    for(int j=0;j<2;j++){
      int d = wave*32 + j*16 + fr;
      #pragma unroll
      for(int r=0;r<4;r++) c_l[rbase + r][d] = f2bf(acc[i][j][r]);
    }
  }
  __syncthreads();
  #pragma unroll
  for(int p=0;p<4;p++){
    int i = t + p*256;
    int row = i>>4, seg = i&15;
    int glr = l0 + row;
    if(glr < HW){
      uint4 cu = *reinterpret_cast<const uint4*>(&c_l[row][seg*8]);
      const uint4 ku = *reinterpret_cast<const uint4*>(kvpe + (size_t)(startL+glr)*CC + seg*8);
      uint4 ou;
      ou.x = addbf2(cu.x, ku.x); ou.y = addbf2(cu.y, ku.y);
      ou.z = addbf2(cu.z, ku.z); ou.w = addbf2(cu.w, ku.w);
      *reinterpret_cast<uint4*>(value + ((size_t)bv*LTOT + startL + glr)*CC + seg*8) = ou;
    }
  }
}

// ---------------- fused: proj+LN1 -> qc (LDS) -> offset matvec + attn-weight softmax ----------------
__global__ void __launch_bounds__(384) k_q2(
    const float* __restrict__ att, const float* __restrict__ sa_wo, const float* __restrict__ sa_bo,
    float* __restrict__ x, const float* __restrict__ ln1_g, const float* __restrict__ ln1_b,
    const float* __restrict__ qpe,
    const float* __restrict__ dow, const float* __restrict__ dob,
    const float* __restrict__ daw, const float* __restrict__ dab,
    float* __restrict__ offb, float* __restrict__ awb){
  int r0 = blockIdx.x*8; int t = threadIdx.x; // 384 threads
  __shared__ float s_att[8][128];
  __shared__ float s_qc[8][128];
  __shared__ float s_m[8][2][2];
  __shared__ float s_aw[8][130];
  for(int i=t;i<1024;i+=384){ int r=i>>7, c=i&127; s_att[r][c]=att[(size_t)(r0+r)*128+c]; }
  __syncthreads();
  int lane = t&63, wid = (t>>6)&1;
  float v[8];
  if(t < 128){
    int d = t;
    float acc[8];
    #pragma unroll
    for(int r=0;r<8;r++) acc[r]=sa_bo[d];
    #pragma unroll 4
    for(int c=0;c<128;c++){ float wv = sa_wo[c*128+d];
      #pragma unroll
      for(int r=0;r<8;r++) acc[r] += s_att[r][c]*wv; }
    #pragma unroll
    for(int r=0;r<8;r++){
      v[r] = acc[r] + x[(size_t)(r0+r)*128 + d];
      float s1=v[r], s2=v[r]*v[r];
      for(int o=32;o>0;o>>=1){ s1 += __shfl_down(s1,o); s2 += __shfl_down(s2,o); }
      if(lane==0){ s_m[r][wid][0]=s1; s_m[r][wid][1]=s2; }
    }
  }
  __syncthreads();
  if(t < 128){
    int d = t;
    #pragma unroll
    for(int r=0;r<8;r++){
      float S1=s_m[r][0][0]+s_m[r][1][0], S2=s_m[r][0][1]+s_m[r][1][1];
      float mean=S1*(1.f/128.f), var=S2*(1.f/128.f)-mean*mean;
      float rs=rsqrtf(var+1e-5f);
      float o=(v[r]-mean)*rs*ln1_g[d]+ln1_b[d];
      x[(size_t)(r0+r)*128+d]=o;
      s_qc[r][d]=o+qpe[(size_t)(r0+r)*128+d];
    }
  }
  __syncthreads();
  if(t < 256){
    int d = t;
    float acc[8];
    #pragma unroll
    for(int r=0;r<8;r++) acc[r]=dob[d];
    #pragma unroll 4
    for(int c=0;c<128;c++){ float wv = dow[(size_t)c*256+d];
      #pragma unroll
      for(int r=0;r<8;r++) acc[r] += s_qc[r][c]*wv; }
    #pragma unroll
    for(int r=0;r<8;r++) offb[(size_t)(r0+r)*256+d]=acc[r];
  } else {
    int d = t - 256;
    float acc[8];
    #pragma unroll
    for(int r=0;r<8;r++) acc[r]=dab[d];
    #pragma unroll 4
    for(int c=0;c<128;c++){ float wv = daw[(size_t)c*128+d];
      #pragma unroll
      for(int r=0;r<8;r++) acc[r] += s_qc[r][c]*wv; }
    #pragma unroll
    for(int r=0;r<8;r++) s_aw[r][d]=acc[r];
  }
  __syncthreads();
  if(t < 64){
    int r = t>>3, h = t&7;
    float mx=-1e30f;
    #pragma unroll
    for(int i=0;i<16;i++) mx = fmaxf(mx, s_aw[r][h*16+i]);
    float e[16]; float sm=0.f;
    #pragma unroll
    for(int i=0;i<16;i++){ e[i]=__expf(s_aw[r][h*16+i]-mx); sm+=e[i]; }
    float inv = 1.f/sm;
    #pragma unroll
    for(int i=0;i<16;i++) awb[(size_t)(r0+r)*128 + h*16+i] = e[i]*inv;
  }
}

// ---------------- fused tail: bilinear sample + proj_ln2 + FFN1 + FFN2/LN3 + head ----------------
__global__ void __launch_bounds__(128) k_tail2(
    const float* __restrict__ qpos, const int* __restrict__ view,
    const float* __restrict__ offb, const float* __restrict__ awb,
    const unsigned short* __restrict__ value,
    const float* __restrict__ dOw, const float* __restrict__ dOb,
    const float* __restrict__ xres,
    const float* __restrict__ ln2_g, const float* __restrict__ ln2_b,
    const float* __restrict__ fw1, const float* __restrict__ fb1,
    const float* __restrict__ fw2, const float* __restrict__ fb2,
    const float* __restrict__ ln3_g, const float* __restrict__ ln3_b,
    const float* __restrict__ pw1, const float* __restrict__ pb1,
    const float* __restrict__ pw2, const float* __restrict__ pb2,
    const int* __restrict__ counts, float* __restrict__ dout){
  int r0 = blockIdx.x*4; int d = threadIdx.x;  // 128 threads
  __shared__ float s_a[4][256];
  __shared__ float s_x[4][128];
  __shared__ float s_m[4][2][2];
  __shared__ float s_res[4][6];
  __shared__ float sred[128][17];
  __shared__ float s_ca[4][128];
  int lane = d&63, wid = d>>6;

  int h = d>>4, lp = d&15, lvl = lp>>2;
  int w = c_W[lvl], hh = c_H[lvl];
  float samp[4][16]; float aw4[4];
  int vw4[4];
  #pragma unroll
  for(int r=0;r<4;r++){
    size_t row = (size_t)(r0+r);
    int b = (r0+r)/NQ;
    float rx = sigm(qpos[row*2]), ry = sigm(qpos[row*2+1]);
    int vw = view[row]; vw4[r]=vw;
    float ox = offb[row*256 + d*2], oy = offb[row*256 + d*2+1];
    aw4[r] = awb[row*128 + d];
    float lx = rx*(float)w + ox - 0.5f;
    float ly = ry*(float)hh + oy - 0.5f;
    float x0f = floorf(lx), y0f = floorf(ly);
    float fx = lx - x0f, fy = ly - y0f;
    int x0 = (int)x0f, y0 = (int)y0f;
    #pragma unroll
    for(int c=0;c<16;c++) samp[r][c]=0.f;
    size_t brow = ((size_t)(b*VV + vw))*LTOT + c_S[lvl];
    #pragma unroll
    for(int dy=0;dy<2;dy++){
      #pragma unroll
      for(int dx=0;dx<2;dx++){
        int xi=x0+dx, yi=y0+dy;
        if(xi<0||xi>=w||yi<0||yi>=hh) continue;
        float wt = (dx?fx:(1.f-fx))*(dy?fy:(1.f-fy));
        const uint4* vp = reinterpret_cast<const uint4*>(value + (brow + (size_t)yi*w + xi)*CC + h*16);
        uint4 u0 = vp[0], u1 = vp[1];
        samp[r][0] += wt*bflo(u0.x); samp[r][1] += wt*bfhi(u0.x);
        samp[r][2] += wt*bflo(u0.y); samp[r][3] += wt*bfhi(u0.y);
        samp[r][4] += wt*bflo(u0.z); samp[r][5] += wt*bfhi(u0.z);
        samp[r][6] += wt*bflo(u0.w); samp[r][7] += wt*bfhi(u0.w);
        samp[r][8] += wt*bflo(u1.x); samp[r][9] += wt*bfhi(u1.x);
        samp[r][10]+= wt*bflo(u1.y); samp[r][11]+= wt*bfhi(u1.y);
        samp[r][12]+= wt*bflo(u1.z); samp[r][13]+= wt*bfhi(u1.z);
        samp[r][14]+= wt*bflo(u1.w); samp[r][15]+= wt*bfhi(u1.w);
      }
    }
  }
  #pragma unroll
  for(int r=0;r<4;r++){
    #pragma unroll
    for(int c=0;c<16;c++) sred[d][c] = aw4[r]*samp[r][c];
    __syncthreads();
    int h2=d>>4, c2=d&15;
    float sum=0.f;
    #pragma unroll
    for(int j=0;j<16;j++) sum += sred[h2*16+j][c2];
    s_ca[r][d] = sum;
    __syncthreads();
  }

  #pragma unroll
  for(int r=0;r<4;r++) s_a[r][d] = s_ca[r][d];
  __syncthreads();
  float acc[4];
  #pragma unroll
  for(int r=0;r<4;r++) acc[r]=dOb[d];
  #pragma unroll 4
  for(int c=0;c<128;c++){ float wv = dOw[c*128+d];
    #pragma unroll
    for(int r=0;r<4;r++) acc[r] += s_a[r][c]*wv; }
  float v[4];
  #pragma unroll
  for(int r=0;r<4;r++){
    v[r] = acc[r] + xres[(size_t)(r0+r)*128 + d];
    float s1=v[r], s2=v[r]*v[r];
    for(int o=32;o>0;o>>=1){ s1 += __shfl_down(s1,o); s2 += __shfl_down(s2,o); }
    if(lane==0){ s_m[r][wid][0]=s1; s_m[r][wid][1]=s2; }
  }
  __syncthreads();
  #pragma unroll
  for(int r=0;r<4;r++){
    float S1=s_m[r][0][0]+s_m[r][1][0], S2=s_m[r][0][1]+s_m[r][1][1];
    float mean=S1*(1.f/128.f), var=S2*(1.f/128.f)-mean*mean;
    float rs=rsqrtf(var+1e-5f);
    s_x[r][d]=(v[r]-mean)*rs*ln2_g[d]+ln2_b[d];
  }
  __syncthreads();

  float a2a[4], a2b[4];
  #pragma unroll
  for(int r=0;r<4;r++){ a2a[r]=fb1[d]; a2b[r]=fb1[d+128]; }
  #pragma unroll 4
  for(int c=0;c<128;c++){ float w0 = fw1[c*256+d], w1_ = fw1[c*256+d+128];
    #pragma unroll
    for(int r=0;r<4;r++){ float xv = s_x[r][c]; a2a[r] += xv*w0; a2b[r] += xv*w1_; } }
  __syncthreads();
  #pragma unroll
  for(int r=0;r<4;r++){ s_a[r][d]=fmaxf(a2a[r],0.f); s_a[r][d+128]=fmaxf(a2b[r],0.f); }
  __syncthreads();

  float a3[4];
  #pragma unroll
  for(int r=0;r<4;r++) a3[r]=fb2[d];
  #pragma unroll 4
  for(int c=0;c<256;c++){ float wv = fw2[c*128+d];
    #pragma unroll
    for(int r=0;r<4;r++) a3[r] += s_a[r][c]*wv; }
  #pragma unroll
  for(int r=0;r<4;r++){
    v[r] = a3[r] + s_x[r][d];
    float s1=v[r], s2=v[r]*v[r];
    for(int o=32;o>0;o>>=1){ s1 += __shfl_down(s1,o); s2 += __shfl_down(s2,o); }
    if(lane==0){ s_m[r][wid][0]=s1; s_m[r][wid][1]=s2; }
  }
  __syncthreads();
  #pragma unroll
  for(int r=0;r<4;r++){
    float S1=s_m[r][0][0]+s_m[r][1][0], S2=s_m[r][0][1]+s_m[r][1][1];
    float mean=S1*(1.f/128.f), var=S2*(1.f/128.f)-mean*mean;
    float rs=rsqrtf(var+1e-5f);
    float o=(v[r]-mean)*rs*ln3_g[d]+ln3_b[d];
    int row=r0+r; int b=row/NQ, n=row%NQ;
    bool val = counts[b*VV + vw4[r]] > 1;
    float oz = val ? o : 0.f;
    s_x[r][d]=oz;
    dout[((size_t)b*CC + d)*NQ + n]=oz;
  }
  __syncthreads();

  float a4[4];
  #pragma unroll
  for(int r=0;r<4;r++) a4[r]=pb1[d];
  #pragma unroll 4
  for(int c=0;c<128;c++){ float wv = pw1[c*128+d];
    #pragma unroll
    for(int r=0;r<4;r++) a4[r] += s_x[r][c]*wv; }
  #pragma unroll
  for(int r=0;r<4;r++) s_a[r][d]=fmaxf(a4[r],0.f);
  __syncthreads();

  if(d < 24){
    int r = d/6, o = d%6;
    float a5 = pb2[o];
    #pragma unroll 4
    for(int c=0;c<128;c++) a5 += s_a[r][c]*pw2[c*6+o];
    s_res[r][o] = a5;
  }
  __syncthreads();
  if(d < 4){
    int r = d; int row = r0+r; int b=row/NQ, n=row%NQ;
    const int O1 = BB*CC*NQ;
    const int O2 = O1 + BB*NQ*2;
    const int O3 = O2 + BB*2*NQ;
    const int O4 = O3 + BB*4*NQ;
    float p0=qpos[row*2], p1=qpos[row*2+1];
    float cr0 = s_res[r][0]+p0, cr1 = s_res[r][1]+p1;
    dout[O1 + row*2]   = cr0;
    dout[O1 + row*2+1] = cr1;
    float cen0 = sigm(cr0), cen1 = sigm(cr1);
    dout[O2 + (b*2+0)*NQ + n] = cen0;
    dout[O2 + (b*2+1)*NQ + n] = cen1;
    float f0=sigm(s_res[r][2]), f1=sigm(s_res[r][3]), f2=sigm(s_res[r][4]), f3=sigm(s_res[r][5]);
    dout[O3 + (b*4+0)*NQ + n] = f0;
    dout[O3 + (b*4+1)*NQ + n] = f1;
    dout[O3 + (b*4+2)*NQ + n] = f2;
    dout[O3 + (b*4+3)*NQ + n] = f3;
    float bw=f0+f2, bh=f1+f3;
    float cx=(2.f*cen0 - f0 + f2)*0.5f;
    float cy=(2.f*cen1 - f1 + f3)*0.5f;
    dout[O4 + (b*4+0)*NQ + n] = cx;
    dout[O4 + (b*4+1)*NQ + n] = cy;
    dout[O4 + (b*4+2)*NQ + n] = bw;
    dout[O4 + (b*4+3)*NQ + n] = bh;
  }
}

extern "C" void kernel_launch(void* const* d_in, const int* in_sizes, int n_in,
                              void* d_out, int out_size, void* d_ws, size_t ws_size,
                              hipStream_t stream){
  (void)in_sizes; (void)n_in; (void)out_size; (void)ws_size;
  const float* in_iqf  = (const float*)d_in[0];
  const float* in_qpos = (const float*)d_in[1];
  const float* in_feat[4] = {(const float*)d_in[2],(const float*)d_in[3],(const float*)d_in[4],(const float*)d_in[5]};
  const float* in_kpos = (const float*)d_in[6];
  const float* sp_w1=(const float*)d_in[7], *sp_b1=(const float*)d_in[8], *sp_w2=(const float*)d_in[9], *sp_b2=(const float*)d_in[10];
  const float* cp_w1=(const float*)d_in[11], *cp_b1=(const float*)d_in[12], *cp_w2=(const float*)d_in[13], *cp_b2=(const float*)d_in[14];
  const float* sa_wqkv=(const float*)d_in[15], *sa_bqkv=(const float*)d_in[16], *sa_wo=(const float*)d_in[17], *sa_bo=(const float*)d_in[18];
  const float* ln1_g=(const float*)d_in[19], *ln1_b=(const float*)d_in[20];
  const float* dvw=(const float*)d_in[21], *dvb=(const float*)d_in[22];
  const float* dow=(const float*)d_in[23], *dob=(const float*)d_in[24];
  const float* daw=(const float*)d_in[25], *dab=(const float*)d_in[26];
  const float* dOw=(const float*)d_in[27], *dOb=(const float*)d_in[28];
  const float* ln2_g=(const float*)d_in[29], *ln2_b=(const float*)d_in[30];
  const float* fw1=(const float*)d_in[31], *fb1=(const float*)d_in[32], *fw2=(const float*)d_in[33], *fb2=(const float*)d_in[34];
  const float* ln3_g=(const float*)d_in[35], *ln3_b=(const float*)d_in[36];
  const float* pw1=(const float*)d_in[37], *pb1=(const float*)d_in[38], *pw2=(const float*)d_in[39], *pb2=(const float*)d_in[40];
  const int* in_view = (const int*)d_in[41];
  float* out = (float*)d_out;

  char* ws = (char*)d_ws;
  unsigned short* value = (unsigned short*)ws;                       // 91,392,000 B
  unsigned short* kvpe  = (unsigned short*)(ws + 91392000);          //  7,616,000 B
  float* f = (float*)(ws + 91392000 + 7616000);
  float* qpe  = f;               // 307200
  float* x    = f + 307200;      // 307200
  float* qkv  = f + 614400;      // 921600
  float* att  = f + 1536000;     // 307200
  float* offb = f + 2150400;     // 614400
  float* awb  = f + 2764800;     // 307200
  int* counts = (int*)(f + 4300800);   // 12 ints
  int* order  = (int*)(f + 4300816);   // B*VV*NQ = 14400 ints
  unsigned short* wtb   = (unsigned short*)(f + 4315216);  // 32768 B
  unsigned short* cw2tb = (unsigned short*)(f + 4323408);  // 32768 B

  k_misc<<<dim3(BB+32+76+600),dim3(256),0,stream>>>(in_view,order,counts,dvw,wtb,
      cp_w2,cw2tb,in_iqf,x,in_qpos,sp_w1,sp_b1,sp_w2,sp_b2,qpe);
  k_kvpe_qkv<<<dim3(NKVPE + 300),dim3(256),0,stream>>>(in_kpos,cp_w1,cp_b1,cw2tb,cp_b2,wtb,dvb,kvpe,
      x,qpe,sa_wqkv,sa_bqkv,qkv);
  k_value_attn2<<<dim3(NATT + 466*12),dim3(256),0,stream>>>(in_feat[0],in_feat[1],in_feat[2],in_feat[3],
      kvpe,wtb,value,qkv,order,counts,att);
  k_q2<<<dim3(NROWS/8),dim3(384),0,stream>>>(att,sa_wo,sa_bo,x,ln1_g,ln1_b,qpe,
      dow,dob,daw,dab,offb,awb);
  k_tail2<<<dim3(NROWS/4),dim3(128),0,stream>>>(in_qpos,in_view,offb,awb,value,
      dOw,dOb,x,ln2_g,ln2_b,fw1,fb1,fw2,fb2,ln3_g,ln3_b,pw1,pb1,pw2,pb2,counts,out);
}

// Round 14
// 207.444 us; speedup vs baseline: 1.8813x; 1.0223x over previous
//
#include <hip/hip_runtime.h>
#include <hip/hip_bf16.h>
#include <math.h>

#define DEV __device__ __forceinline__

#define BB 2
#define VV 6
#define CC 128
#define NQ 1200
#define HH 8
#define PTSN 4
#define FFND 256
#define LVLSN 4
#define LTOT 29750
#define NROWS (BB*NQ)

__constant__ int c_W[4] = {200,100,50,25};
__constant__ int c_H[4] = {112,56,28,14};
__constant__ int c_S[4] = {0,22400,28000,29400};

DEV float bflo(unsigned u){ union{unsigned i; float f;}x; x.i = u<<16; return x.f; }
DEV float bfhi(unsigned u){ union{unsigned i; float f;}x; x.i = u&0xffff0000u; return x.f; }
DEV unsigned short f2bf(float f){ union{float f; unsigned i;}x; x.f=f; unsigned i=x.i;
  return (unsigned short)((i + 0x7fffu + ((i>>16)&1u))>>16); }
DEV unsigned addbf2(unsigned a, unsigned b){
  float lo = bflo(a)+bflo(b); float hi = bfhi(a)+bfhi(b);
  return (unsigned)f2bf(lo) | ((unsigned)f2bf(hi)<<16);
}
DEV float sigm(float z){ return 1.f/(1.f+__expf(-z)); }

typedef __attribute__((ext_vector_type(8))) short bf16x8;
typedef __attribute__((ext_vector_type(4))) float f32x4;

// ---------------- fused setup: bucket(2) + wt(16) + cw2t(16) + xpose(76) + qpe(600) ----------------
__global__ void k_misc(const int* __restrict__ view, int* __restrict__ order,
                       int* __restrict__ counts,
                       const float* __restrict__ vw, unsigned short* __restrict__ wt,
                       const float* __restrict__ cw2, unsigned short* __restrict__ cw2t,
                       const float* __restrict__ iqf, float* __restrict__ x,
                       const float* __restrict__ pos,
                       const float* __restrict__ w1, const float* __restrict__ b1,
                       const float* __restrict__ w2, const float* __restrict__ b2,
                       float* __restrict__ qpe){
  int bid = blockIdx.x;
  int t = threadIdx.x;
  if(bid < BB){
    if(t < 64){
      int b = bid; int lane = t;
      int base0=0,base1=0,base2=0,base3=0,base4=0,base5=0;
      for(int c0=0;c0<NQ;c0+=64){
        int n = c0 + lane;
        int v = (n<NQ) ? view[b*NQ+n] : -1;
        unsigned long long lower = (lane==63)? 0x7fffffffffffffffull : ((1ull<<lane)-1ull);
        #define BUCKET_STEP(VVV, BASE) { \
          unsigned long long mk = __ballot(v==VVV); \
          if(v==VVV){ int r = BASE + __popcll(mk & lower); order[(b*VV+VVV)*NQ + r] = n; } \
          BASE += __popcll(mk); }
        BUCKET_STEP(0, base0) BUCKET_STEP(1, base1) BUCKET_STEP(2, base2)
        BUCKET_STEP(3, base3) BUCKET_STEP(4, base4) BUCKET_STEP(5, base5)
        #undef BUCKET_STEP
      }
      if(lane==0){
        counts[b*VV+0]=base0; counts[b*VV+1]=base1; counts[b*VV+2]=base2;
        counts[b*VV+3]=base3; counts[b*VV+4]=base4; counts[b*VV+5]=base5;
      }
    }
  } else if(bid < BB+16){
    int d0 = (bid-BB)*8;
    __shared__ float s[128][9];
    #pragma unroll
    for(int p=0;p<4;p++){ int i = t + p*256; int c = i>>3, dd = i&7;
      s[c][dd] = vw[c*128 + d0 + dd]; }
    __syncthreads();
    #pragma unroll
    for(int p=0;p<4;p++){ int i = t + p*256; int dd = i>>7, c = i&127;
      wt[(size_t)(d0+dd)*128 + c] = f2bf(s[c][dd]); }
  } else if(bid < BB+32){
    int d0 = (bid-BB-16)*8;
    __shared__ float s[128][9];
    #pragma unroll
    for(int p=0;p<4;p++){ int i = t + p*256; int c = i>>3, dd = i&7;
      s[c][dd] = cw2[c*128 + d0 + dd]; }
    __syncthreads();
    #pragma unroll
    for(int p=0;p<4;p++){ int i = t + p*256; int dd = i>>7, c = i&127;
      cw2t[(size_t)(d0+dd)*128 + c] = f2bf(s[c][dd]); }
  } else if(bid < BB+32+76){
    __shared__ float tile[128][33];
    int idx = bid - (BB+32);
    int b = idx/38; int n0 = (idx%38)*32;
    for(int i=t;i<128*32;i+=256){ int c=i>>5, nn=i&31; int n=n0+nn;
      tile[c][nn] = (n<NQ)? iqf[((size_t)b*CC + c)*NQ + n] : 0.f; }
    __syncthreads();
    for(int i=t;i<32*128;i+=256){ int nn=i>>7, c=i&127;
      int n=n0+nn; if(n<NQ) x[((size_t)b*NQ+n)*128 + c] = tile[c][nn]; }
  } else {
    __shared__ float hid[4][128];
    int row0 = (bid - (BB+32+76))*4;
    int r = t>>7, d = t&127;
    #pragma unroll
    for(int rr=r; rr<4; rr+=2){
      int row = row0 + rr;
      float p0 = pos[row*2+0], p1 = pos[row*2+1];
      hid[rr][d] = fmaxf(p0*w1[d] + p1*w1[128+d] + b1[d], 0.f);
    }
    __syncthreads();
    #pragma unroll
    for(int rr=r; rr<4; rr+=2){
      float acc = b2[d];
      #pragma unroll 4
      for(int c=0;c<128;c++) acc += hid[rr][c]*w2[c*128 + d];
      qpe[(size_t)(row0+rr)*128+d] = acc;
    }
  }
}

// ---------------- merged: kvpe MFMA (blocks 0..464) + qkv matvec (blocks 465..764) ----------------
#define NKVPE 465
__global__ void __launch_bounds__(256) k_kvpe_qkv(
    const float* __restrict__ kpos,
    const float* __restrict__ cw1, const float* __restrict__ cb1,
    const unsigned short* __restrict__ cw2t, const float* __restrict__ cb2,
    const unsigned short* __restrict__ wt, const float* __restrict__ vb,
    unsigned short* __restrict__ kvpe,
    const float* __restrict__ x, const float* __restrict__ qpe,
    const float* __restrict__ sa_wqkv, const float* __restrict__ sa_bqkv,
    float* __restrict__ qkv){
  __shared__ unsigned short h_t[64][136];
  __shared__ unsigned short k_t[64][136];
  int t = threadIdx.x;
  int bid = blockIdx.x;
  if(bid >= NKVPE){
    float (*s_q)[128] = (float(*)[128])h_t;
    int r0 = (bid - NKVPE)*8;
    for(int i=t;i<1024;i+=256){ int r=i>>7, c=i&127;
      size_t row = (size_t)(r0+r);
      s_q[r][c] = x[row*128+c] + qpe[row*128+c]; }
    __syncthreads();
    for(int d=t; d<384; d+=256){
      float acc[8];
      #pragma unroll
      for(int r=0;r<8;r++) acc[r]=sa_bqkv[d];
      #pragma unroll 4
      for(int c=0;c<128;c++){ float wv = sa_wqkv[c*384+d];
        #pragma unroll
        for(int r=0;r<8;r++) acc[r] += s_q[r][c]*wv; }
      #pragma unroll
      for(int r=0;r<8;r++) qkv[(size_t)(r0+r)*384+d]=acc[r];
    }
    return;
  }
  int r0 = bid*64;
  int lane = t&63, wave = t>>6;
  int fr = lane&15, kg = lane>>4;

  int p = t & 63;
  int d0 = p*2;
  float w1a0 = cw1[d0],     w1a1 = cw1[d0+1];
  float w1b0 = cw1[128+d0], w1b1 = cw1[128+d0+1];
  float b10 = cb1[d0], b11 = cb1[d0+1];
  #pragma unroll 4
  for(int k=0;k<16;k++){
    int r = wave + k*4;
    int row = r0 + r;
    float p0=0.f, p1=0.f;
    if(row < LTOT){ p0 = kpos[row*2]; p1 = kpos[row*2+1]; }
    float h0 = fmaxf(p0*w1a0 + p1*w1b0 + b10, 0.f);
    float h1 = fmaxf(p0*w1a1 + p1*w1b1 + b11, 0.f);
    *reinterpret_cast<unsigned*>(&h_t[r][d0]) = (unsigned)f2bf(h0) | ((unsigned)f2bf(h1)<<16);
  }
  __syncthreads();

  f32x4 acc[4][2];
  #pragma unroll
  for(int i=0;i<4;i++)
    #pragma unroll
    for(int j=0;j<2;j++) acc[i][j] = (f32x4)0.f;
  #pragma unroll
  for(int ck=0; ck<4; ck++){
    int c0 = ck*32;
    bf16x8 bfr[2], af[4];
    #pragma unroll
    for(int j=0;j<2;j++){ int d = wave*32 + j*16 + fr;
      bfr[j] = *reinterpret_cast<const bf16x8*>(cw2t + (size_t)d*128 + c0 + kg*8); }
    #pragma unroll
    for(int i=0;i<4;i++) af[i] = *reinterpret_cast<const bf16x8*>(&h_t[i*16 + fr][c0 + kg*8]);
    #pragma unroll
    for(int i=0;i<4;i++)
      #pragma unroll
      for(int j=0;j<2;j++)
        acc[i][j] = __builtin_amdgcn_mfma_f32_16x16x32_bf16(af[i], bfr[j], acc[i][j], 0, 0, 0);
  }
  #pragma unroll
  for(int i=0;i<4;i++){
    int rbase = i*16 + kg*4;
    #pragma unroll
    for(int j=0;j<2;j++){
      int d = wave*32 + j*16 + fr;
      float bv_ = cb2[d];
      #pragma unroll
      for(int r=0;r<4;r++) k_t[rbase + r][d] = f2bf(acc[i][j][r] + bv_);
    }
  }
  __syncthreads();

  #pragma unroll
  for(int i=0;i<4;i++)
    #pragma unroll
    for(int j=0;j<2;j++) acc[i][j] = (f32x4)0.f;
  #pragma unroll
  for(int ck=0; ck<4; ck++){
    int c0 = ck*32;
    bf16x8 bfr[2], af[4];
    #pragma unroll
    for(int j=0;j<2;j++){ int d = wave*32 + j*16 + fr;
      bfr[j] = *reinterpret_cast<const bf16x8*>(wt + (size_t)d*128 + c0 + kg*8); }
    #pragma unroll
    for(int i=0;i<4;i++) af[i] = *reinterpret_cast<const bf16x8*>(&k_t[i*16 + fr][c0 + kg*8]);
    #pragma unroll
    for(int i=0;i<4;i++)
      #pragma unroll
      for(int j=0;j<2;j++)
        acc[i][j] = __builtin_amdgcn_mfma_f32_16x16x32_bf16(af[i], bfr[j], acc[i][j], 0, 0, 0);
  }
  __syncthreads();
  unsigned short (*c_l)[136] = h_t;
  #pragma unroll
  for(int i=0;i<4;i++){
    int rbase = i*16 + kg*4;
    #pragma unroll
    for(int j=0;j<2;j++){
      int d = wave*32 + j*16 + fr;
      float bv_ = vb[d];
      #pragma unroll
      for(int r=0;r<4;r++) c_l[rbase + r][d] = f2bf(acc[i][j][r] + bv_);
    }
  }
  __syncthreads();
  #pragma unroll
  for(int p4=0;p4<4;p4++){
    int i = t + p4*256;
    int row = i>>4, seg = i&15;
    int glr = r0 + row;
    if(glr < LTOT){
      uint4 cu = *reinterpret_cast<const uint4*>(&c_l[row][seg*8]);
      *reinterpret_cast<uint4*>(kvpe + (size_t)glr*CC + seg*8) = cu;
    }
  }
}

// ---------------- merged: self-attention (blocks 0..1823, reads qkv) + value GEMM ----------------
#define NATT (19*48*2)
#define QT2 64
#define KTA 64
__global__ void __launch_bounds__(256) k_value_attn2(
    const float* __restrict__ f0, const float* __restrict__ f1,
    const float* __restrict__ f2, const float* __restrict__ f3,
    const unsigned short* __restrict__ kvpe, const unsigned short* __restrict__ wt,
    unsigned short* __restrict__ value,
    const float* __restrict__ qkv,
    const int* __restrict__ order, const int* __restrict__ counts,
    float* __restrict__ att){
  __shared__ __align__(16) char smem[18688];
  int t = threadIdx.x;
  int bid = blockIdx.x;
  if(bid < NATT){
    int qt = bid % 19;
    int vh = (bid/19) % 48;
    int b  = bid/(19*48);
    int v = vh>>3, h = vh&7;
    int C = counts[b*VV+v];
    int q0 = qt*QT2;
    if(q0 >= C) return;
    const int* ord = order + (size_t)(b*VV+v)*NQ;
    float (*q_s)[17] = (float(*)[17])smem;               // 4352
    float (*k_s)[16] = (float(*)[16])(smem + 4352);      // 4096
    float (*v_s)[16] = (float(*)[16])(smem + 8448);      // 4096
    float (*red)[QT2][18] = (float(*)[QT2][18])smem;     // 18432, aliases q/k/v
    int* qn_s = (int*)(smem + 18432);                    // 256
    for(int i=t;i<QT2;i+=256){ int qi=q0+i; qn_s[i] = (qi<C)? ord[qi] : -1; }
    __syncthreads();
    for(int i=t;i<QT2*16;i+=256){ int r=i>>4,c=i&15; int n=qn_s[r];
      q_s[r][c] = (n>=0)? qkv[((size_t)b*NQ+n)*384 + h*16 + c] : 0.f; }
    int qi = t&63, sub = t>>6;
    float m = -1e30f, s = 0.f, acc[16];
    #pragma unroll
    for(int c=0;c<16;c++) acc[c]=0.f;
    for(int k0=0; k0<C; k0+=KTA){
      int kn = C-k0; if(kn>KTA) kn=KTA;
      __syncthreads();
      for(int i=t;i<KTA*16;i+=256){ int r=i>>4,c=i&15;
        float kv=0.f, vv=0.f;
        if(r<kn){ int n=ord[k0+r]; size_t base=((size_t)b*NQ+n)*384 + h*16 + c;
          kv = qkv[base+128]; vv = qkv[base+256]; }
        k_s[r][c]=kv; v_s[r][c]=vv; }
      __syncthreads();
      for(int mm=sub; mm<kn; mm+=4){
        float l=0.f;
        #pragma unroll
        for(int c=0;c<16;c++) l += q_s[qi][c]*k_s[mm][c];
        l *= 0.25f;
        float newm = fmaxf(m,l);
        float e = __expf(l - newm);
        if(newm > m){
          float rr = __expf(m - newm);
          s *= rr;
          #pragma unroll
          for(int c=0;c<16;c++) acc[c]*=rr;
          m = newm;
        }
        s += e;
        #pragma unroll
        for(int c=0;c<16;c++) acc[c] += e*v_s[mm][c];
      }
    }
    __syncthreads();
    red[sub][qi][0]=m; red[sub][qi][1]=s;
    #pragma unroll
    for(int c=0;c<16;c++) red[sub][qi][2+c]=acc[c];
    __syncthreads();
    if(sub==0){
      int n = qn_s[qi];
      if(n>=0){
        float M=-1e30f;
        #pragma unroll
        for(int j=0;j<4;j++) M=fmaxf(M,red[j][qi][0]);
        float S=0.f; float o[16];
        #pragma unroll
        for(int c=0;c<16;c++) o[c]=0.f;
        #pragma unroll
        for(int j=0;j<4;j++){ float e=__expf(red[j][qi][0]-M); S += e*red[j][qi][1];
          #pragma unroll
          for(int c=0;c<16;c++) o[c] += e*red[j][qi][2+c]; }
        float inv = 1.f/S;
        #pragma unroll
        for(int c=0;c<16;c++) att[((size_t)b*NQ+n)*128 + h*16 + c] = o[c]*inv;
      }
    }
    return;
  }
  unsigned short (*a_t)[136] = (unsigned short(*)[136])smem;
  int bxy = bid - NATT;
  int bv = bxy % 12;
  int bx = bxy / 12;
  int lvl, tile;
  if(bx < 350){ lvl=0; tile=bx; }
  else if(bx < 438){ lvl=1; tile=bx-350; }
  else if(bx < 460){ lvl=2; tile=bx-438; }
  else { lvl=3; tile=bx-460; }
  const int HW = (lvl==0)?22400:(lvl==1)?5600:(lvl==2)?1400:350;
  const int startL = (lvl==0)?0:(lvl==1)?22400:(lvl==2)?28000:29400;
  const float* feat = (lvl==0)?f0:(lvl==1)?f1:(lvl==2)?f2:f3;
  const float* fbase = feat + (size_t)bv*128*(size_t)HW;
  int l0 = tile*64;

  int lane = t&63, wave = t>>6;
  int fr = lane&15, kg = lane>>4;

  int l_u = t & 63, oct0 = t>>6;
  int gl = l0 + l_u; bool ok = (gl < HW);
  const float* fcol = fbase + (size_t)(oct0*8)*HW + (ok ? gl : 0);

  float v32[4][8];
  #pragma unroll
  for(int q=0;q<4;q++)
    #pragma unroll
    for(int j=0;j<8;j++)
      v32[q][j] = ok ? fcol[(size_t)(q*32+j)*HW] : 0.f;

  #pragma unroll
  for(int q=0;q<4;q++){
    uint4 u;
    u.x = (unsigned)f2bf(v32[q][0]) | ((unsigned)f2bf(v32[q][1])<<16);
    u.y = (unsigned)f2bf(v32[q][2]) | ((unsigned)f2bf(v32[q][3])<<16);
    u.z = (unsigned)f2bf(v32[q][4]) | ((unsigned)f2bf(v32[q][5])<<16);
    u.w = (unsigned)f2bf(v32[q][6]) | ((unsigned)f2bf(v32[q][7])<<16);
    *reinterpret_cast<uint4*>(&a_t[l_u][oct0*8 + q*32]) = u;
  }
  __syncthreads();

  f32x4 acc[4][2];
  #pragma unroll
  for(int i=0;i<4;i++)
    #pragma unroll
    for(int j=0;j<2;j++) acc[i][j] = (f32x4)0.f;

  #pragma unroll
  for(int ck=0; ck<4; ck++){
    int c0 = ck*32;
    bf16x8 bfr[2];
    #pragma unroll
    for(int j=0;j<2;j++){
      int d = wave*32 + j*16 + fr;
      bfr[j] = *reinterpret_cast<const bf16x8*>(wt + (size_t)d*128 + c0 + kg*8);
    }
    bf16x8 af[4];
    #pragma unroll
    for(int i=0;i<4;i++) af[i] = *reinterpret_cast<const bf16x8*>(&a_t[i*16 + fr][c0 + kg*8]);
    #pragma unroll
    for(int i=0;i<4;i++)
      #pragma unroll
      for(int j=0;j<2;j++)
        acc[i][j] = __builtin_amdgcn_mfma_f32_16x16x32_bf16(af[i], bfr[j], acc[i][j], 0, 0, 0);
  }

  __syncthreads();
  unsigned short (*c_l)[136] = a_t;
  #pragma unroll
  for(int i=0;i<4;i++){
    int rbase = i*16 + kg*4;
    #pragma unroll
    for(int j=0;j<2;j++){
      int d = wave*32 + j*16 + fr;
      #pragma unroll
      for(int r=0;r<4;r++) c_l[rbase + r][d] = f2bf(acc[i][j][r]);
    }
  }
  __syncthreads();
  #pragma unroll
  for(int p=0;p<4;p++){
    int i = t + p*256;
    int row = i>>4, seg = i&15;
    int glr = l0 + row;
    if(glr < HW){
      uint4 cu = *reinterpret_cast<const uint4*>(&c_l[row][seg*8]);
      const uint4 ku = *reinterpret_cast<const uint4*>(kvpe + (size_t)(startL+glr)*CC + seg*8);
      uint4 ou;
      ou.x = addbf2(cu.x, ku.x); ou.y = addbf2(cu.y, ku.y);
      ou.z = addbf2(cu.z, ku.z); ou.w = addbf2(cu.w, ku.w);
      *reinterpret_cast<uint4*>(value + ((size_t)bv*LTOT + startL + glr)*CC + seg*8) = ou;
    }
  }
}

// ---------------- fused: proj+LN1 -> qc (LDS) -> offset matvec + attn-weight softmax ----------------
__global__ void __launch_bounds__(384) k_q2(
    const float* __restrict__ att, const float* __restrict__ sa_wo, const float* __restrict__ sa_bo,
    float* __restrict__ x, const float* __restrict__ ln1_g, const float* __restrict__ ln1_b,
    const float* __restrict__ qpe,
    const float* __restrict__ dow, const float* __restrict__ dob,
    const float* __restrict__ daw, const float* __restrict__ dab,
    float* __restrict__ offb, float* __restrict__ awb){
  int r0 = blockIdx.x*8; int t = threadIdx.x; // 384 threads
  __shared__ float s_att[8][128];
  __shared__ float s_qc[8][128];
  __shared__ float s_m[8][2][2];
  __shared__ float s_aw[8][130];
  for(int i=t;i<1024;i+=384){ int r=i>>7, c=i&127; s_att[r][c]=att[(size_t)(r0+r)*128+c]; }
  __syncthreads();
  int lane = t&63, wid = (t>>6)&1;
  float v[8];
  if(t < 128){
    int d = t;
    float acc[8];
    #pragma unroll
    for(int r=0;r<8;r++) acc[r]=sa_bo[d];
    #pragma unroll 4
    for(int c=0;c<128;c++){ float wv = sa_wo[c*128+d];
      #pragma unroll
      for(int r=0;r<8;r++) acc[r] += s_att[r][c]*wv; }
    #pragma unroll
    for(int r=0;r<8;r++){
      v[r] = acc[r] + x[(size_t)(r0+r)*128 + d];
      float s1=v[r], s2=v[r]*v[r];
      for(int o=32;o>0;o>>=1){ s1 += __shfl_down(s1,o); s2 += __shfl_down(s2,o); }
      if(lane==0){ s_m[r][wid][0]=s1; s_m[r][wid][1]=s2; }
    }
  }
  __syncthreads();
  if(t < 128){
    int d = t;
    #pragma unroll
    for(int r=0;r<8;r++){
      float S1=s_m[r][0][0]+s_m[r][1][0], S2=s_m[r][0][1]+s_m[r][1][1];
      float mean=S1*(1.f/128.f), var=S2*(1.f/128.f)-mean*mean;
      float rs=rsqrtf(var+1e-5f);
      float o=(v[r]-mean)*rs*ln1_g[d]+ln1_b[d];
      x[(size_t)(r0+r)*128+d]=o;
      s_qc[r][d]=o+qpe[(size_t)(r0+r)*128+d];
    }
  }
  __syncthreads();
  if(t < 256){
    int d = t;
    float acc[8];
    #pragma unroll
    for(int r=0;r<8;r++) acc[r]=dob[d];
    #pragma unroll 4
    for(int c=0;c<128;c++){ float wv = dow[(size_t)c*256+d];
      #pragma unroll
      for(int r=0;r<8;r++) acc[r] += s_qc[r][c]*wv; }
    #pragma unroll
    for(int r=0;r<8;r++) offb[(size_t)(r0+r)*256+d]=acc[r];
  } else {
    int d = t - 256;
    float acc[8];
    #pragma unroll
    for(int r=0;r<8;r++) acc[r]=dab[d];
    #pragma unroll 4
    for(int c=0;c<128;c++){ float wv = daw[(size_t)c*128+d];
      #pragma unroll
      for(int r=0;r<8;r++) acc[r] += s_qc[r][c]*wv; }
    #pragma unroll
    for(int r=0;r<8;r++) s_aw[r][d]=acc[r];
  }
  __syncthreads();
  if(t < 64){
    int r = t>>3, h = t&7;
    float mx=-1e30f;
    #pragma unroll
    for(int i=0;i<16;i++) mx = fmaxf(mx, s_aw[r][h*16+i]);
    float e[16]; float sm=0.f;
    #pragma unroll
    for(int i=0;i<16;i++){ e[i]=__expf(s_aw[r][h*16+i]-mx); sm+=e[i]; }
    float inv = 1.f/sm;
    #pragma unroll
    for(int i=0;i<16;i++) awb[(size_t)(r0+r)*128 + h*16+i] = e[i]*inv;
  }
}

// ---------------- fused tail (2 rows/block): sample + proj_ln2 + FFN + LN3 + head ----------------
__global__ void __launch_bounds__(128) k_tail3(
    const float* __restrict__ qpos, const int* __restrict__ view,
    const float* __restrict__ offb, const float* __restrict__ awb,
    const unsigned short* __restrict__ value,
    const float* __restrict__ dOw, const float* __restrict__ dOb,
    const float* __restrict__ xres,
    const float* __restrict__ ln2_g, const float* __restrict__ ln2_b,
    const float* __restrict__ fw1, const float* __restrict__ fb1,
    const float* __restrict__ fw2, const float* __restrict__ fb2,
    const float* __restrict__ ln3_g, const float* __restrict__ ln3_b,
    const float* __restrict__ pw1, const float* __restrict__ pb1,
    const float* __restrict__ pw2, const float* __restrict__ pb2,
    const int* __restrict__ counts, float* __restrict__ dout){
  int r0 = blockIdx.x*2; int d = threadIdx.x;  // 128 threads, 2 rows
  __shared__ float s_a[2][256];
  __shared__ float s_x[2][128];
  __shared__ float s_m[2][2][2];
  __shared__ float s_res[2][6];
  __shared__ float sred[128][17];
  __shared__ float s_ca[2][128];
  int lane = d&63, wid = d>>6;

  int h = d>>4, lp = d&15, lvl = lp>>2;
  int w = c_W[lvl], hh = c_H[lvl];
  float samp[2][16]; float aw2[2];
  int vw2[2];
  #pragma unroll
  for(int r=0;r<2;r++){
    size_t row = (size_t)(r0+r);
    int b = (r0+r)/NQ;
    float rx = sigm(qpos[row*2]), ry = sigm(qpos[row*2+1]);
    int vw = view[row]; vw2[r]=vw;
    float ox = offb[row*256 + d*2], oy = offb[row*256 + d*2+1];
    aw2[r] = awb[row*128 + d];
    float lx = rx*(float)w + ox - 0.5f;
    float ly = ry*(float)hh + oy - 0.5f;
    float x0f = floorf(lx), y0f = floorf(ly);
    float fx = lx - x0f, fy = ly - y0f;
    int x0 = (int)x0f, y0 = (int)y0f;
    #pragma unroll
    for(int c=0;c<16;c++) samp[r][c]=0.f;
    size_t brow = ((size_t)(b*VV + vw))*LTOT + c_S[lvl];
    #pragma unroll
    for(int dy=0;dy<2;dy++){
      #pragma unroll
      for(int dx=0;dx<2;dx++){
        int xi=x0+dx, yi=y0+dy;
        if(xi<0||xi>=w||yi<0||yi>=hh) continue;
        float wt = (dx?fx:(1.f-fx))*(dy?fy:(1.f-fy));
        const uint4* vp = reinterpret_cast<const uint4*>(value + (brow + (size_t)yi*w + xi)*CC + h*16);
        uint4 u0 = vp[0], u1 = vp[1];
        samp[r][0] += wt*bflo(u0.x); samp[r][1] += wt*bfhi(u0.x);
        samp[r][2] += wt*bflo(u0.y); samp[r][3] += wt*bfhi(u0.y);
        samp[r][4] += wt*bflo(u0.z); samp[r][5] += wt*bfhi(u0.z);
        samp[r][6] += wt*bflo(u0.w); samp[r][7] += wt*bfhi(u0.w);
        samp[r][8] += wt*bflo(u1.x); samp[r][9] += wt*bfhi(u1.x);
        samp[r][10]+= wt*bflo(u1.y); samp[r][11]+= wt*bfhi(u1.y);
        samp[r][12]+= wt*bflo(u1.z); samp[r][13]+= wt*bfhi(u1.z);
        samp[r][14]+= wt*bflo(u1.w); samp[r][15]+= wt*bfhi(u1.w);
      }
    }
  }
  #pragma unroll
  for(int r=0;r<2;r++){
    #pragma unroll
    for(int c=0;c<16;c++) sred[d][c] = aw2[r]*samp[r][c];
    __syncthreads();
    int h2=d>>4, c2=d&15;
    float sum=0.f;
    #pragma unroll
    for(int j=0;j<16;j++) sum += sred[h2*16+j][c2];
    s_ca[r][d] = sum;
    __syncthreads();
  }

  #pragma unroll
  for(int r=0;r<2;r++) s_a[r][d] = s_ca[r][d];
  __syncthreads();
  float acc[2];
  #pragma unroll
  for(int r=0;r<2;r++) acc[r]=dOb[d];
  #pragma unroll 4
  for(int c=0;c<128;c++){ float wv = dOw[c*128+d];
    #pragma unroll
    for(int r=0;r<2;r++) acc[r] += s_a[r][c]*wv; }
  float v[2];
  #pragma unroll
  for(int r=0;r<2;r++){
    v[r] = acc[r] + xres[(size_t)(r0+r)*128 + d];
    float s1=v[r], s2=v[r]*v[r];
    for(int o=32;o>0;o>>=1){ s1 += __shfl_down(s1,o); s2 += __shfl_down(s2,o); }
    if(lane==0){ s_m[r][wid][0]=s1; s_m[r][wid][1]=s2; }
  }
  __syncthreads();
  #pragma unroll
  for(int r=0;r<2;r++){
    float S1=s_m[r][0][0]+s_m[r][1][0], S2=s_m[r][0][1]+s_m[r][1][1];
    float mean=S1*(1.f/128.f), var=S2*(1.f/128.f)-mean*mean;
    float rs=rsqrtf(var+1e-5f);
    s_x[r][d]=(v[r]-mean)*rs*ln2_g[d]+ln2_b[d];
  }
  __syncthreads();

  float a2a[2], a2b[2];
  #pragma unroll
  for(int r=0;r<2;r++){ a2a[r]=fb1[d]; a2b[r]=fb1[d+128]; }
  #pragma unroll 4
  for(int c=0;c<128;c++){ float w0 = fw1[c*256+d], w1_ = fw1[c*256+d+128];
    #pragma unroll
    for(int r=0;r<2;r++){ float xv = s_x[r][c]; a2a[r] += xv*w0; a2b[r] += xv*w1_; } }
  __syncthreads();
  #pragma unroll
  for(int r=0;r<2;r++){ s_a[r][d]=fmaxf(a2a[r],0.f); s_a[r][d+128]=fmaxf(a2b[r],0.f); }
  __syncthreads();

  float a3[2];
  #pragma unroll
  for(int r=0;r<2;r++) a3[r]=fb2[d];
  #pragma unroll 4
  for(int c=0;c<256;c++){ float wv = fw2[c*128+d];
    #pragma unroll
    for(int r=0;r<2;r++) a3[r] += s_a[r][c]*wv; }
  #pragma unroll
  for(int r=0;r<2;r++){
    v[r] = a3[r] + s_x[r][d];
    float s1=v[r], s2=v[r]*v[r];
    for(int o=32;o>0;o>>=1){ s1 += __shfl_down(s1,o); s2 += __shfl_down(s2,o); }
    if(lane==0){ s_m[r][wid][0]=s1; s_m[r][wid][1]=s2; }
  }
  __syncthreads();
  #pragma unroll
  for(int r=0;r<2;r++){
    float S1=s_m[r][0][0]+s_m[r][1][0], S2=s_m[r][0][1]+s_m[r][1][1];
    float mean=S1*(1.f/128.f), var=S2*(1.f/128.f)-mean*mean;
    float rs=rsqrtf(var+1e-5f);
    float o=(v[r]-mean)*rs*ln3_g[d]+ln3_b[d];
    int row=r0+r; int b=row/NQ, n=row%NQ;
    bool val = counts[b*VV + vw2[r]] > 1;
    float oz = val ? o : 0.f;
    s_x[r][d]=oz;
    dout[((size_t)b*CC + d)*NQ + n]=oz;
  }
  __syncthreads();

  float a4[2];
  #pragma unroll
  for(int r=0;r<2;r++) a4[r]=pb1[d];
  #pragma unroll 4
  for(int c=0;c<128;c++){ float wv = pw1[c*128+d];
    #pragma unroll
    for(int r=0;r<2;r++) a4[r] += s_x[r][c]*wv; }
  #pragma unroll
  for(int r=0;r<2;r++) s_a[r][d]=fmaxf(a4[r],0.f);
  __syncthreads();

  if(d < 12){
    int r = d/6, o = d%6;
    float a5 = pb2[o];
    #pragma unroll 4
    for(int c=0;c<128;c++) a5 += s_a[r][c]*pw2[c*6+o];
    s_res[r][o] = a5;
  }
  __syncthreads();
  if(d < 2){
    int r = d; int row = r0+r; int b=row/NQ, n=row%NQ;
    const int O1 = BB*CC*NQ;
    const int O2 = O1 + BB*NQ*2;
    const int O3 = O2 + BB*2*NQ;
    const int O4 = O3 + BB*4*NQ;
    float p0=qpos[row*2], p1=qpos[row*2+1];
    float cr0 = s_res[r][0]+p0, cr1 = s_res[r][1]+p1;
    dout[O1 + row*2]   = cr0;
    dout[O1 + row*2+1] = cr1;
    float cen0 = sigm(cr0), cen1 = sigm(cr1);
    dout[O2 + (b*2+0)*NQ + n] = cen0;
    dout[O2 + (b*2+1)*NQ + n] = cen1;
    float f0=sigm(s_res[r][2]), f1=sigm(s_res[r][3]), f2=sigm(s_res[r][4]), f3=sigm(s_res[r][5]);
    dout[O3 + (b*4+0)*NQ + n] = f0;
    dout[O3 + (b*4+1)*NQ + n] = f1;
    dout[O3 + (b*4+2)*NQ + n] = f2;
    dout[O3 + (b*4+3)*NQ + n] = f3;
    float bw=f0+f2, bh=f1+f3;
    float cx=(2.f*cen0 - f0 + f2)*0.5f;
    float cy=(2.f*cen1 - f1 + f3)*0.5f;
    dout[O4 + (b*4+0)*NQ + n] = cx;
    dout[O4 + (b*4+1)*NQ + n] = cy;
    dout[O4 + (b*4+2)*NQ + n] = bw;
    dout[O4 + (b*4+3)*NQ + n] = bh;
  }
}

extern "C" void kernel_launch(void* const* d_in, const int* in_sizes, int n_in,
                              void* d_out, int out_size, void* d_ws, size_t ws_size,
                              hipStream_t stream){
  (void)in_sizes; (void)n_in; (void)out_size; (void)ws_size;
  const float* in_iqf  = (const float*)d_in[0];
  const float* in_qpos = (const float*)d_in[1];
  const float* in_feat[4] = {(const float*)d_in[2],(const float*)d_in[3],(const float*)d_in[4],(const float*)d_in[5]};
  const float* in_kpos = (const float*)d_in[6];
  const float* sp_w1=(const float*)d_in[7], *sp_b1=(const float*)d_in[8], *sp_w2=(const float*)d_in[9], *sp_b2=(const float*)d_in[10];
  const float* cp_w1=(const float*)d_in[11], *cp_b1=(const float*)d_in[12], *cp_w2=(const float*)d_in[13], *cp_b2=(const float*)d_in[14];
  const float* sa_wqkv=(const float*)d_in[15], *sa_bqkv=(const float*)d_in[16], *sa_wo=(const float*)d_in[17], *sa_bo=(const float*)d_in[18];
  const float* ln1_g=(const float*)d_in[19], *ln1_b=(const float*)d_in[20];
  const float* dvw=(const float*)d_in[21], *dvb=(const float*)d_in[22];
  const float* dow=(const float*)d_in[23], *dob=(const float*)d_in[24];
  const float* daw=(const float*)d_in[25], *dab=(const float*)d_in[26];
  const float* dOw=(const float*)d_in[27], *dOb=(const float*)d_in[28];
  const float* ln2_g=(const float*)d_in[29], *ln2_b=(const float*)d_in[30];
  const float* fw1=(const float*)d_in[31], *fb1=(const float*)d_in[32], *fw2=(const float*)d_in[33], *fb2=(const float*)d_in[34];
  const float* ln3_g=(const float*)d_in[35], *ln3_b=(const float*)d_in[36];
  const float* pw1=(const float*)d_in[37], *pb1=(const float*)d_in[38], *pw2=(const float*)d_in[39], *pb2=(const float*)d_in[40];
  const int* in_view = (const int*)d_in[41];
  float* out = (float*)d_out;

  char* ws = (char*)d_ws;
  unsigned short* value = (unsigned short*)ws;                       // 91,392,000 B
  unsigned short* kvpe  = (unsigned short*)(ws + 91392000);          //  7,616,000 B
  float* f = (float*)(ws + 91392000 + 7616000);
  float* qpe  = f;               // 307200
  float* x    = f + 307200;      // 307200
  float* qkv  = f + 614400;      // 921600
  float* att  = f + 1536000;     // 307200
  float* offb = f + 2150400;     // 614400
  float* awb  = f + 2764800;     // 307200
  int* counts = (int*)(f + 4300800);   // 12 ints
  int* order  = (int*)(f + 4300816);   // B*VV*NQ = 14400 ints
  unsigned short* wtb   = (unsigned short*)(f + 4315216);  // 32768 B
  unsigned short* cw2tb = (unsigned short*)(f + 4323408);  // 32768 B

  k_misc<<<dim3(BB+32+76+600),dim3(256),0,stream>>>(in_view,order,counts,dvw,wtb,
      cp_w2,cw2tb,in_iqf,x,in_qpos,sp_w1,sp_b1,sp_w2,sp_b2,qpe);
  k_kvpe_qkv<<<dim3(NKVPE + 300),dim3(256),0,stream>>>(in_kpos,cp_w1,cp_b1,cw2tb,cp_b2,wtb,dvb,kvpe,
      x,qpe,sa_wqkv,sa_bqkv,qkv);
  k_value_attn2<<<dim3(NATT + 466*12),dim3(256),0,stream>>>(in_feat[0],in_feat[1],in_feat[2],in_feat[3],
      kvpe,wtb,value,qkv,order,counts,att);
  k_q2<<<dim3(NROWS/8),dim3(384),0,stream>>>(att,sa_wo,sa_bo,x,ln1_g,ln1_b,qpe,
      dow,dob,daw,dab,offb,awb);
  k_tail3<<<dim3(NROWS/2),dim3(128),0,stream>>>(in_qpos,in_view,offb,awb,value,
      dOw,dOb,x,ln2_g,ln2_b,fw1,fb1,fw2,fb2,ln3_g,ln3_b,pw1,pb1,pw2,pb2,counts,out);
}

// Round 15
// 198.569 us; speedup vs baseline: 1.9654x; 1.0447x over previous
//
#include <hip/hip_runtime.h>
#include <hip/hip_bf16.h>
#include <math.h>

#define DEV __device__ __forceinline__

#define BB 2
#define VV 6
#define CC 128
#define NQ 1200
#define HH 8
#define PTSN 4
#define FFND 256
#define LVLSN 4
#define LTOT 29750
#define NROWS (BB*NQ)

__constant__ int c_W[4] = {200,100,50,25};
__constant__ int c_H[4] = {112,56,28,14};
__constant__ int c_S[4] = {0,22400,28000,29400};

DEV float bflo(unsigned u){ union{unsigned i; float f;}x; x.i = u<<16; return x.f; }
DEV float bfhi(unsigned u){ union{unsigned i; float f;}x; x.i = u&0xffff0000u; return x.f; }
DEV unsigned short f2bf(float f){ union{float f; unsigned i;}x; x.f=f; unsigned i=x.i;
  return (unsigned short)((i + 0x7fffu + ((i>>16)&1u))>>16); }
DEV unsigned addbf2(unsigned a, unsigned b){
  float lo = bflo(a)+bflo(b); float hi = bfhi(a)+bfhi(b);
  return (unsigned)f2bf(lo) | ((unsigned)f2bf(hi)<<16);
}
DEV float sigm(float z){ return 1.f/(1.f+__expf(-z)); }

typedef __attribute__((ext_vector_type(8))) short bf16x8;
typedef __attribute__((ext_vector_type(4))) float f32x4;

// ---------------- fused setup: bucket(2) + wt(16) + cw2t(16) + xpose(76) + qpe(600) ----------------
__global__ void k_misc(const int* __restrict__ view, int* __restrict__ order,
                       int* __restrict__ counts,
                       const float* __restrict__ vw, unsigned short* __restrict__ wt,
                       const float* __restrict__ cw2, unsigned short* __restrict__ cw2t,
                       const float* __restrict__ iqf, float* __restrict__ x,
                       const float* __restrict__ pos,
                       const float* __restrict__ w1, const float* __restrict__ b1,
                       const float* __restrict__ w2, const float* __restrict__ b2,
                       float* __restrict__ qpe){
  int bid = blockIdx.x;
  int t = threadIdx.x;
  if(bid < BB){
    if(t < 64){
      int b = bid; int lane = t;
      int base0=0,base1=0,base2=0,base3=0,base4=0,base5=0;
      for(int c0=0;c0<NQ;c0+=64){
        int n = c0 + lane;
        int v = (n<NQ) ? view[b*NQ+n] : -1;
        unsigned long long lower = (lane==63)? 0x7fffffffffffffffull : ((1ull<<lane)-1ull);
        #define BUCKET_STEP(VVV, BASE) { \
          unsigned long long mk = __ballot(v==VVV); \
          if(v==VVV){ int r = BASE + __popcll(mk & lower); order[(b*VV+VVV)*NQ + r] = n; } \
          BASE += __popcll(mk); }
        BUCKET_STEP(0, base0) BUCKET_STEP(1, base1) BUCKET_STEP(2, base2)
        BUCKET_STEP(3, base3) BUCKET_STEP(4, base4) BUCKET_STEP(5, base5)
        #undef BUCKET_STEP
      }
      if(lane==0){
        counts[b*VV+0]=base0; counts[b*VV+1]=base1; counts[b*VV+2]=base2;
        counts[b*VV+3]=base3; counts[b*VV+4]=base4; counts[b*VV+5]=base5;
      }
    }
  } else if(bid < BB+16){
    int d0 = (bid-BB)*8;
    __shared__ float s[128][9];
    #pragma unroll
    for(int p=0;p<4;p++){ int i = t + p*256; int c = i>>3, dd = i&7;
      s[c][dd] = vw[c*128 + d0 + dd]; }
    __syncthreads();
    #pragma unroll
    for(int p=0;p<4;p++){ int i = t + p*256; int dd = i>>7, c = i&127;
      wt[(size_t)(d0+dd)*128 + c] = f2bf(s[c][dd]); }
  } else if(bid < BB+32){
    int d0 = (bid-BB-16)*8;
    __shared__ float s[128][9];
    #pragma unroll
    for(int p=0;p<4;p++){ int i = t + p*256; int c = i>>3, dd = i&7;
      s[c][dd] = cw2[c*128 + d0 + dd]; }
    __syncthreads();
    #pragma unroll
    for(int p=0;p<4;p++){ int i = t + p*256; int dd = i>>7, c = i&127;
      cw2t[(size_t)(d0+dd)*128 + c] = f2bf(s[c][dd]); }
  } else if(bid < BB+32+76){
    __shared__ float tile[128][33];
    int idx = bid - (BB+32);
    int b = idx/38; int n0 = (idx%38)*32;
    for(int i=t;i<128*32;i+=256){ int c=i>>5, nn=i&31; int n=n0+nn;
      tile[c][nn] = (n<NQ)? iqf[((size_t)b*CC + c)*NQ + n] : 0.f; }
    __syncthreads();
    for(int i=t;i<32*128;i+=256){ int nn=i>>7, c=i&127;
      int n=n0+nn; if(n<NQ) x[((size_t)b*NQ+n)*128 + c] = tile[c][nn]; }
  } else {
    __shared__ float hid[4][128];
    int row0 = (bid - (BB+32+76))*4;
    int r = t>>7, d = t&127;
    #pragma unroll
    for(int rr=r; rr<4; rr+=2){
      int row = row0 + rr;
      float p0 = pos[row*2+0], p1 = pos[row*2+1];
      hid[rr][d] = fmaxf(p0*w1[d] + p1*w1[128+d] + b1[d], 0.f);
    }
    __syncthreads();
    #pragma unroll
    for(int rr=r; rr<4; rr+=2){
      float acc = b2[d];
      #pragma unroll 4
      for(int c=0;c<128;c++) acc += hid[rr][c]*w2[c*128 + d];
      qpe[(size_t)(row0+rr)*128+d] = acc;
    }
  }
}

// ---------------- merged: kvpe MFMA (blocks 0..464) + qkv matvec (blocks 465..764) ----------------
#define NKVPE 465
__global__ void __launch_bounds__(256) k_kvpe_qkv(
    const float* __restrict__ kpos,
    const float* __restrict__ cw1, const float* __restrict__ cb1,
    const unsigned short* __restrict__ cw2t, const float* __restrict__ cb2,
    const unsigned short* __restrict__ wt, const float* __restrict__ vb,
    unsigned short* __restrict__ kvpe,
    const float* __restrict__ x, const float* __restrict__ qpe,
    const float* __restrict__ sa_wqkv, const float* __restrict__ sa_bqkv,
    float* __restrict__ qkv){
  __shared__ unsigned short h_t[64][136];
  __shared__ unsigned short k_t[64][136];
  int t = threadIdx.x;
  int bid = blockIdx.x;
  if(bid >= NKVPE){
    float (*s_q)[128] = (float(*)[128])h_t;
    int r0 = (bid - NKVPE)*8;
    for(int i=t;i<1024;i+=256){ int r=i>>7, c=i&127;
      size_t row = (size_t)(r0+r);
      s_q[r][c] = x[row*128+c] + qpe[row*128+c]; }
    __syncthreads();
    for(int d=t; d<384; d+=256){
      float acc[8];
      #pragma unroll
      for(int r=0;r<8;r++) acc[r]=sa_bqkv[d];
      #pragma unroll 4
      for(int c=0;c<128;c++){ float wv = sa_wqkv[c*384+d];
        #pragma unroll
        for(int r=0;r<8;r++) acc[r] += s_q[r][c]*wv; }
      #pragma unroll
      for(int r=0;r<8;r++) qkv[(size_t)(r0+r)*384+d]=acc[r];
    }
    return;
  }
  int r0 = bid*64;
  int lane = t&63, wave = t>>6;
  int fr = lane&15, kg = lane>>4;

  int p = t & 63;
  int d0 = p*2;
  float w1a0 = cw1[d0],     w1a1 = cw1[d0+1];
  float w1b0 = cw1[128+d0], w1b1 = cw1[128+d0+1];
  float b10 = cb1[d0], b11 = cb1[d0+1];
  #pragma unroll 4
  for(int k=0;k<16;k++){
    int r = wave + k*4;
    int row = r0 + r;
    float p0=0.f, p1=0.f;
    if(row < LTOT){ p0 = kpos[row*2]; p1 = kpos[row*2+1]; }
    float h0 = fmaxf(p0*w1a0 + p1*w1b0 + b10, 0.f);
    float h1 = fmaxf(p0*w1a1 + p1*w1b1 + b11, 0.f);
    *reinterpret_cast<unsigned*>(&h_t[r][d0]) = (unsigned)f2bf(h0) | ((unsigned)f2bf(h1)<<16);
  }
  __syncthreads();

  f32x4 acc[4][2];
  #pragma unroll
  for(int i=0;i<4;i++)
    #pragma unroll
    for(int j=0;j<2;j++) acc[i][j] = (f32x4)0.f;
  #pragma unroll
  for(int ck=0; ck<4; ck++){
    int c0 = ck*32;
    bf16x8 bfr[2], af[4];
    #pragma unroll
    for(int j=0;j<2;j++){ int d = wave*32 + j*16 + fr;
      bfr[j] = *reinterpret_cast<const bf16x8*>(cw2t + (size_t)d*128 + c0 + kg*8); }
    #pragma unroll
    for(int i=0;i<4;i++) af[i] = *reinterpret_cast<const bf16x8*>(&h_t[i*16 + fr][c0 + kg*8]);
    #pragma unroll
    for(int i=0;i<4;i++)
      #pragma unroll
      for(int j=0;j<2;j++)
        acc[i][j] = __builtin_amdgcn_mfma_f32_16x16x32_bf16(af[i], bfr[j], acc[i][j], 0, 0, 0);
  }
  #pragma unroll
  for(int i=0;i<4;i++){
    int rbase = i*16 + kg*4;
    #pragma unroll
    for(int j=0;j<2;j++){
      int d = wave*32 + j*16 + fr;
      float bv_ = cb2[d];
      #pragma unroll
      for(int r=0;r<4;r++) k_t[rbase + r][d] = f2bf(acc[i][j][r] + bv_);
    }
  }
  __syncthreads();

  #pragma unroll
  for(int i=0;i<4;i++)
    #pragma unroll
    for(int j=0;j<2;j++) acc[i][j] = (f32x4)0.f;
  #pragma unroll
  for(int ck=0; ck<4; ck++){
    int c0 = ck*32;
    bf16x8 bfr[2], af[4];
    #pragma unroll
    for(int j=0;j<2;j++){ int d = wave*32 + j*16 + fr;
      bfr[j] = *reinterpret_cast<const bf16x8*>(wt + (size_t)d*128 + c0 + kg*8); }
    #pragma unroll
    for(int i=0;i<4;i++) af[i] = *reinterpret_cast<const bf16x8*>(&k_t[i*16 + fr][c0 + kg*8]);
    #pragma unroll
    for(int i=0;i<4;i++)
      #pragma unroll
      for(int j=0;j<2;j++)
        acc[i][j] = __builtin_amdgcn_mfma_f32_16x16x32_bf16(af[i], bfr[j], acc[i][j], 0, 0, 0);
  }
  __syncthreads();
  unsigned short (*c_l)[136] = h_t;
  #pragma unroll
  for(int i=0;i<4;i++){
    int rbase = i*16 + kg*4;
    #pragma unroll
    for(int j=0;j<2;j++){
      int d = wave*32 + j*16 + fr;
      float bv_ = vb[d];
      #pragma unroll
      for(int r=0;r<4;r++) c_l[rbase + r][d] = f2bf(acc[i][j][r] + bv_);
    }
  }
  __syncthreads();
  #pragma unroll
  for(int p4=0;p4<4;p4++){
    int i = t + p4*256;
    int row = i>>4, seg = i&15;
    int glr = r0 + row;
    if(glr < LTOT){
      uint4 cu = *reinterpret_cast<const uint4*>(&c_l[row][seg*8]);
      *reinterpret_cast<uint4*>(kvpe + (size_t)glr*CC + seg*8) = cu;
    }
  }
}

// ---------------- merged: self-attention (blocks 0..1823, reads qkv) + value GEMM ----------------
#define NATT (19*48*2)
#define QT2 64
#define KTA 64
__global__ void __launch_bounds__(256) k_value_attn2(
    const float* __restrict__ f0, const float* __restrict__ f1,
    const float* __restrict__ f2, const float* __restrict__ f3,
    const unsigned short* __restrict__ kvpe, const unsigned short* __restrict__ wt,
    unsigned short* __restrict__ value,
    const float* __restrict__ qkv,
    const int* __restrict__ order, const int* __restrict__ counts,
    float* __restrict__ att){
  __shared__ __align__(16) char smem[18688];
  int t = threadIdx.x;
  int bid = blockIdx.x;
  if(bid < NATT){
    int qt = bid % 19;
    int vh = (bid/19) % 48;
    int b  = bid/(19*48);
    int v = vh>>3, h = vh&7;
    int C = counts[b*VV+v];
    int q0 = qt*QT2;
    if(q0 >= C) return;
    const int* ord = order + (size_t)(b*VV+v)*NQ;
    float (*q_s)[17] = (float(*)[17])smem;
    float (*k_s)[16] = (float(*)[16])(smem + 4352);
    float (*v_s)[16] = (float(*)[16])(smem + 8448);
    float (*red)[QT2][18] = (float(*)[QT2][18])smem;
    int* qn_s = (int*)(smem + 18432);
    for(int i=t;i<QT2;i+=256){ int qi=q0+i; qn_s[i] = (qi<C)? ord[qi] : -1; }
    __syncthreads();
    for(int i=t;i<QT2*16;i+=256){ int r=i>>4,c=i&15; int n=qn_s[r];
      q_s[r][c] = (n>=0)? qkv[((size_t)b*NQ+n)*384 + h*16 + c] : 0.f; }
    int qi = t&63, sub = t>>6;
    float m = -1e30f, s = 0.f, acc[16];
    #pragma unroll
    for(int c=0;c<16;c++) acc[c]=0.f;
    for(int k0=0; k0<C; k0+=KTA){
      int kn = C-k0; if(kn>KTA) kn=KTA;
      __syncthreads();
      for(int i=t;i<KTA*16;i+=256){ int r=i>>4,c=i&15;
        float kv=0.f, vv=0.f;
        if(r<kn){ int n=ord[k0+r]; size_t base=((size_t)b*NQ+n)*384 + h*16 + c;
          kv = qkv[base+128]; vv = qkv[base+256]; }
        k_s[r][c]=kv; v_s[r][c]=vv; }
      __syncthreads();
      for(int mm=sub; mm<kn; mm+=4){
        float l=0.f;
        #pragma unroll
        for(int c=0;c<16;c++) l += q_s[qi][c]*k_s[mm][c];
        l *= 0.25f;
        float newm = fmaxf(m,l);
        float e = __expf(l - newm);
        if(newm > m){
          float rr = __expf(m - newm);
          s *= rr;
          #pragma unroll
          for(int c=0;c<16;c++) acc[c]*=rr;
          m = newm;
        }
        s += e;
        #pragma unroll
        for(int c=0;c<16;c++) acc[c] += e*v_s[mm][c];
      }
    }
    __syncthreads();
    red[sub][qi][0]=m; red[sub][qi][1]=s;
    #pragma unroll
    for(int c=0;c<16;c++) red[sub][qi][2+c]=acc[c];
    __syncthreads();
    if(sub==0){
      int n = qn_s[qi];
      if(n>=0){
        float M=-1e30f;
        #pragma unroll
        for(int j=0;j<4;j++) M=fmaxf(M,red[j][qi][0]);
        float S=0.f; float o[16];
        #pragma unroll
        for(int c=0;c<16;c++) o[c]=0.f;
        #pragma unroll
        for(int j=0;j<4;j++){ float e=__expf(red[j][qi][0]-M); S += e*red[j][qi][1];
          #pragma unroll
          for(int c=0;c<16;c++) o[c] += e*red[j][qi][2+c]; }
        float inv = 1.f/S;
        #pragma unroll
        for(int c=0;c<16;c++) att[((size_t)b*NQ+n)*128 + h*16 + c] = o[c]*inv;
      }
    }
    return;
  }
  unsigned short (*a_t)[136] = (unsigned short(*)[136])smem;
  int bxy = bid - NATT;
  int bv = bxy % 12;
  int bx = bxy / 12;
  int lvl, tile;
  if(bx < 350){ lvl=0; tile=bx; }
  else if(bx < 438){ lvl=1; tile=bx-350; }
  else if(bx < 460){ lvl=2; tile=bx-438; }
  else { lvl=3; tile=bx-460; }
  const int HW = (lvl==0)?22400:(lvl==1)?5600:(lvl==2)?1400:350;
  const int startL = (lvl==0)?0:(lvl==1)?22400:(lvl==2)?28000:29400;
  const float* feat = (lvl==0)?f0:(lvl==1)?f1:(lvl==2)?f2:f3;
  const float* fbase = feat + (size_t)bv*128*(size_t)HW;
  int l0 = tile*64;

  int lane = t&63, wave = t>>6;
  int fr = lane&15, kg = lane>>4;

  int l_u = t & 63, oct0 = t>>6;
  int gl = l0 + l_u; bool ok = (gl < HW);
  const float* fcol = fbase + (size_t)(oct0*8)*HW + (ok ? gl : 0);

  float v32[4][8];
  #pragma unroll
  for(int q=0;q<4;q++)
    #pragma unroll
    for(int j=0;j<8;j++)
      v32[q][j] = ok ? fcol[(size_t)(q*32+j)*HW] : 0.f;

  #pragma unroll
  for(int q=0;q<4;q++){
    uint4 u;
    u.x = (unsigned)f2bf(v32[q][0]) | ((unsigned)f2bf(v32[q][1])<<16);
    u.y = (unsigned)f2bf(v32[q][2]) | ((unsigned)f2bf(v32[q][3])<<16);
    u.z = (unsigned)f2bf(v32[q][4]) | ((unsigned)f2bf(v32[q][5])<<16);
    u.w = (unsigned)f2bf(v32[q][6]) | ((unsigned)f2bf(v32[q][7])<<16);
    *reinterpret_cast<uint4*>(&a_t[l_u][oct0*8 + q*32]) = u;
  }
  __syncthreads();

  f32x4 acc[4][2];
  #pragma unroll
  for(int i=0;i<4;i++)
    #pragma unroll
    for(int j=0;j<2;j++) acc[i][j] = (f32x4)0.f;

  #pragma unroll
  for(int ck=0; ck<4; ck++){
    int c0 = ck*32;
    bf16x8 bfr[2];
    #pragma unroll
    for(int j=0;j<2;j++){
      int d = wave*32 + j*16 + fr;
      bfr[j] = *reinterpret_cast<const bf16x8*>(wt + (size_t)d*128 + c0 + kg*8);
    }
    bf16x8 af[4];
    #pragma unroll
    for(int i=0;i<4;i++) af[i] = *reinterpret_cast<const bf16x8*>(&a_t[i*16 + fr][c0 + kg*8]);
    #pragma unroll
    for(int i=0;i<4;i++)
      #pragma unroll
      for(int j=0;j<2;j++)
        acc[i][j] = __builtin_amdgcn_mfma_f32_16x16x32_bf16(af[i], bfr[j], acc[i][j], 0, 0, 0);
  }

  __syncthreads();
  unsigned short (*c_l)[136] = a_t;
  #pragma unroll
  for(int i=0;i<4;i++){
    int rbase = i*16 + kg*4;
    #pragma unroll
    for(int j=0;j<2;j++){
      int d = wave*32 + j*16 + fr;
      #pragma unroll
      for(int r=0;r<4;r++) c_l[rbase + r][d] = f2bf(acc[i][j][r]);
    }
  }
  __syncthreads();
  #pragma unroll
  for(int p=0;p<4;p++){
    int i = t + p*256;
    int row = i>>4, seg = i&15;
    int glr = l0 + row;
    if(glr < HW){
      uint4 cu = *reinterpret_cast<const uint4*>(&c_l[row][seg*8]);
      const uint4 ku = *reinterpret_cast<const uint4*>(kvpe + (size_t)(startL+glr)*CC + seg*8);
      uint4 ou;
      ou.x = addbf2(cu.x, ku.x); ou.y = addbf2(cu.y, ku.y);
      ou.z = addbf2(cu.z, ku.z); ou.w = addbf2(cu.w, ku.w);
      *reinterpret_cast<uint4*>(value + ((size_t)bv*LTOT + startL + glr)*CC + seg*8) = ou;
    }
  }
}

// ---------------- fully fused tail (2 rows/block): proj_ln1 + off/aw + sample + LN2/FFN/LN3 + head ----------------
__global__ void __launch_bounds__(128) k_tail4(
    const float* __restrict__ att, const float* __restrict__ sa_wo, const float* __restrict__ sa_bo,
    const float* __restrict__ xres, const float* __restrict__ ln1_g, const float* __restrict__ ln1_b,
    const float* __restrict__ qpe,
    const float* __restrict__ dow, const float* __restrict__ dob,
    const float* __restrict__ daw, const float* __restrict__ dab,
    const float* __restrict__ qpos, const int* __restrict__ view,
    const unsigned short* __restrict__ value,
    const float* __restrict__ dOw, const float* __restrict__ dOb,
    const float* __restrict__ ln2_g, const float* __restrict__ ln2_b,
    const float* __restrict__ fw1, const float* __restrict__ fb1,
    const float* __restrict__ fw2, const float* __restrict__ fb2,
    const float* __restrict__ ln3_g, const float* __restrict__ ln3_b,
    const float* __restrict__ pw1, const float* __restrict__ pb1,
    const float* __restrict__ pw2, const float* __restrict__ pb2,
    const int* __restrict__ counts, float* __restrict__ dout){
  int r0 = blockIdx.x*2; int d = threadIdx.x;  // 128 threads, 2 rows
  __shared__ float s_a[2][256];     // att in / FFN hidden
  __shared__ float s_x1[2][128];    // LN1 out (qc source + LN2 residual)
  __shared__ float s_qc[2][128];
  __shared__ float s_off[2][256];
  __shared__ float s_awr[2][130];
  __shared__ float s_x[2][128];
  __shared__ float s_m[2][2][2];
  __shared__ float s_res[2][6];
  __shared__ float sred[128][17];
  __shared__ float s_ca[2][128];
  int lane = d&63, wid = d>>6;
  float v[2];

  // ---- phase A: o-proj + residual + LN1 ----
  #pragma unroll
  for(int r=0;r<2;r++) s_a[r][d] = att[(size_t)(r0+r)*128 + d];
  __syncthreads();
  float acc[2];
  #pragma unroll
  for(int r=0;r<2;r++) acc[r]=sa_bo[d];
  #pragma unroll 4
  for(int c=0;c<128;c++){ float wv = sa_wo[c*128+d];
    #pragma unroll
    for(int r=0;r<2;r++) acc[r] += s_a[r][c]*wv; }
  #pragma unroll
  for(int r=0;r<2;r++){
    v[r] = acc[r] + xres[(size_t)(r0+r)*128 + d];
    float s1=v[r], s2=v[r]*v[r];
    for(int o=32;o>0;o>>=1){ s1 += __shfl_down(s1,o); s2 += __shfl_down(s2,o); }
    if(lane==0){ s_m[r][wid][0]=s1; s_m[r][wid][1]=s2; }
  }
  __syncthreads();
  #pragma unroll
  for(int r=0;r<2;r++){
    float S1=s_m[r][0][0]+s_m[r][1][0], S2=s_m[r][0][1]+s_m[r][1][1];
    float mean=S1*(1.f/128.f), var=S2*(1.f/128.f)-mean*mean;
    float rs=rsqrtf(var+1e-5f);
    float o=(v[r]-mean)*rs*ln1_g[d]+ln1_b[d];
    s_x1[r][d]=o;
    s_qc[r][d]=o+qpe[(size_t)(r0+r)*128+d];
  }
  __syncthreads();

  // ---- phase B: offset matvec (256) + aw matvec (128) + per-head softmax ----
  float o0[2], o1[2], aw[2];
  #pragma unroll
  for(int r=0;r<2;r++){ o0[r]=dob[d]; o1[r]=dob[d+128]; aw[r]=dab[d]; }
  #pragma unroll 4
  for(int c=0;c<128;c++){
    float w0 = dow[(size_t)c*256+d], w1_ = dow[(size_t)c*256+d+128];
    float wa = daw[(size_t)c*128+d];
    #pragma unroll
    for(int r=0;r<2;r++){ float q = s_qc[r][c]; o0[r]+=q*w0; o1[r]+=q*w1_; aw[r]+=q*wa; }
  }
  #pragma unroll
  for(int r=0;r<2;r++){ s_off[r][d]=o0[r]; s_off[r][d+128]=o1[r]; s_awr[r][d]=aw[r]; }
  __syncthreads();
  if(d < 16){
    int r = d>>3, h = d&7;
    float mx=-1e30f;
    #pragma unroll
    for(int i=0;i<16;i++) mx = fmaxf(mx, s_awr[r][h*16+i]);
    float e[16]; float sm=0.f;
    #pragma unroll
    for(int i=0;i<16;i++){ e[i]=__expf(s_awr[r][h*16+i]-mx); sm+=e[i]; }
    float inv = 1.f/sm;
    #pragma unroll
    for(int i=0;i<16;i++) s_awr[r][h*16+i] = e[i]*inv;
  }
  __syncthreads();

  // ---- phase C: bilinear sample ----
  int h = d>>4, lp = d&15, lvl = lp>>2;
  int w = c_W[lvl], hh = c_H[lvl];
  float samp[2][16]; float aw2[2];
  int vw2[2];
  #pragma unroll
  for(int r=0;r<2;r++){
    size_t row = (size_t)(r0+r);
    int b = (r0+r)/NQ;
    float rx = sigm(qpos[row*2]), ry = sigm(qpos[row*2+1]);
    int vw = view[row]; vw2[r]=vw;
    float ox = s_off[r][d*2], oy = s_off[r][d*2+1];
    aw2[r] = s_awr[r][d];
    float lx = rx*(float)w + ox - 0.5f;
    float ly = ry*(float)hh + oy - 0.5f;
    float x0f = floorf(lx), y0f = floorf(ly);
    float fx = lx - x0f, fy = ly - y0f;
    int x0 = (int)x0f, y0 = (int)y0f;
    #pragma unroll
    for(int c=0;c<16;c++) samp[r][c]=0.f;
    size_t brow = ((size_t)(b*VV + vw))*LTOT + c_S[lvl];
    #pragma unroll
    for(int dy=0;dy<2;dy++){
      #pragma unroll
      for(int dx=0;dx<2;dx++){
        int xi=x0+dx, yi=y0+dy;
        if(xi<0||xi>=w||yi<0||yi>=hh) continue;
        float wt = (dx?fx:(1.f-fx))*(dy?fy:(1.f-fy));
        const uint4* vp = reinterpret_cast<const uint4*>(value + (brow + (size_t)yi*w + xi)*CC + h*16);
        uint4 u0 = vp[0], u1 = vp[1];
        samp[r][0] += wt*bflo(u0.x); samp[r][1] += wt*bfhi(u0.x);
        samp[r][2] += wt*bflo(u0.y); samp[r][3] += wt*bfhi(u0.y);
        samp[r][4] += wt*bflo(u0.z); samp[r][5] += wt*bfhi(u0.z);
        samp[r][6] += wt*bflo(u0.w); samp[r][7] += wt*bfhi(u0.w);
        samp[r][8] += wt*bflo(u1.x); samp[r][9] += wt*bfhi(u1.x);
        samp[r][10]+= wt*bflo(u1.y); samp[r][11]+= wt*bfhi(u1.y);
        samp[r][12]+= wt*bflo(u1.z); samp[r][13]+= wt*bfhi(u1.z);
        samp[r][14]+= wt*bflo(u1.w); samp[r][15]+= wt*bfhi(u1.w);
      }
    }
  }
  #pragma unroll
  for(int r=0;r<2;r++){
    #pragma unroll
    for(int c=0;c<16;c++) sred[d][c] = aw2[r]*samp[r][c];
    __syncthreads();
    int h2=d>>4, c2=d&15;
    float sum=0.f;
    #pragma unroll
    for(int j=0;j<16;j++) sum += sred[h2*16+j][c2];
    s_ca[r][d] = sum;
    __syncthreads();
  }

  // ---- phase D: proj2 + resid(LN1 out) + LN2 ----
  #pragma unroll
  for(int r=0;r<2;r++) s_a[r][d] = s_ca[r][d];
  __syncthreads();
  #pragma unroll
  for(int r=0;r<2;r++) acc[r]=dOb[d];
  #pragma unroll 4
  for(int c=0;c<128;c++){ float wv = dOw[c*128+d];
    #pragma unroll
    for(int r=0;r<2;r++) acc[r] += s_a[r][c]*wv; }
  #pragma unroll
  for(int r=0;r<2;r++){
    v[r] = acc[r] + s_x1[r][d];
    float s1=v[r], s2=v[r]*v[r];
    for(int o=32;o>0;o>>=1){ s1 += __shfl_down(s1,o); s2 += __shfl_down(s2,o); }
    if(lane==0){ s_m[r][wid][0]=s1; s_m[r][wid][1]=s2; }
  }
  __syncthreads();
  #pragma unroll
  for(int r=0;r<2;r++){
    float S1=s_m[r][0][0]+s_m[r][1][0], S2=s_m[r][0][1]+s_m[r][1][1];
    float mean=S1*(1.f/128.f), var=S2*(1.f/128.f)-mean*mean;
    float rs=rsqrtf(var+1e-5f);
    s_x[r][d]=(v[r]-mean)*rs*ln2_g[d]+ln2_b[d];
  }
  __syncthreads();

  // ---- FFN1 ----
  float a2a[2], a2b[2];
  #pragma unroll
  for(int r=0;r<2;r++){ a2a[r]=fb1[d]; a2b[r]=fb1[d+128]; }
  #pragma unroll 4
  for(int c=0;c<128;c++){ float w0 = fw1[c*256+d], w1_ = fw1[c*256+d+128];
    #pragma unroll
    for(int r=0;r<2;r++){ float xv = s_x[r][c]; a2a[r] += xv*w0; a2b[r] += xv*w1_; } }
  __syncthreads();
  #pragma unroll
  for(int r=0;r<2;r++){ s_a[r][d]=fmaxf(a2a[r],0.f); s_a[r][d+128]=fmaxf(a2b[r],0.f); }
  __syncthreads();

  // ---- FFN2 + resid + LN3 + valid-zero ----
  float a3[2];
  #pragma unroll
  for(int r=0;r<2;r++) a3[r]=fb2[d];
  #pragma unroll 4
  for(int c=0;c<256;c++){ float wv = fw2[c*128+d];
    #pragma unroll
    for(int r=0;r<2;r++) a3[r] += s_a[r][c]*wv; }
  #pragma unroll
  for(int r=0;r<2;r++){
    v[r] = a3[r] + s_x[r][d];
    float s1=v[r], s2=v[r]*v[r];
    for(int o=32;o>0;o>>=1){ s1 += __shfl_down(s1,o); s2 += __shfl_down(s2,o); }
    if(lane==0){ s_m[r][wid][0]=s1; s_m[r][wid][1]=s2; }
  }
  __syncthreads();
  #pragma unroll
  for(int r=0;r<2;r++){
    float S1=s_m[r][0][0]+s_m[r][1][0], S2=s_m[r][0][1]+s_m[r][1][1];
    float mean=S1*(1.f/128.f), var=S2*(1.f/128.f)-mean*mean;
    float rs=rsqrtf(var+1e-5f);
    float o=(v[r]-mean)*rs*ln3_g[d]+ln3_b[d];
    int row=r0+r; int b=row/NQ, n=row%NQ;
    bool val = counts[b*VV + vw2[r]] > 1;
    float oz = val ? o : 0.f;
    s_x[r][d]=oz;
    dout[((size_t)b*CC + d)*NQ + n]=oz;
  }
  __syncthreads();

  // ---- head ----
  float a4[2];
  #pragma unroll
  for(int r=0;r<2;r++) a4[r]=pb1[d];
  #pragma unroll 4
  for(int c=0;c<128;c++){ float wv = pw1[c*128+d];
    #pragma unroll
    for(int r=0;r<2;r++) a4[r] += s_x[r][c]*wv; }
  #pragma unroll
  for(int r=0;r<2;r++) s_a[r][d]=fmaxf(a4[r],0.f);
  __syncthreads();

  if(d < 12){
    int r = d/6, o = d%6;
    float a5 = pb2[o];
    #pragma unroll 4
    for(int c=0;c<128;c++) a5 += s_a[r][c]*pw2[c*6+o];
    s_res[r][o] = a5;
  }
  __syncthreads();
  if(d < 2){
    int r = d; int row = r0+r; int b=row/NQ, n=row%NQ;
    const int O1 = BB*CC*NQ;
    const int O2 = O1 + BB*NQ*2;
    const int O3 = O2 + BB*2*NQ;
    const int O4 = O3 + BB*4*NQ;
    float p0=qpos[row*2], p1=qpos[row*2+1];
    float cr0 = s_res[r][0]+p0, cr1 = s_res[r][1]+p1;
    dout[O1 + row*2]   = cr0;
    dout[O1 + row*2+1] = cr1;
    float cen0 = sigm(cr0), cen1 = sigm(cr1);
    dout[O2 + (b*2+0)*NQ + n] = cen0;
    dout[O2 + (b*2+1)*NQ + n] = cen1;
    float f0=sigm(s_res[r][2]), f1=sigm(s_res[r][3]), f2=sigm(s_res[r][4]), f3=sigm(s_res[r][5]);
    dout[O3 + (b*4+0)*NQ + n] = f0;
    dout[O3 + (b*4+1)*NQ + n] = f1;
    dout[O3 + (b*4+2)*NQ + n] = f2;
    dout[O3 + (b*4+3)*NQ + n] = f3;
    float bw=f0+f2, bh=f1+f3;
    float cx=(2.f*cen0 - f0 + f2)*0.5f;
    float cy=(2.f*cen1 - f1 + f3)*0.5f;
    dout[O4 + (b*4+0)*NQ + n] = cx;
    dout[O4 + (b*4+1)*NQ + n] = cy;
    dout[O4 + (b*4+2)*NQ + n] = bw;
    dout[O4 + (b*4+3)*NQ + n] = bh;
  }
}

extern "C" void kernel_launch(void* const* d_in, const int* in_sizes, int n_in,
                              void* d_out, int out_size, void* d_ws, size_t ws_size,
                              hipStream_t stream){
  (void)in_sizes; (void)n_in; (void)out_size; (void)ws_size;
  const float* in_iqf  = (const float*)d_in[0];
  const float* in_qpos = (const float*)d_in[1];
  const float* in_feat[4] = {(const float*)d_in[2],(const float*)d_in[3],(const float*)d_in[4],(const float*)d_in[5]};
  const float* in_kpos = (const float*)d_in[6];
  const float* sp_w1=(const float*)d_in[7], *sp_b1=(const float*)d_in[8], *sp_w2=(const float*)d_in[9], *sp_b2=(const float*)d_in[10];
  const float* cp_w1=(const float*)d_in[11], *cp_b1=(const float*)d_in[12], *cp_w2=(const float*)d_in[13], *cp_b2=(const float*)d_in[14];
  const float* sa_wqkv=(const float*)d_in[15], *sa_bqkv=(const float*)d_in[16], *sa_wo=(const float*)d_in[17], *sa_bo=(const float*)d_in[18];
  const float* ln1_g=(const float*)d_in[19], *ln1_b=(const float*)d_in[20];
  const float* dvw=(const float*)d_in[21], *dvb=(const float*)d_in[22];
  const float* dow=(const float*)d_in[23], *dob=(const float*)d_in[24];
  const float* daw=(const float*)d_in[25], *dab=(const float*)d_in[26];
  const float* dOw=(const float*)d_in[27], *dOb=(const float*)d_in[28];
  const float* ln2_g=(const float*)d_in[29], *ln2_b=(const float*)d_in[30];
  const float* fw1=(const float*)d_in[31], *fb1=(const float*)d_in[32], *fw2=(const float*)d_in[33], *fb2=(const float*)d_in[34];
  const float* ln3_g=(const float*)d_in[35], *ln3_b=(const float*)d_in[36];
  const float* pw1=(const float*)d_in[37], *pb1=(const float*)d_in[38], *pw2=(const float*)d_in[39], *pb2=(const float*)d_in[40];
  const int* in_view = (const int*)d_in[41];
  float* out = (float*)d_out;

  char* ws = (char*)d_ws;
  unsigned short* value = (unsigned short*)ws;                       // 91,392,000 B
  unsigned short* kvpe  = (unsigned short*)(ws + 91392000);          //  7,616,000 B
  float* f = (float*)(ws + 91392000 + 7616000);
  float* qpe  = f;               // 307200
  float* x    = f + 307200;      // 307200
  float* qkv  = f + 614400;      // 921600
  float* att  = f + 1536000;     // 307200
  int* counts = (int*)(f + 4300800);   // 12 ints
  int* order  = (int*)(f + 4300816);   // B*VV*NQ = 14400 ints
  unsigned short* wtb   = (unsigned short*)(f + 4315216);  // 32768 B
  unsigned short* cw2tb = (unsigned short*)(f + 4323408);  // 32768 B

  k_misc<<<dim3(BB+32+76+600),dim3(256),0,stream>>>(in_view,order,counts,dvw,wtb,
      cp_w2,cw2tb,in_iqf,x,in_qpos,sp_w1,sp_b1,sp_w2,sp_b2,qpe);
  k_kvpe_qkv<<<dim3(NKVPE + 300),dim3(256),0,stream>>>(in_kpos,cp_w1,cp_b1,cw2tb,cp_b2,wtb,dvb,kvpe,
      x,qpe,sa_wqkv,sa_bqkv,qkv);
  k_value_attn2<<<dim3(NATT + 466*12),dim3(256),0,stream>>>(in_feat[0],in_feat[1],in_feat[2],in_feat[3],
      kvpe,wtb,value,qkv,order,counts,att);
  k_tail4<<<dim3(NROWS/2),dim3(128),0,stream>>>(att,sa_wo,sa_bo,x,ln1_g,ln1_b,qpe,
      dow,dob,daw,dab,in_qpos,in_view,value,
      dOw,dOb,ln2_g,ln2_b,fw1,fb1,fw2,fb2,ln3_g,ln3_b,pw1,pb1,pw2,pb2,counts,out);
}

// Round 16
// 197.510 us; speedup vs baseline: 1.9759x; 1.0054x over previous
//
#include <hip/hip_runtime.h>
#include <hip/hip_bf16.h>
#include <math.h>

#define DEV __device__ __forceinline__

#define BB 2
#define VV 6
#define CC 128
#define NQ 1200
#define HH 8
#define PTSN 4
#define FFND 256
#define LVLSN 4
#define LTOT 29750
#define NROWS (BB*NQ)

__constant__ int c_W[4] = {200,100,50,25};
__constant__ int c_H[4] = {112,56,28,14};
__constant__ int c_S[4] = {0,22400,28000,29400};

DEV float bflo(unsigned u){ union{unsigned i; float f;}x; x.i = u<<16; return x.f; }
DEV float bfhi(unsigned u){ union{unsigned i; float f;}x; x.i = u&0xffff0000u; return x.f; }
DEV unsigned short f2bf(float f){ union{float f; unsigned i;}x; x.f=f; unsigned i=x.i;
  return (unsigned short)((i + 0x7fffu + ((i>>16)&1u))>>16); }
DEV unsigned addbf2(unsigned a, unsigned b){
  float lo = bflo(a)+bflo(b); float hi = bfhi(a)+bfhi(b);
  return (unsigned)f2bf(lo) | ((unsigned)f2bf(hi)<<16);
}
DEV float sigm(float z){ return 1.f/(1.f+__expf(-z)); }

typedef __attribute__((ext_vector_type(8))) short bf16x8;
typedef __attribute__((ext_vector_type(4))) float f32x4;

// ---------------- fused setup: bucket(2) + wt(16) + cw2t(16) + xpose(76) + qpe(600) ----------------
__global__ void k_misc(const int* __restrict__ view, int* __restrict__ order,
                       int* __restrict__ counts,
                       const float* __restrict__ vw, unsigned short* __restrict__ wt,
                       const float* __restrict__ cw2, unsigned short* __restrict__ cw2t,
                       const float* __restrict__ iqf, float* __restrict__ x,
                       const float* __restrict__ pos,
                       const float* __restrict__ w1, const float* __restrict__ b1,
                       const float* __restrict__ w2, const float* __restrict__ b2,
                       float* __restrict__ qpe){
  int bid = blockIdx.x;
  int t = threadIdx.x;
  if(bid < BB){
    if(t < 64){
      int b = bid; int lane = t;
      int base0=0,base1=0,base2=0,base3=0,base4=0,base5=0;
      for(int c0=0;c0<NQ;c0+=64){
        int n = c0 + lane;
        int v = (n<NQ) ? view[b*NQ+n] : -1;
        unsigned long long lower = (lane==63)? 0x7fffffffffffffffull : ((1ull<<lane)-1ull);
        #define BUCKET_STEP(VVV, BASE) { \
          unsigned long long mk = __ballot(v==VVV); \
          if(v==VVV){ int r = BASE + __popcll(mk & lower); order[(b*VV+VVV)*NQ + r] = n; } \
          BASE += __popcll(mk); }
        BUCKET_STEP(0, base0) BUCKET_STEP(1, base1) BUCKET_STEP(2, base2)
        BUCKET_STEP(3, base3) BUCKET_STEP(4, base4) BUCKET_STEP(5, base5)
        #undef BUCKET_STEP
      }
      if(lane==0){
        counts[b*VV+0]=base0; counts[b*VV+1]=base1; counts[b*VV+2]=base2;
        counts[b*VV+3]=base3; counts[b*VV+4]=base4; counts[b*VV+5]=base5;
      }
    }
  } else if(bid < BB+16){
    int d0 = (bid-BB)*8;
    __shared__ float s[128][9];
    #pragma unroll
    for(int p=0;p<4;p++){ int i = t + p*256; int c = i>>3, dd = i&7;
      s[c][dd] = vw[c*128 + d0 + dd]; }
    __syncthreads();
    #pragma unroll
    for(int p=0;p<4;p++){ int i = t + p*256; int dd = i>>7, c = i&127;
      wt[(size_t)(d0+dd)*128 + c] = f2bf(s[c][dd]); }
  } else if(bid < BB+32){
    int d0 = (bid-BB-16)*8;
    __shared__ float s[128][9];
    #pragma unroll
    for(int p=0;p<4;p++){ int i = t + p*256; int c = i>>3, dd = i&7;
      s[c][dd] = cw2[c*128 + d0 + dd]; }
    __syncthreads();
    #pragma unroll
    for(int p=0;p<4;p++){ int i = t + p*256; int dd = i>>7, c = i&127;
      cw2t[(size_t)(d0+dd)*128 + c] = f2bf(s[c][dd]); }
  } else if(bid < BB+32+76){
    __shared__ float tile[128][33];
    int idx = bid - (BB+32);
    int b = idx/38; int n0 = (idx%38)*32;
    for(int i=t;i<128*32;i+=256){ int c=i>>5, nn=i&31; int n=n0+nn;
      tile[c][nn] = (n<NQ)? iqf[((size_t)b*CC + c)*NQ + n] : 0.f; }
    __syncthreads();
    for(int i=t;i<32*128;i+=256){ int nn=i>>7, c=i&127;
      int n=n0+nn; if(n<NQ) x[((size_t)b*NQ+n)*128 + c] = tile[c][nn]; }
  } else {
    __shared__ float hid[4][128];
    int row0 = (bid - (BB+32+76))*4;
    int r = t>>7, d = t&127;
    #pragma unroll
    for(int rr=r; rr<4; rr+=2){
      int row = row0 + rr;
      float p0 = pos[row*2+0], p1 = pos[row*2+1];
      hid[rr][d] = fmaxf(p0*w1[d] + p1*w1[128+d] + b1[d], 0.f);
    }
    __syncthreads();
    #pragma unroll
    for(int rr=r; rr<4; rr+=2){
      float acc = b2[d];
      #pragma unroll 4
      for(int c=0;c<128;c++) acc += hid[rr][c]*w2[c*128 + d];
      qpe[(size_t)(row0+rr)*128+d] = acc;
    }
  }
}

// ---------------- merged: kvpe MFMA (blocks 0..464) + qkv matvec (blocks 465..764) ----------------
#define NKVPE 465
__global__ void __launch_bounds__(256) k_kvpe_qkv(
    const float* __restrict__ kpos,
    const float* __restrict__ cw1, const float* __restrict__ cb1,
    const unsigned short* __restrict__ cw2t, const float* __restrict__ cb2,
    const unsigned short* __restrict__ wt, const float* __restrict__ vb,
    unsigned short* __restrict__ kvpe,
    const float* __restrict__ x, const float* __restrict__ qpe,
    const float* __restrict__ sa_wqkv, const float* __restrict__ sa_bqkv,
    float* __restrict__ qkv){
  __shared__ unsigned short h_t[64][136];
  __shared__ unsigned short k_t[64][136];
  int t = threadIdx.x;
  int bid = blockIdx.x;
  if(bid >= NKVPE){
    float (*s_q)[128] = (float(*)[128])h_t;
    int r0 = (bid - NKVPE)*8;
    for(int i=t;i<1024;i+=256){ int r=i>>7, c=i&127;
      size_t row = (size_t)(r0+r);
      s_q[r][c] = x[row*128+c] + qpe[row*128+c]; }
    __syncthreads();
    for(int d=t; d<384; d+=256){
      float acc[8];
      #pragma unroll
      for(int r=0;r<8;r++) acc[r]=sa_bqkv[d];
      #pragma unroll 4
      for(int c=0;c<128;c++){ float wv = sa_wqkv[c*384+d];
        #pragma unroll
        for(int r=0;r<8;r++) acc[r] += s_q[r][c]*wv; }
      #pragma unroll
      for(int r=0;r<8;r++) qkv[(size_t)(r0+r)*384+d]=acc[r];
    }
    return;
  }
  int r0 = bid*64;
  int lane = t&63, wave = t>>6;
  int fr = lane&15, kg = lane>>4;

  int p = t & 63;
  int d0 = p*2;
  float w1a0 = cw1[d0],     w1a1 = cw1[d0+1];
  float w1b0 = cw1[128+d0], w1b1 = cw1[128+d0+1];
  float b10 = cb1[d0], b11 = cb1[d0+1];
  #pragma unroll 4
  for(int k=0;k<16;k++){
    int r = wave + k*4;
    int row = r0 + r;
    float p0=0.f, p1=0.f;
    if(row < LTOT){ p0 = kpos[row*2]; p1 = kpos[row*2+1]; }
    float h0 = fmaxf(p0*w1a0 + p1*w1b0 + b10, 0.f);
    float h1 = fmaxf(p0*w1a1 + p1*w1b1 + b11, 0.f);
    *reinterpret_cast<unsigned*>(&h_t[r][d0]) = (unsigned)f2bf(h0) | ((unsigned)f2bf(h1)<<16);
  }
  __syncthreads();

  f32x4 acc[4][2];
  #pragma unroll
  for(int i=0;i<4;i++)
    #pragma unroll
    for(int j=0;j<2;j++) acc[i][j] = (f32x4)0.f;
  #pragma unroll
  for(int ck=0; ck<4; ck++){
    int c0 = ck*32;
    bf16x8 bfr[2], af[4];
    #pragma unroll
    for(int j=0;j<2;j++){ int d = wave*32 + j*16 + fr;
      bfr[j] = *reinterpret_cast<const bf16x8*>(cw2t + (size_t)d*128 + c0 + kg*8); }
    #pragma unroll
    for(int i=0;i<4;i++) af[i] = *reinterpret_cast<const bf16x8*>(&h_t[i*16 + fr][c0 + kg*8]);
    #pragma unroll
    for(int i=0;i<4;i++)
      #pragma unroll
      for(int j=0;j<2;j++)
        acc[i][j] = __builtin_amdgcn_mfma_f32_16x16x32_bf16(af[i], bfr[j], acc[i][j], 0, 0, 0);
  }
  #pragma unroll
  for(int i=0;i<4;i++){
    int rbase = i*16 + kg*4;
    #pragma unroll
    for(int j=0;j<2;j++){
      int d = wave*32 + j*16 + fr;
      float bv_ = cb2[d];
      #pragma unroll
      for(int r=0;r<4;r++) k_t[rbase + r][d] = f2bf(acc[i][j][r] + bv_);
    }
  }
  __syncthreads();

  #pragma unroll
  for(int i=0;i<4;i++)
    #pragma unroll
    for(int j=0;j<2;j++) acc[i][j] = (f32x4)0.f;
  #pragma unroll
  for(int ck=0; ck<4; ck++){
    int c0 = ck*32;
    bf16x8 bfr[2], af[4];
    #pragma unroll
    for(int j=0;j<2;j++){ int d = wave*32 + j*16 + fr;
      bfr[j] = *reinterpret_cast<const bf16x8*>(wt + (size_t)d*128 + c0 + kg*8); }
    #pragma unroll
    for(int i=0;i<4;i++) af[i] = *reinterpret_cast<const bf16x8*>(&k_t[i*16 + fr][c0 + kg*8]);
    #pragma unroll
    for(int i=0;i<4;i++)
      #pragma unroll
      for(int j=0;j<2;j++)
        acc[i][j] = __builtin_amdgcn_mfma_f32_16x16x32_bf16(af[i], bfr[j], acc[i][j], 0, 0, 0);
  }
  __syncthreads();
  unsigned short (*c_l)[136] = h_t;
  #pragma unroll
  for(int i=0;i<4;i++){
    int rbase = i*16 + kg*4;
    #pragma unroll
    for(int j=0;j<2;j++){
      int d = wave*32 + j*16 + fr;
      float bv_ = vb[d];
      #pragma unroll
      for(int r=0;r<4;r++) c_l[rbase + r][d] = f2bf(acc[i][j][r] + bv_);
    }
  }
  __syncthreads();
  #pragma unroll
  for(int p4=0;p4<4;p4++){
    int i = t + p4*256;
    int row = i>>4, seg = i&15;
    int glr = r0 + row;
    if(glr < LTOT){
      uint4 cu = *reinterpret_cast<const uint4*>(&c_l[row][seg*8]);
      *reinterpret_cast<uint4*>(kvpe + (size_t)glr*CC + seg*8) = cu;
    }
  }
}

// ---------------- merged: self-attention (blocks 0..1823, reads qkv) + value GEMM ----------------
#define NATT (19*48*2)
#define QT2 64
#define KTA 64
__global__ void __launch_bounds__(256) k_value_attn2(
    const float* __restrict__ f0, const float* __restrict__ f1,
    const float* __restrict__ f2, const float* __restrict__ f3,
    const unsigned short* __restrict__ kvpe, const unsigned short* __restrict__ wt,
    unsigned short* __restrict__ value,
    const float* __restrict__ qkv,
    const int* __restrict__ order, const int* __restrict__ counts,
    float* __restrict__ att){
  __shared__ __align__(16) char smem[18688];
  int t = threadIdx.x;
  int bid = blockIdx.x;
  if(bid < NATT){
    int qt = bid % 19;
    int vh = (bid/19) % 48;
    int b  = bid/(19*48);
    int v = vh>>3, h = vh&7;
    int C = counts[b*VV+v];
    int q0 = qt*QT2;
    if(q0 >= C) return;
    const int* ord = order + (size_t)(b*VV+v)*NQ;
    float (*q_s)[17] = (float(*)[17])smem;
    float (*k_s)[16] = (float(*)[16])(smem + 4352);
    float (*v_s)[16] = (float(*)[16])(smem + 8448);
    float (*red)[QT2][18] = (float(*)[QT2][18])smem;
    int* qn_s = (int*)(smem + 18432);
    for(int i=t;i<QT2;i+=256){ int qi=q0+i; qn_s[i] = (qi<C)? ord[qi] : -1; }
    __syncthreads();
    for(int i=t;i<QT2*16;i+=256){ int r=i>>4,c=i&15; int n=qn_s[r];
      q_s[r][c] = (n>=0)? qkv[((size_t)b*NQ+n)*384 + h*16 + c] : 0.f; }
    int qi = t&63, sub = t>>6;
    float m = -1e30f, s = 0.f, acc[16];
    #pragma unroll
    for(int c=0;c<16;c++) acc[c]=0.f;
    for(int k0=0; k0<C; k0+=KTA){
      int kn = C-k0; if(kn>KTA) kn=KTA;
      __syncthreads();
      for(int i=t;i<KTA*16;i+=256){ int r=i>>4,c=i&15;
        float kv=0.f, vv=0.f;
        if(r<kn){ int n=ord[k0+r]; size_t base=((size_t)b*NQ+n)*384 + h*16 + c;
          kv = qkv[base+128]; vv = qkv[base+256]; }
        k_s[r][c]=kv; v_s[r][c]=vv; }
      __syncthreads();
      for(int mm=sub; mm<kn; mm+=4){
        float l=0.f;
        #pragma unroll
        for(int c=0;c<16;c++) l += q_s[qi][c]*k_s[mm][c];
        l *= 0.25f;
        float newm = fmaxf(m,l);
        float e = __expf(l - newm);
        if(newm > m){
          float rr = __expf(m - newm);
          s *= rr;
          #pragma unroll
          for(int c=0;c<16;c++) acc[c]*=rr;
          m = newm;
        }
        s += e;
        #pragma unroll
        for(int c=0;c<16;c++) acc[c] += e*v_s[mm][c];
      }
    }
    __syncthreads();
    red[sub][qi][0]=m; red[sub][qi][1]=s;
    #pragma unroll
    for(int c=0;c<16;c++) red[sub][qi][2+c]=acc[c];
    __syncthreads();
    if(sub==0){
      int n = qn_s[qi];
      if(n>=0){
        float M=-1e30f;
        #pragma unroll
        for(int j=0;j<4;j++) M=fmaxf(M,red[j][qi][0]);
        float S=0.f; float o[16];
        #pragma unroll
        for(int c=0;c<16;c++) o[c]=0.f;
        #pragma unroll
        for(int j=0;j<4;j++){ float e=__expf(red[j][qi][0]-M); S += e*red[j][qi][1];
          #pragma unroll
          for(int c=0;c<16;c++) o[c] += e*red[j][qi][2+c]; }
        float inv = 1.f/S;
        #pragma unroll
        for(int c=0;c<16;c++) att[((size_t)b*NQ+n)*128 + h*16 + c] = o[c]*inv;
      }
    }
    return;
  }
  unsigned short (*a_t)[136] = (unsigned short(*)[136])smem;
  int bxy = bid - NATT;
  int bv = bxy % 12;
  int bx = bxy / 12;
  int lvl, tile;
  if(bx < 350){ lvl=0; tile=bx; }
  else if(bx < 438){ lvl=1; tile=bx-350; }
  else if(bx < 460){ lvl=2; tile=bx-438; }
  else { lvl=3; tile=bx-460; }
  const int HW = (lvl==0)?22400:(lvl==1)?5600:(lvl==2)?1400:350;
  const int startL = (lvl==0)?0:(lvl==1)?22400:(lvl==2)?28000:29400;
  const float* feat = (lvl==0)?f0:(lvl==1)?f1:(lvl==2)?f2:f3;
  const float* fbase = feat + (size_t)bv*128*(size_t)HW;
  int l0 = tile*64;

  int lane = t&63, wave = t>>6;
  int fr = lane&15, kg = lane>>4;

  int l_u = t & 63, oct0 = t>>6;
  int gl = l0 + l_u; bool ok = (gl < HW);
  const float* fcol = fbase + (size_t)(oct0*8)*HW + (ok ? gl : 0);

  float v32[4][8];
  #pragma unroll
  for(int q=0;q<4;q++)
    #pragma unroll
    for(int j=0;j<8;j++)
      v32[q][j] = ok ? fcol[(size_t)(q*32+j)*HW] : 0.f;

  #pragma unroll
  for(int q=0;q<4;q++){
    uint4 u;
    u.x = (unsigned)f2bf(v32[q][0]) | ((unsigned)f2bf(v32[q][1])<<16);
    u.y = (unsigned)f2bf(v32[q][2]) | ((unsigned)f2bf(v32[q][3])<<16);
    u.z = (unsigned)f2bf(v32[q][4]) | ((unsigned)f2bf(v32[q][5])<<16);
    u.w = (unsigned)f2bf(v32[q][6]) | ((unsigned)f2bf(v32[q][7])<<16);
    *reinterpret_cast<uint4*>(&a_t[l_u][oct0*8 + q*32]) = u;
  }
  __syncthreads();

  f32x4 acc[4][2];
  #pragma unroll
  for(int i=0;i<4;i++)
    #pragma unroll
    for(int j=0;j<2;j++) acc[i][j] = (f32x4)0.f;

  #pragma unroll
  for(int ck=0; ck<4; ck++){
    int c0 = ck*32;
    bf16x8 bfr[2];
    #pragma unroll
    for(int j=0;j<2;j++){
      int d = wave*32 + j*16 + fr;
      bfr[j] = *reinterpret_cast<const bf16x8*>(wt + (size_t)d*128 + c0 + kg*8);
    }
    bf16x8 af[4];
    #pragma unroll
    for(int i=0;i<4;i++) af[i] = *reinterpret_cast<const bf16x8*>(&a_t[i*16 + fr][c0 + kg*8]);
    #pragma unroll
    for(int i=0;i<4;i++)
      #pragma unroll
      for(int j=0;j<2;j++)
        acc[i][j] = __builtin_amdgcn_mfma_f32_16x16x32_bf16(af[i], bfr[j], acc[i][j], 0, 0, 0);
  }

  __syncthreads();
  unsigned short (*c_l)[136] = a_t;
  #pragma unroll
  for(int i=0;i<4;i++){
    int rbase = i*16 + kg*4;
    #pragma unroll
    for(int j=0;j<2;j++){
      int d = wave*32 + j*16 + fr;
      #pragma unroll
      for(int r=0;r<4;r++) c_l[rbase + r][d] = f2bf(acc[i][j][r]);
    }
  }
  __syncthreads();
  #pragma unroll
  for(int p=0;p<4;p++){
    int i = t + p*256;
    int row = i>>4, seg = i&15;
    int glr = l0 + row;
    if(glr < HW){
      uint4 cu = *reinterpret_cast<const uint4*>(&c_l[row][seg*8]);
      const uint4 ku = *reinterpret_cast<const uint4*>(kvpe + (size_t)(startL+glr)*CC + seg*8);
      uint4 ou;
      ou.x = addbf2(cu.x, ku.x); ou.y = addbf2(cu.y, ku.y);
      ou.z = addbf2(cu.z, ku.z); ou.w = addbf2(cu.w, ku.w);
      *reinterpret_cast<uint4*>(value + ((size_t)bv*LTOT + startL + glr)*CC + seg*8) = ou;
    }
  }
}

// ---------------- fully fused tail (1 row/block): proj_ln1 + off/aw + sample + LN2/FFN/LN3 + head ----------------
__global__ void __launch_bounds__(128) k_tail5(
    const float* __restrict__ att, const float* __restrict__ sa_wo, const float* __restrict__ sa_bo,
    const float* __restrict__ xres, const float* __restrict__ ln1_g, const float* __restrict__ ln1_b,
    const float* __restrict__ qpe,
    const float* __restrict__ dow, const float* __restrict__ dob,
    const float* __restrict__ daw, const float* __restrict__ dab,
    const float* __restrict__ qpos, const int* __restrict__ view,
    const unsigned short* __restrict__ value,
    const float* __restrict__ dOw, const float* __restrict__ dOb,
    const float* __restrict__ ln2_g, const float* __restrict__ ln2_b,
    const float* __restrict__ fw1, const float* __restrict__ fb1,
    const float* __restrict__ fw2, const float* __restrict__ fb2,
    const float* __restrict__ ln3_g, const float* __restrict__ ln3_b,
    const float* __restrict__ pw1, const float* __restrict__ pb1,
    const float* __restrict__ pw2, const float* __restrict__ pb2,
    const int* __restrict__ counts, float* __restrict__ dout){
  int row = blockIdx.x; int d = threadIdx.x;  // 128 threads, 1 row
  int b = row/NQ, n = row%NQ;
  __shared__ float s_a[256];     // att in / FFN hidden
  __shared__ float s_x1[128];    // LN1 out
  __shared__ float s_qc[128];
  __shared__ float s_off[256];
  __shared__ float s_awr[130];
  __shared__ float s_x[128];
  __shared__ float s_m[2][2];
  __shared__ float s_res[6];
  __shared__ float sred[128][17];
  int lane = d&63, wid = d>>6;
  float v;

  // ---- phase A: o-proj + residual + LN1 ----
  s_a[d] = att[(size_t)row*128 + d];
  __syncthreads();
  float acc = sa_bo[d];
  #pragma unroll 4
  for(int c=0;c<128;c++) acc += s_a[c]*sa_wo[c*128+d];
  v = acc + xres[(size_t)row*128 + d];
  {
    float s1=v, s2=v*v;
    for(int o=32;o>0;o>>=1){ s1 += __shfl_down(s1,o); s2 += __shfl_down(s2,o); }
    if(lane==0){ s_m[wid][0]=s1; s_m[wid][1]=s2; }
  }
  __syncthreads();
  {
    float S1=s_m[0][0]+s_m[1][0], S2=s_m[0][1]+s_m[1][1];
    float mean=S1*(1.f/128.f), var=S2*(1.f/128.f)-mean*mean;
    float rs=rsqrtf(var+1e-5f);
    float o=(v-mean)*rs*ln1_g[d]+ln1_b[d];
    s_x1[d]=o;
    s_qc[d]=o+qpe[(size_t)row*128+d];
  }
  __syncthreads();

  // ---- phase B: offset matvec (256) + aw matvec (128) + per-head softmax ----
  float o0=dob[d], o1=dob[d+128], aw=dab[d];
  #pragma unroll 4
  for(int c=0;c<128;c++){
    float q = s_qc[c];
    o0 += q*dow[(size_t)c*256+d];
    o1 += q*dow[(size_t)c*256+d+128];
    aw += q*daw[(size_t)c*128+d];
  }
  s_off[d]=o0; s_off[d+128]=o1; s_awr[d]=aw;
  __syncthreads();
  if(d < 8){
    int h = d;
    float mx=-1e30f;
    #pragma unroll
    for(int i=0;i<16;i++) mx = fmaxf(mx, s_awr[h*16+i]);
    float e[16]; float sm=0.f;
    #pragma unroll
    for(int i=0;i<16;i++){ e[i]=__expf(s_awr[h*16+i]-mx); sm+=e[i]; }
    float inv = 1.f/sm;
    #pragma unroll
    for(int i=0;i<16;i++) s_awr[h*16+i] = e[i]*inv;
  }
  __syncthreads();

  // ---- phase C: bilinear sample ----
  int h = d>>4, lp = d&15, lvl = lp>>2;
  int w = c_W[lvl], hh = c_H[lvl];
  float rx = sigm(qpos[row*2]), ry = sigm(qpos[row*2+1]);
  int vw = view[row];
  float ox = s_off[d*2], oy = s_off[d*2+1];
  float awv = s_awr[d];
  float lx = rx*(float)w + ox - 0.5f;
  float ly = ry*(float)hh + oy - 0.5f;
  float x0f = floorf(lx), y0f = floorf(ly);
  float fx = lx - x0f, fy = ly - y0f;
  int x0 = (int)x0f, y0 = (int)y0f;
  float samp[16];
  #pragma unroll
  for(int c=0;c<16;c++) samp[c]=0.f;
  size_t brow = ((size_t)(b*VV + vw))*LTOT + c_S[lvl];
  #pragma unroll
  for(int dy=0;dy<2;dy++){
    #pragma unroll
    for(int dx=0;dx<2;dx++){
      int xi=x0+dx, yi=y0+dy;
      if(xi<0||xi>=w||yi<0||yi>=hh) continue;
      float wt = (dx?fx:(1.f-fx))*(dy?fy:(1.f-fy));
      const uint4* vp = reinterpret_cast<const uint4*>(value + (brow + (size_t)yi*w + xi)*CC + h*16);
      uint4 u0 = vp[0], u1 = vp[1];
      samp[0] += wt*bflo(u0.x); samp[1] += wt*bfhi(u0.x);
      samp[2] += wt*bflo(u0.y); samp[3] += wt*bfhi(u0.y);
      samp[4] += wt*bflo(u0.z); samp[5] += wt*bfhi(u0.z);
      samp[6] += wt*bflo(u0.w); samp[7] += wt*bfhi(u0.w);
      samp[8] += wt*bflo(u1.x); samp[9] += wt*bfhi(u1.x);
      samp[10]+= wt*bflo(u1.y); samp[11]+= wt*bfhi(u1.y);
      samp[12]+= wt*bflo(u1.z); samp[13]+= wt*bfhi(u1.z);
      samp[14]+= wt*bflo(u1.w); samp[15]+= wt*bfhi(u1.w);
    }
  }
  #pragma unroll
  for(int c=0;c<16;c++) sred[d][c] = awv*samp[c];
  __syncthreads();
  {
    int h2=d>>4, c2=d&15;
    float sum=0.f;
    #pragma unroll
    for(int j=0;j<16;j++) sum += sred[h2*16+j][c2];
    s_a[d] = sum;   // ca
  }
  __syncthreads();

  // ---- phase D: proj2 + resid(LN1 out) + LN2 ----
  acc = dOb[d];
  #pragma unroll 4
  for(int c=0;c<128;c++) acc += s_a[c]*dOw[c*128+d];
  v = acc + s_x1[d];
  {
    float s1=v, s2=v*v;
    for(int o=32;o>0;o>>=1){ s1 += __shfl_down(s1,o); s2 += __shfl_down(s2,o); }
    if(lane==0){ s_m[wid][0]=s1; s_m[wid][1]=s2; }
  }
  __syncthreads();
  {
    float S1=s_m[0][0]+s_m[1][0], S2=s_m[0][1]+s_m[1][1];
    float mean=S1*(1.f/128.f), var=S2*(1.f/128.f)-mean*mean;
    float rs=rsqrtf(var+1e-5f);
    s_x[d]=(v-mean)*rs*ln2_g[d]+ln2_b[d];
  }
  __syncthreads();

  // ---- FFN1 ----
  float a2a=fb1[d], a2b=fb1[d+128];
  #pragma unroll 4
  for(int c=0;c<128;c++){
    float xv = s_x[c];
    a2a += xv*fw1[c*256+d];
    a2b += xv*fw1[c*256+d+128];
  }
  __syncthreads();
  s_a[d]=fmaxf(a2a,0.f); s_a[d+128]=fmaxf(a2b,0.f);
  __syncthreads();

  // ---- FFN2 + resid + LN3 + valid-zero ----
  float a3 = fb2[d];
  #pragma unroll 4
  for(int c=0;c<256;c++) a3 += s_a[c]*fw2[c*128+d];
  v = a3 + s_x[d];
  {
    float s1=v, s2=v*v;
    for(int o=32;o>0;o>>=1){ s1 += __shfl_down(s1,o); s2 += __shfl_down(s2,o); }
    if(lane==0){ s_m[wid][0]=s1; s_m[wid][1]=s2; }
  }
  __syncthreads();
  bool val = counts[b*VV + vw] > 1;
  {
    float S1=s_m[0][0]+s_m[1][0], S2=s_m[0][1]+s_m[1][1];
    float mean=S1*(1.f/128.f), var=S2*(1.f/128.f)-mean*mean;
    float rs=rsqrtf(var+1e-5f);
    float o=(v-mean)*rs*ln3_g[d]+ln3_b[d];
    float oz = val ? o : 0.f;
    s_x[d]=oz;
    dout[((size_t)b*CC + d)*NQ + n]=oz;
  }
  __syncthreads();

  // ---- head ----
  float a4 = pb1[d];
  #pragma unroll 4
  for(int c=0;c<128;c++) a4 += s_x[c]*pw1[c*128+d];
  __syncthreads();
  s_a[d]=fmaxf(a4,0.f);
  __syncthreads();

  if(d < 6){
    float a5 = pb2[d];
    #pragma unroll 4
    for(int c=0;c<128;c++) a5 += s_a[c]*pw2[c*6+d];
    s_res[d] = a5;
  }
  __syncthreads();
  if(d == 0){
    const int O1 = BB*CC*NQ;
    const int O2 = O1 + BB*NQ*2;
    const int O3 = O2 + BB*2*NQ;
    const int O4 = O3 + BB*4*NQ;
    float p0=qpos[row*2], p1=qpos[row*2+1];
    float cr0 = s_res[0]+p0, cr1 = s_res[1]+p1;
    dout[O1 + row*2]   = cr0;
    dout[O1 + row*2+1] = cr1;
    float cen0 = sigm(cr0), cen1 = sigm(cr1);
    dout[O2 + (b*2+0)*NQ + n] = cen0;
    dout[O2 + (b*2+1)*NQ + n] = cen1;
    float f0=sigm(s_res[2]), f1=sigm(s_res[3]), f2=sigm(s_res[4]), f3=sigm(s_res[5]);
    dout[O3 + (b*4+0)*NQ + n] = f0;
    dout[O3 + (b*4+1)*NQ + n] = f1;
    dout[O3 + (b*4+2)*NQ + n] = f2;
    dout[O3 + (b*4+3)*NQ + n] = f3;
    float bw=f0+f2, bh=f1+f3;
    float cx=(2.f*cen0 - f0 + f2)*0.5f;
    float cy=(2.f*cen1 - f1 + f3)*0.5f;
    dout[O4 + (b*4+0)*NQ + n] = cx;
    dout[O4 + (b*4+1)*NQ + n] = cy;
    dout[O4 + (b*4+2)*NQ + n] = bw;
    dout[O4 + (b*4+3)*NQ + n] = bh;
  }
}

extern "C" void kernel_launch(void* const* d_in, const int* in_sizes, int n_in,
                              void* d_out, int out_size, void* d_ws, size_t ws_size,
                              hipStream_t stream){
  (void)in_sizes; (void)n_in; (void)out_size; (void)ws_size;
  const float* in_iqf  = (const float*)d_in[0];
  const float* in_qpos = (const float*)d_in[1];
  const float* in_feat[4] = {(const float*)d_in[2],(const float*)d_in[3],(const float*)d_in[4],(const float*)d_in[5]};
  const float* in_kpos = (const float*)d_in[6];
  const float* sp_w1=(const float*)d_in[7], *sp_b1=(const float*)d_in[8], *sp_w2=(const float*)d_in[9], *sp_b2=(const float*)d_in[10];
  const float* cp_w1=(const float*)d_in[11], *cp_b1=(const float*)d_in[12], *cp_w2=(const float*)d_in[13], *cp_b2=(const float*)d_in[14];
  const float* sa_wqkv=(const float*)d_in[15], *sa_bqkv=(const float*)d_in[16], *sa_wo=(const float*)d_in[17], *sa_bo=(const float*)d_in[18];
  const float* ln1_g=(const float*)d_in[19], *ln1_b=(const float*)d_in[20];
  const float* dvw=(const float*)d_in[21], *dvb=(const float*)d_in[22];
  const float* dow=(const float*)d_in[23], *dob=(const float*)d_in[24];
  const float* daw=(const float*)d_in[25], *dab=(const float*)d_in[26];
  const float* dOw=(const float*)d_in[27], *dOb=(const float*)d_in[28];
  const float* ln2_g=(const float*)d_in[29], *ln2_b=(const float*)d_in[30];
  const float* fw1=(const float*)d_in[31], *fb1=(const float*)d_in[32], *fw2=(const float*)d_in[33], *fb2=(const float*)d_in[34];
  const float* ln3_g=(const float*)d_in[35], *ln3_b=(const float*)d_in[36];
  const float* pw1=(const float*)d_in[37], *pb1=(const float*)d_in[38], *pw2=(const float*)d_in[39], *pb2=(const float*)d_in[40];
  const int* in_view = (const int*)d_in[41];
  float* out = (float*)d_out;

  char* ws = (char*)d_ws;
  unsigned short* value = (unsigned short*)ws;                       // 91,392,000 B
  unsigned short* kvpe  = (unsigned short*)(ws + 91392000);          //  7,616,000 B
  float* f = (float*)(ws + 91392000 + 7616000);
  float* qpe  = f;               // 307200
  float* x    = f + 307200;      // 307200
  float* qkv  = f + 614400;      // 921600
  float* att  = f + 1536000;     // 307200
  int* counts = (int*)(f + 4300800);   // 12 ints
  int* order  = (int*)(f + 4300816);   // B*VV*NQ = 14400 ints
  unsigned short* wtb   = (unsigned short*)(f + 4315216);  // 32768 B
  unsigned short* cw2tb = (unsigned short*)(f + 4323408);  // 32768 B

  k_misc<<<dim3(BB+32+76+600),dim3(256),0,stream>>>(in_view,order,counts,dvw,wtb,
      cp_w2,cw2tb,in_iqf,x,in_qpos,sp_w1,sp_b1,sp_w2,sp_b2,qpe);
  k_kvpe_qkv<<<dim3(NKVPE + 300),dim3(256),0,stream>>>(in_kpos,cp_w1,cp_b1,cw2tb,cp_b2,wtb,dvb,kvpe,
      x,qpe,sa_wqkv,sa_bqkv,qkv);
  k_value_attn2<<<dim3(NATT + 466*12),dim3(256),0,stream>>>(in_feat[0],in_feat[1],in_feat[2],in_feat[3],
      kvpe,wtb,value,qkv,order,counts,att);
  k_tail5<<<dim3(NROWS),dim3(128),0,stream>>>(att,sa_wo,sa_bo,x,ln1_g,ln1_b,qpe,
      dow,dob,daw,dab,in_qpos,in_view,value,
      dOw,dOb,ln2_g,ln2_b,fw1,fb1,fw2,fb2,ln3_g,ln3_b,pw1,pb1,pw2,pb2,counts,out);
}